// Round 1
// baseline (937.561 us; speedup 1.0000x reference)
//
#include <hip/hip_runtime.h>
#include <math.h>

// ---------------------------------------------------------------------------
// Problem dims (fixed by the reference): N=32768 nodes, E=524288 edges,
// node feat 64, edge feat 32, transformer H=4 heads x C=64 = 256 channels.
// ---------------------------------------------------------------------------

// ---------------- edge_index dtype detection + convert ---------------------
// int64 values in [0,32768) have all high 32-bit words == 0. For int32 data
// the "high word" positions hold real indices (P(all zero) ~ 0).
__global__ void k_detect(const unsigned int* __restrict__ w, int* __restrict__ flag)
{
    __shared__ int any;
    if (threadIdx.x == 0) any = 0;
    __syncthreads();
    int found = 0;
    for (int i = threadIdx.x; i < 2048; i += 256)
        if (w[2 * i + 1] != 0u) found = 1;
    if (found) atomicOr(&any, 1);
    __syncthreads();
    if (threadIdx.x == 0) flag[0] = any ? 0 : 1;   // 1 => int64
}

__global__ void k_cvt(const void* __restrict__ eidx, const int* __restrict__ flag,
                      int* __restrict__ out, int n)
{
    int i = blockIdx.x * blockDim.x + threadIdx.x;
    if (i >= n) return;
    if (flag[0])
        out[i] = (int)((const long long*)eidx)[i];
    else
        out[i] = ((const int*)eidx)[i];
}

// ---------------- CSR build (group edges by dst) ---------------------------
__global__ void k_hist(const int* __restrict__ dst, int* __restrict__ counts, int E)
{
    int i = blockIdx.x * blockDim.x + threadIdx.x;
    if (i < E) atomicAdd(&counts[dst[i]], 1);
}

// single block, 1024 threads, N = 32768 = 1024*32
__global__ void k_scan(const int* __restrict__ counts, int* __restrict__ offs,
                       int* __restrict__ cursor, int N)
{
    __shared__ int part[1024];
    int t = threadIdx.x;
    int base = t * 32;
    int loc[32];
    int s = 0;
#pragma unroll
    for (int i = 0; i < 32; i++) { loc[i] = counts[base + i]; s += loc[i]; }
    part[t] = s;
    __syncthreads();
    for (int off = 1; off < 1024; off <<= 1) {
        int v = (t >= off) ? part[t - off] : 0;
        __syncthreads();
        part[t] += v;
        __syncthreads();
    }
    int run = part[t] - s;   // exclusive prefix
#pragma unroll
    for (int i = 0; i < 32; i++) {
        offs[base + i] = run;
        cursor[base + i] = run;
        run += loc[i];
    }
    if (t == 1023) offs[N] = run;   // == E
}

__global__ void k_scatter(const int* __restrict__ dst, int* __restrict__ cursor,
                          int* __restrict__ perm, int E)
{
    int i = blockIdx.x * blockDim.x + threadIdx.x;
    if (i < E) {
        int d = dst[i];
        int p = atomicAdd(&cursor[d], 1);
        perm[p] = i;
    }
}

// ---------------- generic small GEMM: Y = [relu](X @ W + b) ----------------
// X: N x Kdim, W: Kdim x Kout, Y: N x Kout. grid = (N/64, ceil(Kout/64)).
__global__ __launch_bounds__(256) void k_gemm(
    const float* __restrict__ X, int Kdim,
    const float* __restrict__ W, const float* __restrict__ bias,
    float* __restrict__ Y, int Kout, int dorelu)
{
    __shared__ float Xs[64][68];
    __shared__ float Ws[64][68];
    int n0 = blockIdx.x * 64;
    int j0 = blockIdx.y * 64;
    int t  = threadIdx.x;
    float acc[4][4] = {};
    for (int kk = 0; kk < Kdim; kk += 64) {
        for (int f = t; f < 4096; f += 256) {
            int r = f >> 6, c = f & 63;
            Xs[r][c] = (kk + c < Kdim) ? X[(size_t)(n0 + r) * Kdim + kk + c] : 0.f;
        }
        for (int f = t; f < 4096; f += 256) {
            int k = f >> 6, j = f & 63;
            Ws[k][j] = (kk + k < Kdim && j0 + j < Kout)
                           ? W[(size_t)(kk + k) * Kout + j0 + j] : 0.f;
        }
        __syncthreads();
        int rr = (t >> 4) << 2, jj = (t & 15) << 2;
#pragma unroll 8
        for (int k = 0; k < 64; k++) {
            float4 wv = *(const float4*)&Ws[k][jj];
            float x0 = Xs[rr + 0][k], x1 = Xs[rr + 1][k];
            float x2 = Xs[rr + 2][k], x3 = Xs[rr + 3][k];
            acc[0][0] = fmaf(x0, wv.x, acc[0][0]); acc[0][1] = fmaf(x0, wv.y, acc[0][1]);
            acc[0][2] = fmaf(x0, wv.z, acc[0][2]); acc[0][3] = fmaf(x0, wv.w, acc[0][3]);
            acc[1][0] = fmaf(x1, wv.x, acc[1][0]); acc[1][1] = fmaf(x1, wv.y, acc[1][1]);
            acc[1][2] = fmaf(x1, wv.z, acc[1][2]); acc[1][3] = fmaf(x1, wv.w, acc[1][3]);
            acc[2][0] = fmaf(x2, wv.x, acc[2][0]); acc[2][1] = fmaf(x2, wv.y, acc[2][1]);
            acc[2][2] = fmaf(x2, wv.z, acc[2][2]); acc[2][3] = fmaf(x2, wv.w, acc[2][3]);
            acc[3][0] = fmaf(x3, wv.x, acc[3][0]); acc[3][1] = fmaf(x3, wv.y, acc[3][1]);
            acc[3][2] = fmaf(x3, wv.z, acc[3][2]); acc[3][3] = fmaf(x3, wv.w, acc[3][3]);
        }
        __syncthreads();
    }
    int rr = (t >> 4) << 2, jj = (t & 15) << 2;
    if (j0 + jj < Kout) {
        float4 bv = *(const float4*)&bias[j0 + jj];
#pragma unroll
        for (int i = 0; i < 4; i++) {
            float4 o;
            o.x = acc[i][0] + bv.x; o.y = acc[i][1] + bv.y;
            o.z = acc[i][2] + bv.z; o.w = acc[i][3] + bv.w;
            if (dorelu) {
                o.x = fmaxf(o.x, 0.f); o.y = fmaxf(o.y, 0.f);
                o.z = fmaxf(o.z, 0.f); o.w = fmaxf(o.w, 0.f);
            }
            *(float4*)&Y[(size_t)(n0 + rr + i) * Kout + j0 + jj] = o;
        }
    }
}

// ---------------- GINE aggregation: h = (1+eps)*x + sum relu(x[src]+e) -----
// one wave per dst node, lane = channel (64)
__global__ __launch_bounds__(256) void k_gine_agg(
    const float* __restrict__ xin, const float* __restrict__ we,
    const float* __restrict__ be, const float* __restrict__ epsp,
    const int* __restrict__ src, const float* __restrict__ edge_attr,
    const int* __restrict__ offs, const int* __restrict__ perm,
    float* __restrict__ hout)
{
    int lane = threadIdx.x & 63;
    int wid  = __builtin_amdgcn_readfirstlane(threadIdx.x >> 6);
    int n    = blockIdx.x * 4 + wid;
    float wreg[32];
#pragma unroll
    for (int k = 0; k < 32; k++) wreg[k] = we[k * 64 + lane];
    float bec = be[lane];
    float acc = 0.f;
    int j0 = offs[n], j1 = offs[n + 1];
    for (int j = j0; j < j1; j++) {
        int e = perm[j];
        const float4* ea4 = (const float4*)(edge_attr + (size_t)e * 32);
        float eav[32];
#pragma unroll
        for (int w = 0; w < 8; w++) {
            float4 t4 = ea4[w];
            eav[4 * w] = t4.x; eav[4 * w + 1] = t4.y;
            eav[4 * w + 2] = t4.z; eav[4 * w + 3] = t4.w;
        }
        float ec = bec;
#pragma unroll
        for (int k = 0; k < 32; k++) ec = fmaf(eav[k], wreg[k], ec);
        int s = src[e];
        float v = xin[(size_t)s * 64 + lane] + ec;
        acc += fmaxf(v, 0.f);
    }
    float eps = epsp[0];
    hout[(size_t)n * 64 + lane] = (1.f + eps) * xin[(size_t)n * 64 + lane] + acc;
}

// ---------------- TransformerConv aggregation ------------------------------
// block = one dst node (256 threads); wave = head; lane = channel; ch = tid.
// skip_io holds skip on entry, overwritten with layer output (read-then-write
// by the same thread).
__global__ __launch_bounds__(256) void k_tconv(
    const float* __restrict__ qb, const float* __restrict__ kb,
    const float* __restrict__ vb, const float* __restrict__ we3,
    const int* __restrict__ src, const float* __restrict__ edge_attr,
    const int* __restrict__ offs, const int* __restrict__ perm,
    float* __restrict__ skip_io)
{
    int n  = blockIdx.x;
    int ch = threadIdx.x;            // 0..255 == head*64 + c
    float wreg[32];
#pragma unroll
    for (int k = 0; k < 32; k++) wreg[k] = we3[k * 256 + ch];
    float qc = qb[(size_t)n * 256 + ch];
    float m = -INFINITY, l = 0.f, acc = 0.f;
    int j0 = offs[n], j1 = offs[n + 1];
    for (int j = j0; j < j1; j++) {
        int e = perm[j];
        const float4* ea4 = (const float4*)(edge_attr + (size_t)e * 32);
        float eav[32];
#pragma unroll
        for (int w = 0; w < 8; w++) {
            float4 t4 = ea4[w];
            eav[4 * w] = t4.x; eav[4 * w + 1] = t4.y;
            eav[4 * w + 2] = t4.z; eav[4 * w + 3] = t4.w;
        }
        float ec = 0.f;
#pragma unroll
        for (int k = 0; k < 32; k++) ec = fmaf(eav[k], wreg[k], ec);
        int s = src[e];
        float kv = kb[(size_t)s * 256 + ch] + ec;
        float p = qc * kv;
#pragma unroll
        for (int o = 32; o > 0; o >>= 1) p += __shfl_xor(p, o);
        float logit = p * 0.125f;            // / sqrt(64)
        float mn = fmaxf(m, logit);
        float sc = __expf(m - mn);           // first iter: exp(-inf)=0
        float w  = __expf(logit - mn);
        float vv = vb[(size_t)s * 256 + ch] + ec;
        l   = l * sc + w;
        acc = acc * sc + w * vv;
        m = mn;
    }
    float out = acc / (l + 1e-16f) + skip_io[(size_t)n * 256 + ch];
    skip_io[(size_t)n * 256 + ch] = out;
}

// ---------------- GATv2 aggregation ----------------------------------------
// one wave per dst node, lane = channel (64); writes final output + bias4.
__global__ __launch_bounds__(256) void k_gat(
    const float* __restrict__ xl, const float* __restrict__ xr,
    const float* __restrict__ we4, const float* __restrict__ attv,
    const float* __restrict__ bias4,
    const int* __restrict__ src, const float* __restrict__ edge_attr,
    const int* __restrict__ offs, const int* __restrict__ perm,
    float* __restrict__ out)
{
    int lane = threadIdx.x & 63;
    int wid  = __builtin_amdgcn_readfirstlane(threadIdx.x >> 6);
    int n    = blockIdx.x * 4 + wid;
    float wreg[32];
#pragma unroll
    for (int k = 0; k < 32; k++) wreg[k] = we4[k * 64 + lane];
    float attc = attv[lane];
    float xrc  = xr[(size_t)n * 64 + lane];
    float m = -INFINITY, l = 0.f, acc = 0.f;
    int j0 = offs[n], j1 = offs[n + 1];
    for (int j = j0; j < j1; j++) {
        int e = perm[j];
        const float4* ea4 = (const float4*)(edge_attr + (size_t)e * 32);
        float eav[32];
#pragma unroll
        for (int w = 0; w < 8; w++) {
            float4 t4 = ea4[w];
            eav[4 * w] = t4.x; eav[4 * w + 1] = t4.y;
            eav[4 * w + 2] = t4.z; eav[4 * w + 3] = t4.w;
        }
        float ec = 0.f;
#pragma unroll
        for (int k = 0; k < 32; k++) ec = fmaf(eav[k], wreg[k], ec);
        int s = src[e];
        float xls = xl[(size_t)s * 64 + lane];
        float hm = xls + xrc + ec;
        hm = (hm > 0.f) ? hm : 0.2f * hm;    // leaky_relu 0.2
        float p = hm * attc;
#pragma unroll
        for (int o = 32; o > 0; o >>= 1) p += __shfl_xor(p, o);
        float logit = p;
        float mn = fmaxf(m, logit);
        float sc = __expf(m - mn);
        float w  = __expf(logit - mn);
        l   = l * sc + w;
        acc = acc * sc + w * xls;
        m = mn;
    }
    out[(size_t)n * 64 + lane] = acc / (l + 1e-16f) + bias4[lane];
}

// ---------------------------------------------------------------------------
extern "C" void kernel_launch(void* const* d_in, const int* in_sizes, int n_in,
                              void* d_out, int out_size, void* d_ws, size_t ws_size,
                              hipStream_t stream)
{
    const float* x     = (const float*)d_in[0];
    const float* ea    = (const float*)d_in[1];
    const float* eps1  = (const float*)d_in[2];
    const float* w1a   = (const float*)d_in[3];
    const float* b1a   = (const float*)d_in[4];
    const float* w1b   = (const float*)d_in[5];
    const float* b1b   = (const float*)d_in[6];
    const float* we1   = (const float*)d_in[7];
    const float* be1   = (const float*)d_in[8];
    const float* eps2  = (const float*)d_in[9];
    const float* w2a   = (const float*)d_in[10];
    const float* b2a   = (const float*)d_in[11];
    const float* w2b   = (const float*)d_in[12];
    const float* b2b   = (const float*)d_in[13];
    const float* we2   = (const float*)d_in[14];
    const float* be2   = (const float*)d_in[15];
    const float* wq    = (const float*)d_in[16];
    const float* bq    = (const float*)d_in[17];
    const float* wk    = (const float*)d_in[18];
    const float* bk    = (const float*)d_in[19];
    const float* wv    = (const float*)d_in[20];
    const float* bv    = (const float*)d_in[21];
    const float* we3   = (const float*)d_in[22];
    const float* wskip = (const float*)d_in[23];
    const float* bskip = (const float*)d_in[24];
    const float* wl    = (const float*)d_in[25];
    const float* bl    = (const float*)d_in[26];
    const float* wr    = (const float*)d_in[27];
    const float* br    = (const float*)d_in[28];
    const float* we4   = (const float*)d_in[29];
    const float* attv  = (const float*)d_in[30];
    const float* bias4 = (const float*)d_in[31];
    const void*  eidx  = d_in[32];

    const int N = in_sizes[0] / 64;     // 32768
    const int E = in_sizes[1] / 32;     // 524288

    char* ws = (char*)d_ws;
    size_t off = 0;
    auto alloc = [&](size_t bytes) {
        void* p = ws + off;
        off += (bytes + 255) & ~(size_t)255;
        return p;
    };
    int* flag    = (int*)alloc(4);
    int* econv   = (int*)alloc((size_t)2 * E * 4);
    int* counts  = (int*)alloc((size_t)N * 4);
    int* cursor  = (int*)alloc((size_t)N * 4);
    int* offs    = (int*)alloc((size_t)(N + 1) * 4);
    int* perm    = (int*)alloc((size_t)E * 4);
    float* h     = (float*)alloc((size_t)N * 64 * 4);
    float* t1    = (float*)alloc((size_t)N * 64 * 4);
    float* x1    = (float*)alloc((size_t)N * 64 * 4);
    float* x2    = (float*)alloc((size_t)N * 64 * 4);
    float* qb    = (float*)alloc((size_t)N * 256 * 4);
    float* kb    = (float*)alloc((size_t)N * 256 * 4);
    float* vb    = (float*)alloc((size_t)N * 256 * 4);
    float* skipb = (float*)alloc((size_t)N * 256 * 4);
    float* xlb   = h;    // dead by then, reuse
    float* xrb   = t1;   // dead by then, reuse

    if (off > ws_size) return;   // workspace too small -> visible failure

    // edge_index dtype detect + convert to int32
    k_detect<<<1, 256, 0, stream>>>((const unsigned int*)eidx, flag);
    k_cvt<<<(2 * E + 255) / 256, 256, 0, stream>>>(eidx, flag, econv, 2 * E);
    const int* srcI = econv;
    const int* dstI = econv + E;

    // CSR by dst
    hipMemsetAsync(counts, 0, (size_t)N * 4, stream);
    k_hist<<<(E + 255) / 256, 256, 0, stream>>>(dstI, counts, E);
    k_scan<<<1, 1024, 0, stream>>>(counts, offs, cursor, N);
    k_scatter<<<(E + 255) / 256, 256, 0, stream>>>(dstI, cursor, perm, E);

    // GINE 1
    k_gine_agg<<<N / 4, 256, 0, stream>>>(x, we1, be1, eps1, srcI, ea, offs, perm, h);
    k_gemm<<<dim3(N / 64, 1), 256, 0, stream>>>(h, 64, w1a, b1a, t1, 64, 1);
    k_gemm<<<dim3(N / 64, 1), 256, 0, stream>>>(t1, 64, w1b, b1b, x1, 64, 0);

    // GINE 2
    k_gine_agg<<<N / 4, 256, 0, stream>>>(x1, we2, be2, eps2, srcI, ea, offs, perm, h);
    k_gemm<<<dim3(N / 64, 1), 256, 0, stream>>>(h, 64, w2a, b2a, t1, 32, 1);
    k_gemm<<<dim3(N / 64, 1), 256, 0, stream>>>(t1, 32, w2b, b2b, x2, 64, 0);

    // TransformerConv
    k_gemm<<<dim3(N / 64, 4), 256, 0, stream>>>(x2, 64, wq, bq, qb, 256, 0);
    k_gemm<<<dim3(N / 64, 4), 256, 0, stream>>>(x2, 64, wk, bk, kb, 256, 0);
    k_gemm<<<dim3(N / 64, 4), 256, 0, stream>>>(x2, 64, wv, bv, vb, 256, 0);
    k_gemm<<<dim3(N / 64, 4), 256, 0, stream>>>(x2, 64, wskip, bskip, skipb, 256, 0);
    k_tconv<<<N, 256, 0, stream>>>(qb, kb, vb, we3, srcI, ea, offs, perm, skipb);

    // GATv2
    k_gemm<<<dim3(N / 64, 1), 256, 0, stream>>>(skipb, 256, wl, bl, xlb, 64, 0);
    k_gemm<<<dim3(N / 64, 1), 256, 0, stream>>>(skipb, 256, wr, br, xrb, 64, 0);
    k_gat<<<N / 4, 256, 0, stream>>>(xlb, xrb, we4, attv, bias4, srcI, ea, offs, perm,
                                     (float*)d_out);
}

// Round 2
// 878.702 us; speedup vs baseline: 1.0670x; 1.0670x over previous
//
#include <hip/hip_runtime.h>
#include <math.h>

// ---------------------------------------------------------------------------
// N=32768 nodes, E=524288 edges, node feat 64, edge feat 32, H=4 x C=64 = 256.
// ---------------------------------------------------------------------------

typedef __attribute__((ext_vector_type(8))) short short8v;
typedef __attribute__((ext_vector_type(4))) float float4v;

static __device__ __forceinline__ unsigned short f2bf(float f)
{
    unsigned int u = __float_as_uint(f);
    unsigned int r = (u + 0x7FFFu + ((u >> 16) & 1u)) >> 16;
    return (unsigned short)r;
}
static __device__ __forceinline__ float bf2f(unsigned short b)
{
    return __uint_as_float((unsigned int)b << 16);
}

// ---------------- edge_index dtype detection + convert ---------------------
__global__ void k_detect(const unsigned int* __restrict__ w, int* __restrict__ flag)
{
    __shared__ int any;
    if (threadIdx.x == 0) any = 0;
    __syncthreads();
    int found = 0;
    for (int i = threadIdx.x; i < 2048; i += 256)
        if (w[2 * i + 1] != 0u) found = 1;
    if (found) atomicOr(&any, 1);
    __syncthreads();
    if (threadIdx.x == 0) flag[0] = any ? 0 : 1;   // 1 => int64
}

__global__ void k_cvt(const void* __restrict__ eidx, const int* __restrict__ flag,
                      int* __restrict__ out, int n)
{
    int i = blockIdx.x * blockDim.x + threadIdx.x;
    if (i >= n) return;
    if (flag[0])
        out[i] = (int)((const long long*)eidx)[i];
    else
        out[i] = ((const int*)eidx)[i];
}

// ---------------- CSR build (group edges by dst) ---------------------------
__global__ void k_hist(const int* __restrict__ dst, int* __restrict__ counts, int E)
{
    int i = blockIdx.x * blockDim.x + threadIdx.x;
    if (i < E) atomicAdd(&counts[dst[i]], 1);
}

__global__ void k_scan(const int* __restrict__ counts, int* __restrict__ offs,
                       int* __restrict__ cursor, int N)
{
    __shared__ int part[1024];
    int t = threadIdx.x;
    int base = t * 32;
    int loc[32];
    int s = 0;
#pragma unroll
    for (int i = 0; i < 32; i++) { loc[i] = counts[base + i]; s += loc[i]; }
    part[t] = s;
    __syncthreads();
    for (int off = 1; off < 1024; off <<= 1) {
        int v = (t >= off) ? part[t - off] : 0;
        __syncthreads();
        part[t] += v;
        __syncthreads();
    }
    int run = part[t] - s;   // exclusive prefix
#pragma unroll
    for (int i = 0; i < 32; i++) {
        offs[base + i] = run;
        cursor[base + i] = run;
        run += loc[i];
    }
    if (t == 1023) offs[N] = run;
}

__global__ void k_scatter(const int* __restrict__ dst, const int* __restrict__ srcA,
                          int* __restrict__ cursor, int* __restrict__ perm,
                          int* __restrict__ sperm, int E)
{
    int i = blockIdx.x * blockDim.x + threadIdx.x;
    if (i < E) {
        int d = dst[i];
        int p = atomicAdd(&cursor[d], 1);
        perm[p] = i;
        sperm[p] = srcA[i];
    }
}

// ---------------- generic small GEMM: Y = [relu](X @ W + b) ----------------
__global__ __launch_bounds__(256) void k_gemm(
    const float* __restrict__ X, int Kdim,
    const float* __restrict__ W, const float* __restrict__ bias,
    float* __restrict__ Y, int Kout, int dorelu)
{
    __shared__ float Xs[64][68];
    __shared__ float Ws[64][68];
    int n0 = blockIdx.x * 64;
    int j0 = blockIdx.y * 64;
    int t  = threadIdx.x;
    float acc[4][4] = {};
    for (int kk = 0; kk < Kdim; kk += 64) {
        for (int f = t; f < 4096; f += 256) {
            int r = f >> 6, c = f & 63;
            Xs[r][c] = (kk + c < Kdim) ? X[(size_t)(n0 + r) * Kdim + kk + c] : 0.f;
        }
        for (int f = t; f < 4096; f += 256) {
            int k = f >> 6, j = f & 63;
            Ws[k][j] = (kk + k < Kdim && j0 + j < Kout)
                           ? W[(size_t)(kk + k) * Kout + j0 + j] : 0.f;
        }
        __syncthreads();
        int rr = (t >> 4) << 2, jj = (t & 15) << 2;
#pragma unroll 8
        for (int k = 0; k < 64; k++) {
            float4 wv = *(const float4*)&Ws[k][jj];
            float x0 = Xs[rr + 0][k], x1 = Xs[rr + 1][k];
            float x2 = Xs[rr + 2][k], x3 = Xs[rr + 3][k];
            acc[0][0] = fmaf(x0, wv.x, acc[0][0]); acc[0][1] = fmaf(x0, wv.y, acc[0][1]);
            acc[0][2] = fmaf(x0, wv.z, acc[0][2]); acc[0][3] = fmaf(x0, wv.w, acc[0][3]);
            acc[1][0] = fmaf(x1, wv.x, acc[1][0]); acc[1][1] = fmaf(x1, wv.y, acc[1][1]);
            acc[1][2] = fmaf(x1, wv.z, acc[1][2]); acc[1][3] = fmaf(x1, wv.w, acc[1][3]);
            acc[2][0] = fmaf(x2, wv.x, acc[2][0]); acc[2][1] = fmaf(x2, wv.y, acc[2][1]);
            acc[2][2] = fmaf(x2, wv.z, acc[2][2]); acc[2][3] = fmaf(x2, wv.w, acc[2][3]);
            acc[3][0] = fmaf(x3, wv.x, acc[3][0]); acc[3][1] = fmaf(x3, wv.y, acc[3][1]);
            acc[3][2] = fmaf(x3, wv.z, acc[3][2]); acc[3][3] = fmaf(x3, wv.w, acc[3][3]);
        }
        __syncthreads();
    }
    int rr = (t >> 4) << 2, jj = (t & 15) << 2;
    if (j0 + jj < Kout) {
        float4 bv = *(const float4*)&bias[j0 + jj];
#pragma unroll
        for (int i = 0; i < 4; i++) {
            float4 o;
            o.x = acc[i][0] + bv.x; o.y = acc[i][1] + bv.y;
            o.z = acc[i][2] + bv.z; o.w = acc[i][3] + bv.w;
            if (dorelu) {
                o.x = fmaxf(o.x, 0.f); o.y = fmaxf(o.y, 0.f);
                o.z = fmaxf(o.z, 0.f); o.w = fmaxf(o.w, 0.f);
            }
            *(float4*)&Y[(size_t)(n0 + rr + i) * Kout + j0 + jj] = o;
        }
    }
}

// ---------------- e3 = edge_attr @ we3, bf16, PERM ORDER, via MFMA ---------
// grid = E/64 blocks, 256 thr = 4 waves; wave handles 16 edges x 256 ch.
// A (16 edges x 32k) one frag; B staged in LDS as frags; K=32 == one MFMA.
__global__ __launch_bounds__(256) void k_e3gemm(
    const float* __restrict__ ea, const float* __restrict__ we3,
    const int* __restrict__ perm,
    unsigned short* __restrict__ e3p, int E)
{
    __shared__ unsigned short bfrag[16][64][8];   // 16 KB
    int t = threadIdx.x;
    for (int f = t; f < 1024; f += 256) {
        int tile = f >> 6, lane = f & 63;
        int col = tile * 16 + (lane & 15);
        int k0 = (lane >> 4) * 8;
#pragma unroll
        for (int j = 0; j < 8; j++)
            bfrag[tile][lane][j] = f2bf(we3[(size_t)(k0 + j) * 256 + col]);
    }
    __syncthreads();
    int wid = t >> 6, lane = t & 63;
    int g = blockIdx.x * 4 + wid;             // 16-edge group
    int jbase = g * 16;
    int erow = perm[jbase + (lane & 15)];     // original edge id
    int k0 = (lane >> 4) * 8;
    const float* ap = ea + (size_t)erow * 32 + k0;
    float4 a0 = *(const float4*)ap;
    float4 a1 = *(const float4*)(ap + 4);
    short8v af;
    af[0] = (short)f2bf(a0.x); af[1] = (short)f2bf(a0.y);
    af[2] = (short)f2bf(a0.z); af[3] = (short)f2bf(a0.w);
    af[4] = (short)f2bf(a1.x); af[5] = (short)f2bf(a1.y);
    af[6] = (short)f2bf(a1.z); af[7] = (short)f2bf(a1.w);
    int col16 = lane & 15;
    int rbase = (lane >> 4) * 4;
#pragma unroll
    for (int tile = 0; tile < 16; tile++) {
        short8v bf = *(const short8v*)&bfrag[tile][lane][0];
        float4v d = __builtin_amdgcn_mfma_f32_16x16x32_bf16(af, bf, (float4v){0.f,0.f,0.f,0.f}, 0, 0, 0);
        int col = tile * 16 + col16;
#pragma unroll
        for (int r = 0; r < 4; r++)
            e3p[(size_t)(jbase + rbase + r) * 256 + col] = f2bf(d[r]);
    }
}

// ---------------- GINE aggregation -----------------------------------------
__global__ __launch_bounds__(256) void k_gine_agg(
    const float* __restrict__ xin, const float* __restrict__ we,
    const float* __restrict__ be, const float* __restrict__ epsp,
    const float* __restrict__ edge_attr,
    const int* __restrict__ offs, const int* __restrict__ perm,
    const int* __restrict__ sperm,
    float* __restrict__ hout)
{
    int lane = threadIdx.x & 63;
    int wid  = __builtin_amdgcn_readfirstlane(threadIdx.x >> 6);
    int n    = blockIdx.x * 4 + wid;
    float wreg[32];
#pragma unroll
    for (int k = 0; k < 32; k++) wreg[k] = we[k * 64 + lane];
    float bec = be[lane];
    float acc = 0.f;
    int j0 = __builtin_amdgcn_readfirstlane(offs[n]);
    int j1 = __builtin_amdgcn_readfirstlane(offs[n + 1]);
    for (int j = j0; j < j1; j++) {
        int e = __builtin_amdgcn_readfirstlane(perm[j]);
        int s = __builtin_amdgcn_readfirstlane(sperm[j]);
        const float4* ea4 = (const float4*)(edge_attr + (size_t)e * 32);
        float eav[32];
#pragma unroll
        for (int w = 0; w < 8; w++) {
            float4 t4 = ea4[w];
            eav[4 * w] = t4.x; eav[4 * w + 1] = t4.y;
            eav[4 * w + 2] = t4.z; eav[4 * w + 3] = t4.w;
        }
        float ec = bec;
#pragma unroll
        for (int k = 0; k < 32; k++) ec = fmaf(eav[k], wreg[k], ec);
        float v = xin[(size_t)s * 64 + lane] + ec;
        acc += fmaxf(v, 0.f);
    }
    float eps = epsp[0];
    hout[(size_t)n * 64 + lane] = (1.f + eps) * xin[(size_t)n * 64 + lane] + acc;
}

// ---------------- TransformerConv aggregation (e3 materialized) ------------
__global__ __launch_bounds__(256) void k_tconv(
    const float* __restrict__ qb, const float* __restrict__ kb,
    const float* __restrict__ vb, const unsigned short* __restrict__ e3p,
    const int* __restrict__ offs, const int* __restrict__ sperm,
    float* __restrict__ skip_io)
{
    int n  = blockIdx.x;
    int ch = threadIdx.x;
    float qc = qb[(size_t)n * 256 + ch];
    float l = 0.f, acc = 0.f;
    int j0 = __builtin_amdgcn_readfirstlane(offs[n]);
    int j1 = __builtin_amdgcn_readfirstlane(offs[n + 1]);
    for (int j = j0; j < j1; j++) {
        int s = __builtin_amdgcn_readfirstlane(sperm[j]);
        float e3f = bf2f(e3p[(size_t)j * 256 + ch]);
        float kv = kb[(size_t)s * 256 + ch] + e3f;
        float p = qc * kv;
#pragma unroll
        for (int o = 32; o > 0; o >>= 1) p += __shfl_xor(p, o);
        float w  = __expf(p * 0.125f);      // logits O(0.5): no-max softmax exact
        float vv = vb[(size_t)s * 256 + ch] + e3f;
        l += w;
        acc = fmaf(w, vv, acc);
    }
    float out = acc / (l + 1e-16f) + skip_io[(size_t)n * 256 + ch];
    skip_io[(size_t)n * 256 + ch] = out;
}

// ---------------- TransformerConv fallback (recompute e3) ------------------
__global__ __launch_bounds__(256) void k_tconv_rec(
    const float* __restrict__ qb, const float* __restrict__ kb,
    const float* __restrict__ vb, const float* __restrict__ we3,
    const float* __restrict__ edge_attr,
    const int* __restrict__ offs, const int* __restrict__ perm,
    const int* __restrict__ sperm,
    float* __restrict__ skip_io)
{
    int n  = blockIdx.x;
    int ch = threadIdx.x;
    float wreg[32];
#pragma unroll
    for (int k = 0; k < 32; k++) wreg[k] = we3[k * 256 + ch];
    float qc = qb[(size_t)n * 256 + ch];
    float l = 0.f, acc = 0.f;
    int j0 = __builtin_amdgcn_readfirstlane(offs[n]);
    int j1 = __builtin_amdgcn_readfirstlane(offs[n + 1]);
    for (int j = j0; j < j1; j++) {
        int e = __builtin_amdgcn_readfirstlane(perm[j]);
        int s = __builtin_amdgcn_readfirstlane(sperm[j]);
        const float4* ea4 = (const float4*)(edge_attr + (size_t)e * 32);
        float eav[32];
#pragma unroll
        for (int w = 0; w < 8; w++) {
            float4 t4 = ea4[w];
            eav[4 * w] = t4.x; eav[4 * w + 1] = t4.y;
            eav[4 * w + 2] = t4.z; eav[4 * w + 3] = t4.w;
        }
        float ec = 0.f;
#pragma unroll
        for (int k = 0; k < 32; k++) ec = fmaf(eav[k], wreg[k], ec);
        float kv = kb[(size_t)s * 256 + ch] + ec;
        float p = qc * kv;
#pragma unroll
        for (int o = 32; o > 0; o >>= 1) p += __shfl_xor(p, o);
        float w  = __expf(p * 0.125f);
        float vv = vb[(size_t)s * 256 + ch] + ec;
        l += w;
        acc = fmaf(w, vv, acc);
    }
    float out = acc / (l + 1e-16f) + skip_io[(size_t)n * 256 + ch];
    skip_io[(size_t)n * 256 + ch] = out;
}

// ---------------- GATv2 aggregation ----------------------------------------
__global__ __launch_bounds__(256) void k_gat(
    const float* __restrict__ xl, const float* __restrict__ xr,
    const float* __restrict__ we4, const float* __restrict__ attv,
    const float* __restrict__ bias4,
    const float* __restrict__ edge_attr,
    const int* __restrict__ offs, const int* __restrict__ perm,
    const int* __restrict__ sperm,
    float* __restrict__ out)
{
    int lane = threadIdx.x & 63;
    int wid  = __builtin_amdgcn_readfirstlane(threadIdx.x >> 6);
    int n    = blockIdx.x * 4 + wid;
    float wreg[32];
#pragma unroll
    for (int k = 0; k < 32; k++) wreg[k] = we4[k * 64 + lane];
    float attc = attv[lane];
    float xrc  = xr[(size_t)n * 64 + lane];
    float l = 0.f, acc = 0.f;
    int j0 = __builtin_amdgcn_readfirstlane(offs[n]);
    int j1 = __builtin_amdgcn_readfirstlane(offs[n + 1]);
    for (int j = j0; j < j1; j++) {
        int e = __builtin_amdgcn_readfirstlane(perm[j]);
        int s = __builtin_amdgcn_readfirstlane(sperm[j]);
        const float4* ea4 = (const float4*)(edge_attr + (size_t)e * 32);
        float eav[32];
#pragma unroll
        for (int w = 0; w < 8; w++) {
            float4 t4 = ea4[w];
            eav[4 * w] = t4.x; eav[4 * w + 1] = t4.y;
            eav[4 * w + 2] = t4.z; eav[4 * w + 3] = t4.w;
        }
        float ec = 0.f;
#pragma unroll
        for (int k = 0; k < 32; k++) ec = fmaf(eav[k], wreg[k], ec);
        float xls = xl[(size_t)s * 64 + lane];
        float hm = xls + xrc + ec;
        hm = (hm > 0.f) ? hm : 0.2f * hm;
        float p = hm * attc;
#pragma unroll
        for (int o = 32; o > 0; o >>= 1) p += __shfl_xor(p, o);
        float w = __expf(p);               // logits O(0.5): no-max exact
        l += w;
        acc = fmaf(w, xls, acc);
    }
    out[(size_t)n * 64 + lane] = acc / (l + 1e-16f) + bias4[lane];
}

// ---------------------------------------------------------------------------
extern "C" void kernel_launch(void* const* d_in, const int* in_sizes, int n_in,
                              void* d_out, int out_size, void* d_ws, size_t ws_size,
                              hipStream_t stream)
{
    const float* x     = (const float*)d_in[0];
    const float* ea    = (const float*)d_in[1];
    const float* eps1  = (const float*)d_in[2];
    const float* w1a   = (const float*)d_in[3];
    const float* b1a   = (const float*)d_in[4];
    const float* w1b   = (const float*)d_in[5];
    const float* b1b   = (const float*)d_in[6];
    const float* we1   = (const float*)d_in[7];
    const float* be1   = (const float*)d_in[8];
    const float* eps2  = (const float*)d_in[9];
    const float* w2a   = (const float*)d_in[10];
    const float* b2a   = (const float*)d_in[11];
    const float* w2b   = (const float*)d_in[12];
    const float* b2b   = (const float*)d_in[13];
    const float* we2   = (const float*)d_in[14];
    const float* be2   = (const float*)d_in[15];
    const float* wq    = (const float*)d_in[16];
    const float* bq    = (const float*)d_in[17];
    const float* wk    = (const float*)d_in[18];
    const float* bk    = (const float*)d_in[19];
    const float* wv    = (const float*)d_in[20];
    const float* bv    = (const float*)d_in[21];
    const float* we3   = (const float*)d_in[22];
    const float* wskip = (const float*)d_in[23];
    const float* bskip = (const float*)d_in[24];
    const float* wl    = (const float*)d_in[25];
    const float* bl    = (const float*)d_in[26];
    const float* wr    = (const float*)d_in[27];
    const float* br    = (const float*)d_in[28];
    const float* we4   = (const float*)d_in[29];
    const float* attv  = (const float*)d_in[30];
    const float* bias4 = (const float*)d_in[31];
    const void*  eidx  = d_in[32];

    const int N = in_sizes[0] / 64;     // 32768
    const int E = in_sizes[1] / 32;     // 524288

    char* ws = (char*)d_ws;
    size_t off = 0;
    auto alloc = [&](size_t bytes) {
        void* p = ws + off;
        off += (bytes + 255) & ~(size_t)255;
        return p;
    };
    int* flag    = (int*)alloc(4);
    int* econv   = (int*)alloc((size_t)2 * E * 4);
    int* counts  = (int*)alloc((size_t)N * 4);
    int* cursor  = (int*)alloc((size_t)N * 4);
    int* offs    = (int*)alloc((size_t)(N + 1) * 4);
    int* perm    = (int*)alloc((size_t)E * 4);
    int* sperm   = (int*)alloc((size_t)E * 4);
    float* h     = (float*)alloc((size_t)N * 64 * 4);
    float* t1    = (float*)alloc((size_t)N * 64 * 4);
    float* x1    = (float*)alloc((size_t)N * 64 * 4);
    float* x2    = (float*)alloc((size_t)N * 64 * 4);
    float* qb    = (float*)alloc((size_t)N * 256 * 4);
    float* kb    = (float*)alloc((size_t)N * 256 * 4);
    float* vb    = (float*)alloc((size_t)N * 256 * 4);
    float* skipb = (float*)alloc((size_t)N * 256 * 4);
    float* xlb   = h;    // dead by then, reuse
    float* xrb   = t1;   // dead by then, reuse
    size_t base_off = off;
    unsigned short* e3p = (unsigned short*)alloc((size_t)E * 256 * 2);
    int use_e3 = (off <= ws_size) ? 1 : 0;

    if (base_off > ws_size) return;   // catastrophic: visible failure

    // edge_index dtype detect + convert to int32
    k_detect<<<1, 256, 0, stream>>>((const unsigned int*)eidx, flag);
    k_cvt<<<(2 * E + 255) / 256, 256, 0, stream>>>(eidx, flag, econv, 2 * E);
    const int* srcI = econv;
    const int* dstI = econv + E;

    // CSR by dst (+ sperm = src in perm order)
    hipMemsetAsync(counts, 0, (size_t)N * 4, stream);
    k_hist<<<(E + 255) / 256, 256, 0, stream>>>(dstI, counts, E);
    k_scan<<<1, 1024, 0, stream>>>(counts, offs, cursor, N);
    k_scatter<<<(E + 255) / 256, 256, 0, stream>>>(dstI, srcI, cursor, perm, sperm, E);

    // GINE 1
    k_gine_agg<<<N / 4, 256, 0, stream>>>(x, we1, be1, eps1, ea, offs, perm, sperm, h);
    k_gemm<<<dim3(N / 64, 1), 256, 0, stream>>>(h, 64, w1a, b1a, t1, 64, 1);
    k_gemm<<<dim3(N / 64, 1), 256, 0, stream>>>(t1, 64, w1b, b1b, x1, 64, 0);

    // GINE 2
    k_gine_agg<<<N / 4, 256, 0, stream>>>(x1, we2, be2, eps2, ea, offs, perm, sperm, h);
    k_gemm<<<dim3(N / 64, 1), 256, 0, stream>>>(h, 64, w2a, b2a, t1, 32, 1);
    k_gemm<<<dim3(N / 64, 1), 256, 0, stream>>>(t1, 32, w2b, b2b, x2, 64, 0);

    // TransformerConv
    k_gemm<<<dim3(N / 64, 4), 256, 0, stream>>>(x2, 64, wq, bq, qb, 256, 0);
    k_gemm<<<dim3(N / 64, 4), 256, 0, stream>>>(x2, 64, wk, bk, kb, 256, 0);
    k_gemm<<<dim3(N / 64, 4), 256, 0, stream>>>(x2, 64, wv, bv, vb, 256, 0);
    k_gemm<<<dim3(N / 64, 4), 256, 0, stream>>>(x2, 64, wskip, bskip, skipb, 256, 0);
    if (use_e3) {
        k_e3gemm<<<E / 64, 256, 0, stream>>>(ea, we3, perm, e3p, E);
        k_tconv<<<N, 256, 0, stream>>>(qb, kb, vb, e3p, offs, sperm, skipb);
    } else {
        k_tconv_rec<<<N, 256, 0, stream>>>(qb, kb, vb, we3, ea, offs, perm, sperm, skipb);
    }

    // GATv2
    k_gemm<<<dim3(N / 64, 1), 256, 0, stream>>>(skipb, 256, wl, bl, xlb, 64, 0);
    k_gemm<<<dim3(N / 64, 1), 256, 0, stream>>>(skipb, 256, wr, br, xrb, 64, 0);
    k_gat<<<N / 4, 256, 0, stream>>>(xlb, xrb, we4, attv, bias4, ea, offs, perm, sperm,
                                     (float*)d_out);
}

// Round 3
// 823.534 us; speedup vs baseline: 1.1385x; 1.0670x over previous
//
#include <hip/hip_runtime.h>
#include <math.h>

// ---------------------------------------------------------------------------
// N=32768 nodes, E=524288 edges, node feat 64, edge feat 32, H=4 x C=64 = 256.
// ---------------------------------------------------------------------------

static __device__ __forceinline__ unsigned short f2bf(float f)
{
    unsigned int u = __float_as_uint(f);
    unsigned int r = (u + 0x7FFFu + ((u >> 16) & 1u)) >> 16;
    return (unsigned short)r;
}
static __device__ __forceinline__ float bf2f(unsigned short b)
{
    return __uint_as_float((unsigned int)b << 16);
}

// ---------------- edge_index dtype detection + convert ---------------------
__global__ void k_detect(const unsigned int* __restrict__ w, int* __restrict__ flag)
{
    __shared__ int any;
    if (threadIdx.x == 0) any = 0;
    __syncthreads();
    int found = 0;
    for (int i = threadIdx.x; i < 2048; i += 256)
        if (w[2 * i + 1] != 0u) found = 1;
    if (found) atomicOr(&any, 1);
    __syncthreads();
    if (threadIdx.x == 0) flag[0] = any ? 0 : 1;   // 1 => int64
}

__global__ void k_cvt(const void* __restrict__ eidx, const int* __restrict__ flag,
                      int* __restrict__ out, int n)
{
    int i = blockIdx.x * blockDim.x + threadIdx.x;
    if (i >= n) return;
    if (flag[0])
        out[i] = (int)((const long long*)eidx)[i];
    else
        out[i] = ((const int*)eidx)[i];
}

// ---------------- CSR build (group edges by dst) ---------------------------
__global__ void k_hist(const int* __restrict__ dst, int* __restrict__ counts, int E)
{
    int i = blockIdx.x * blockDim.x + threadIdx.x;
    if (i < E) atomicAdd(&counts[dst[i]], 1);
}

__global__ void k_scan(const int* __restrict__ counts, int* __restrict__ offs,
                       int* __restrict__ cursor, int N)
{
    __shared__ int part[1024];
    int t = threadIdx.x;
    int base = t * 32;
    int loc[32];
    int s = 0;
#pragma unroll
    for (int i = 0; i < 32; i++) { loc[i] = counts[base + i]; s += loc[i]; }
    part[t] = s;
    __syncthreads();
    for (int off = 1; off < 1024; off <<= 1) {
        int v = (t >= off) ? part[t - off] : 0;
        __syncthreads();
        part[t] += v;
        __syncthreads();
    }
    int run = part[t] - s;   // exclusive prefix
#pragma unroll
    for (int i = 0; i < 32; i++) {
        offs[base + i] = run;
        cursor[base + i] = run;
        run += loc[i];
    }
    if (t == 1023) offs[N] = run;
}

__global__ void k_scatter(const int* __restrict__ dst, const int* __restrict__ srcA,
                          int* __restrict__ cursor, int* __restrict__ perm,
                          int* __restrict__ sperm, int E)
{
    int i = blockIdx.x * blockDim.x + threadIdx.x;
    if (i < E) {
        int d = dst[i];
        int p = atomicAdd(&cursor[d], 1);
        perm[p] = i;
        sperm[p] = srcA[i];
    }
}

// ---------------- generic small GEMM: Y = [relu](X @ W + b) ----------------
__global__ __launch_bounds__(256) void k_gemm(
    const float* __restrict__ X, int Kdim,
    const float* __restrict__ W, const float* __restrict__ bias,
    float* __restrict__ Y, int Kout, int dorelu)
{
    __shared__ float Xs[64][68];
    __shared__ float Ws[64][68];
    int n0 = blockIdx.x * 64;
    int j0 = blockIdx.y * 64;
    int t  = threadIdx.x;
    float acc[4][4] = {};
    for (int kk = 0; kk < Kdim; kk += 64) {
        for (int f = t; f < 4096; f += 256) {
            int r = f >> 6, c = f & 63;
            Xs[r][c] = (kk + c < Kdim) ? X[(size_t)(n0 + r) * Kdim + kk + c] : 0.f;
        }
        for (int f = t; f < 4096; f += 256) {
            int k = f >> 6, j = f & 63;
            Ws[k][j] = (kk + k < Kdim && j0 + j < Kout)
                           ? W[(size_t)(kk + k) * Kout + j0 + j] : 0.f;
        }
        __syncthreads();
        int rr = (t >> 4) << 2, jj = (t & 15) << 2;
#pragma unroll 8
        for (int k = 0; k < 64; k++) {
            float4 wv = *(const float4*)&Ws[k][jj];
            float x0 = Xs[rr + 0][k], x1 = Xs[rr + 1][k];
            float x2 = Xs[rr + 2][k], x3 = Xs[rr + 3][k];
            acc[0][0] = fmaf(x0, wv.x, acc[0][0]); acc[0][1] = fmaf(x0, wv.y, acc[0][1]);
            acc[0][2] = fmaf(x0, wv.z, acc[0][2]); acc[0][3] = fmaf(x0, wv.w, acc[0][3]);
            acc[1][0] = fmaf(x1, wv.x, acc[1][0]); acc[1][1] = fmaf(x1, wv.y, acc[1][1]);
            acc[1][2] = fmaf(x1, wv.z, acc[1][2]); acc[1][3] = fmaf(x1, wv.w, acc[1][3]);
            acc[2][0] = fmaf(x2, wv.x, acc[2][0]); acc[2][1] = fmaf(x2, wv.y, acc[2][1]);
            acc[2][2] = fmaf(x2, wv.z, acc[2][2]); acc[2][3] = fmaf(x2, wv.w, acc[2][3]);
            acc[3][0] = fmaf(x3, wv.x, acc[3][0]); acc[3][1] = fmaf(x3, wv.y, acc[3][1]);
            acc[3][2] = fmaf(x3, wv.z, acc[3][2]); acc[3][3] = fmaf(x3, wv.w, acc[3][3]);
        }
        __syncthreads();
    }
    int rr = (t >> 4) << 2, jj = (t & 15) << 2;
    if (j0 + jj < Kout) {
        float4 bv = *(const float4*)&bias[j0 + jj];
#pragma unroll
        for (int i = 0; i < 4; i++) {
            float4 o;
            o.x = acc[i][0] + bv.x; o.y = acc[i][1] + bv.y;
            o.z = acc[i][2] + bv.z; o.w = acc[i][3] + bv.w;
            if (dorelu) {
                o.x = fmaxf(o.x, 0.f); o.y = fmaxf(o.y, 0.f);
                o.z = fmaxf(o.z, 0.f); o.w = fmaxf(o.w, 0.f);
            }
            *(float4*)&Y[(size_t)(n0 + rr + i) * Kout + j0 + jj] = o;
        }
    }
}

// ---------------- fused Q/K/V/skip GEMM (Kdim=64, Kout=256 each) -----------
// grid (N/64, 16): blockIdx.y>>2 selects which of the 4 projections,
// (blockIdx.y&3)*64 is the column tile. Shares k_gemm's inner structure.
__global__ __launch_bounds__(256) void k_gemm4(
    const float* __restrict__ X,
    const float* __restrict__ W0, const float* __restrict__ B0, float* __restrict__ Y0,
    const float* __restrict__ W1, const float* __restrict__ B1, float* __restrict__ Y1,
    const float* __restrict__ W2, const float* __restrict__ B2, float* __restrict__ Y2,
    const float* __restrict__ W3, const float* __restrict__ B3, float* __restrict__ Y3)
{
    __shared__ float Xs[64][68];
    __shared__ float Ws[64][68];
    int which = blockIdx.y >> 2;
    const float* W = (which == 0) ? W0 : (which == 1) ? W1 : (which == 2) ? W2 : W3;
    const float* B = (which == 0) ? B0 : (which == 1) ? B1 : (which == 2) ? B2 : B3;
    float* Y       = (which == 0) ? Y0 : (which == 1) ? Y1 : (which == 2) ? Y2 : Y3;
    int n0 = blockIdx.x * 64;
    int j0 = (blockIdx.y & 3) * 64;
    int t  = threadIdx.x;
    float acc[4][4] = {};
    for (int f = t; f < 4096; f += 256) {
        int r = f >> 6, c = f & 63;
        Xs[r][c] = X[(size_t)(n0 + r) * 64 + c];
    }
    for (int f = t; f < 4096; f += 256) {
        int k = f >> 6, j = f & 63;
        Ws[k][j] = W[(size_t)k * 256 + j0 + j];
    }
    __syncthreads();
    int rr = (t >> 4) << 2, jj = (t & 15) << 2;
#pragma unroll 8
    for (int k = 0; k < 64; k++) {
        float4 wv = *(const float4*)&Ws[k][jj];
        float x0 = Xs[rr + 0][k], x1 = Xs[rr + 1][k];
        float x2 = Xs[rr + 2][k], x3 = Xs[rr + 3][k];
        acc[0][0] = fmaf(x0, wv.x, acc[0][0]); acc[0][1] = fmaf(x0, wv.y, acc[0][1]);
        acc[0][2] = fmaf(x0, wv.z, acc[0][2]); acc[0][3] = fmaf(x0, wv.w, acc[0][3]);
        acc[1][0] = fmaf(x1, wv.x, acc[1][0]); acc[1][1] = fmaf(x1, wv.y, acc[1][1]);
        acc[1][2] = fmaf(x1, wv.z, acc[1][2]); acc[1][3] = fmaf(x1, wv.w, acc[1][3]);
        acc[2][0] = fmaf(x2, wv.x, acc[2][0]); acc[2][1] = fmaf(x2, wv.y, acc[2][1]);
        acc[2][2] = fmaf(x2, wv.z, acc[2][2]); acc[2][3] = fmaf(x2, wv.w, acc[2][3]);
        acc[3][0] = fmaf(x3, wv.x, acc[3][0]); acc[3][1] = fmaf(x3, wv.y, acc[3][1]);
        acc[3][2] = fmaf(x3, wv.z, acc[3][2]); acc[3][3] = fmaf(x3, wv.w, acc[3][3]);
    }
    float4 bv = *(const float4*)&B[j0 + jj];
#pragma unroll
    for (int i = 0; i < 4; i++) {
        float4 o;
        o.x = acc[i][0] + bv.x; o.y = acc[i][1] + bv.y;
        o.z = acc[i][2] + bv.z; o.w = acc[i][3] + bv.w;
        *(float4*)&Y[(size_t)(n0 + rr + i) * 256 + j0 + jj] = o;
    }
}

// ---------------- qt precompute: qt[n,h*32+k] = 0.125*sum_c q[n,h,c]we3[k,h64+c]
// grid N/32 blocks x 256 thr. we3 staged in LDS (padded vs bank conflicts).
__global__ __launch_bounds__(256) void k_qt(
    const float* __restrict__ qb, const float* __restrict__ we3,
    unsigned short* __restrict__ qtp, int N)
{
    __shared__ float we3s[32][257];
    __shared__ float qrow[256];
    int t = threadIdx.x;
    for (int f = t; f < 8192; f += 256)
        we3s[f >> 8][f & 255] = we3[f];
    int n0 = blockIdx.x * 32;
    int h = t >> 5, k = t & 31;          // valid for t<128
    for (int i = 0; i < 32; i++) {
        int n = n0 + i;
        __syncthreads();
        qrow[t] = qb[(size_t)n * 256 + t];
        __syncthreads();
        if (t < 128) {
            float s = 0.f;
#pragma unroll
            for (int c = 0; c < 64; c++)
                s = fmaf(qrow[h * 64 + c], we3s[k][h * 64 + c], s);
            qtp[(size_t)n * 128 + t] = f2bf(s * 0.125f);
        }
    }
}

// ---------------- GINE aggregation -----------------------------------------
__global__ __launch_bounds__(256) void k_gine_agg(
    const float* __restrict__ xin, const float* __restrict__ we,
    const float* __restrict__ be, const float* __restrict__ epsp,
    const float* __restrict__ edge_attr,
    const int* __restrict__ offs, const int* __restrict__ perm,
    const int* __restrict__ sperm,
    float* __restrict__ hout)
{
    int lane = threadIdx.x & 63;
    int wid  = __builtin_amdgcn_readfirstlane(threadIdx.x >> 6);
    int n    = blockIdx.x * 4 + wid;
    float wreg[32];
#pragma unroll
    for (int k = 0; k < 32; k++) wreg[k] = we[k * 64 + lane];
    float bec = be[lane];
    float acc = 0.f;
    int j0 = __builtin_amdgcn_readfirstlane(offs[n]);
    int j1 = __builtin_amdgcn_readfirstlane(offs[n + 1]);
    for (int j = j0; j < j1; j++) {
        int e = __builtin_amdgcn_readfirstlane(perm[j]);
        int s = __builtin_amdgcn_readfirstlane(sperm[j]);
        const float4* ea4 = (const float4*)(edge_attr + (size_t)e * 32);
        float eav[32];
#pragma unroll
        for (int w = 0; w < 8; w++) {
            float4 t4 = ea4[w];
            eav[4 * w] = t4.x; eav[4 * w + 1] = t4.y;
            eav[4 * w + 2] = t4.z; eav[4 * w + 3] = t4.w;
        }
        float ec = bec;
#pragma unroll
        for (int k = 0; k < 32; k++) ec = fmaf(eav[k], wreg[k], ec);
        float v = xin[(size_t)s * 64 + lane] + ec;
        acc += fmaxf(v, 0.f);
    }
    float eps = epsp[0];
    hout[(size_t)n * 64 + lane] = (1.f + eps) * xin[(size_t)n * 64 + lane] + acc;
}

// ---------------- TransformerConv, e3-decomposed ---------------------------
// block = dst node (256 thr); wave = head; lane = channel.
// logit = q·k[src]*0.125 + qt[dst]·ea_e  (qt pre-scaled by 0.125)
// out   = (sum w*v[src] + (sum w*ea_e)@we3)/l + skip
__global__ __launch_bounds__(256) void k_tconv2(
    const float* __restrict__ qb, const float* __restrict__ kb,
    const float* __restrict__ vb, const unsigned short* __restrict__ qtp,
    const float* __restrict__ we3, const float* __restrict__ ea,
    const int* __restrict__ offs, const int* __restrict__ perm,
    const int* __restrict__ sperm,
    float* __restrict__ skip_io)
{
    __shared__ float wa_s[128];
    int n    = blockIdx.x;
    int ch   = threadIdx.x;            // h*64 + c
    int lane = ch & 63;
    int h    = ch >> 6;
    float qc  = qb[(size_t)n * 256 + ch] * 0.125f;
    float qtc = (lane < 32) ? bf2f(qtp[(size_t)n * 128 + h * 32 + lane]) : 0.f;
    float l = 0.f, acc = 0.f, wa = 0.f;
    int j0 = __builtin_amdgcn_readfirstlane(offs[n]);
    int j1 = __builtin_amdgcn_readfirstlane(offs[n + 1]);
    for (int j = j0; j < j1; j++) {
        int e = __builtin_amdgcn_readfirstlane(perm[j]);
        int s = __builtin_amdgcn_readfirstlane(sperm[j]);
        float eac = (lane < 32) ? ea[(size_t)e * 32 + lane] : 0.f;
        float kv  = kb[(size_t)s * 256 + ch];
        float p   = fmaf(qc, kv, qtc * eac);
#pragma unroll
        for (int o = 32; o > 0; o >>= 1) p += __shfl_xor(p, o);
        float w = __expf(p);               // logits O(0.5): no-max exact
        l += w;
        acc = fmaf(w, vb[(size_t)s * 256 + ch], acc);
        wa  = fmaf(w, eac, wa);
    }
    if (lane < 32) wa_s[h * 32 + lane] = wa;
    __syncthreads();
    float corr = 0.f;
#pragma unroll
    for (int k = 0; k < 32; k++)
        corr = fmaf(wa_s[h * 32 + k], we3[k * 256 + ch], corr);
    float out = (acc + corr) / (l + 1e-16f) + skip_io[(size_t)n * 256 + ch];
    skip_io[(size_t)n * 256 + ch] = out;
}

// ---------------- GATv2 aggregation ----------------------------------------
__global__ __launch_bounds__(256) void k_gat(
    const float* __restrict__ xl, const float* __restrict__ xr,
    const float* __restrict__ we4, const float* __restrict__ attv,
    const float* __restrict__ bias4,
    const float* __restrict__ edge_attr,
    const int* __restrict__ offs, const int* __restrict__ perm,
    const int* __restrict__ sperm,
    float* __restrict__ out)
{
    int lane = threadIdx.x & 63;
    int wid  = __builtin_amdgcn_readfirstlane(threadIdx.x >> 6);
    int n    = blockIdx.x * 4 + wid;
    float wreg[32];
#pragma unroll
    for (int k = 0; k < 32; k++) wreg[k] = we4[k * 64 + lane];
    float attc = attv[lane];
    float xrc  = xr[(size_t)n * 64 + lane];
    float l = 0.f, acc = 0.f;
    int j0 = __builtin_amdgcn_readfirstlane(offs[n]);
    int j1 = __builtin_amdgcn_readfirstlane(offs[n + 1]);
    for (int j = j0; j < j1; j++) {
        int e = __builtin_amdgcn_readfirstlane(perm[j]);
        int s = __builtin_amdgcn_readfirstlane(sperm[j]);
        const float4* ea4 = (const float4*)(edge_attr + (size_t)e * 32);
        float eav[32];
#pragma unroll
        for (int w = 0; w < 8; w++) {
            float4 t4 = ea4[w];
            eav[4 * w] = t4.x; eav[4 * w + 1] = t4.y;
            eav[4 * w + 2] = t4.z; eav[4 * w + 3] = t4.w;
        }
        float ec = 0.f;
#pragma unroll
        for (int k = 0; k < 32; k++) ec = fmaf(eav[k], wreg[k], ec);
        float xls = xl[(size_t)s * 64 + lane];
        float hm = xls + xrc + ec;
        hm = (hm > 0.f) ? hm : 0.2f * hm;
        float p = hm * attc;
#pragma unroll
        for (int o = 32; o > 0; o >>= 1) p += __shfl_xor(p, o);
        float w = __expf(p);               // logits O(0.5): no-max exact
        l += w;
        acc = fmaf(w, xls, acc);
    }
    out[(size_t)n * 64 + lane] = acc / (l + 1e-16f) + bias4[lane];
}

// ---------------------------------------------------------------------------
extern "C" void kernel_launch(void* const* d_in, const int* in_sizes, int n_in,
                              void* d_out, int out_size, void* d_ws, size_t ws_size,
                              hipStream_t stream)
{
    const float* x     = (const float*)d_in[0];
    const float* ea    = (const float*)d_in[1];
    const float* eps1  = (const float*)d_in[2];
    const float* w1a   = (const float*)d_in[3];
    const float* b1a   = (const float*)d_in[4];
    const float* w1b   = (const float*)d_in[5];
    const float* b1b   = (const float*)d_in[6];
    const float* we1   = (const float*)d_in[7];
    const float* be1   = (const float*)d_in[8];
    const float* eps2  = (const float*)d_in[9];
    const float* w2a   = (const float*)d_in[10];
    const float* b2a   = (const float*)d_in[11];
    const float* w2b   = (const float*)d_in[12];
    const float* b2b   = (const float*)d_in[13];
    const float* we2   = (const float*)d_in[14];
    const float* be2   = (const float*)d_in[15];
    const float* wq    = (const float*)d_in[16];
    const float* bq    = (const float*)d_in[17];
    const float* wk    = (const float*)d_in[18];
    const float* bk    = (const float*)d_in[19];
    const float* wv    = (const float*)d_in[20];
    const float* bv    = (const float*)d_in[21];
    const float* we3   = (const float*)d_in[22];
    const float* wskip = (const float*)d_in[23];
    const float* bskip = (const float*)d_in[24];
    const float* wl    = (const float*)d_in[25];
    const float* bl    = (const float*)d_in[26];
    const float* wr    = (const float*)d_in[27];
    const float* br    = (const float*)d_in[28];
    const float* we4   = (const float*)d_in[29];
    const float* attv  = (const float*)d_in[30];
    const float* bias4 = (const float*)d_in[31];
    const void*  eidx  = d_in[32];

    const int N = in_sizes[0] / 64;     // 32768
    const int E = in_sizes[1] / 32;     // 524288

    char* ws = (char*)d_ws;
    size_t off = 0;
    auto alloc = [&](size_t bytes) {
        void* p = ws + off;
        off += (bytes + 255) & ~(size_t)255;
        return p;
    };
    int* flag    = (int*)alloc(4);
    int* econv   = (int*)alloc((size_t)2 * E * 4);
    int* counts  = (int*)alloc((size_t)N * 4);
    int* cursor  = (int*)alloc((size_t)N * 4);
    int* offs    = (int*)alloc((size_t)(N + 1) * 4);
    int* perm    = (int*)alloc((size_t)E * 4);
    int* sperm   = (int*)alloc((size_t)E * 4);
    float* h     = (float*)alloc((size_t)N * 64 * 4);
    float* t1    = (float*)alloc((size_t)N * 64 * 4);
    float* x1    = (float*)alloc((size_t)N * 64 * 4);
    float* x2    = (float*)alloc((size_t)N * 64 * 4);
    float* qb    = (float*)alloc((size_t)N * 256 * 4);
    float* kb    = (float*)alloc((size_t)N * 256 * 4);
    float* vb    = (float*)alloc((size_t)N * 256 * 4);
    float* skipb = (float*)alloc((size_t)N * 256 * 4);
    float* xlb   = h;                              // dead by then, reuse
    float* xrb   = t1;                             // dead by then, reuse
    unsigned short* qtp = (unsigned short*)x1;     // x1 dead after x2; N*128*2 == N*64*4

    if (off > ws_size) return;   // workspace too small -> visible failure

    // edge_index dtype detect + convert to int32
    k_detect<<<1, 256, 0, stream>>>((const unsigned int*)eidx, flag);
    k_cvt<<<(2 * E + 255) / 256, 256, 0, stream>>>(eidx, flag, econv, 2 * E);
    const int* srcI = econv;
    const int* dstI = econv + E;

    // CSR by dst (+ sperm = src in perm order)
    hipMemsetAsync(counts, 0, (size_t)N * 4, stream);
    k_hist<<<(E + 255) / 256, 256, 0, stream>>>(dstI, counts, E);
    k_scan<<<1, 1024, 0, stream>>>(counts, offs, cursor, N);
    k_scatter<<<(E + 255) / 256, 256, 0, stream>>>(dstI, srcI, cursor, perm, sperm, E);

    // GINE 1
    k_gine_agg<<<N / 4, 256, 0, stream>>>(x, we1, be1, eps1, ea, offs, perm, sperm, h);
    k_gemm<<<dim3(N / 64, 1), 256, 0, stream>>>(h, 64, w1a, b1a, t1, 64, 1);
    k_gemm<<<dim3(N / 64, 1), 256, 0, stream>>>(t1, 64, w1b, b1b, x1, 64, 0);

    // GINE 2
    k_gine_agg<<<N / 4, 256, 0, stream>>>(x1, we2, be2, eps2, ea, offs, perm, sperm, h);
    k_gemm<<<dim3(N / 64, 1), 256, 0, stream>>>(h, 64, w2a, b2a, t1, 32, 1);
    k_gemm<<<dim3(N / 64, 1), 256, 0, stream>>>(t1, 32, w2b, b2b, x2, 64, 0);

    // TransformerConv (x1 dead from here; reused as qtp)
    k_gemm4<<<dim3(N / 64, 16), 256, 0, stream>>>(x2,
                                                  wq, bq, qb, wk, bk, kb,
                                                  wv, bv, vb, wskip, bskip, skipb);
    k_qt<<<N / 32, 256, 0, stream>>>(qb, we3, qtp, N);
    k_tconv2<<<N, 256, 0, stream>>>(qb, kb, vb, qtp, we3, ea, offs, perm, sperm, skipb);

    // GATv2
    k_gemm<<<dim3(N / 64, 1), 256, 0, stream>>>(skipb, 256, wl, bl, xlb, 64, 0);
    k_gemm<<<dim3(N / 64, 1), 256, 0, stream>>>(skipb, 256, wr, br, xrb, 64, 0);
    k_gat<<<N / 4, 256, 0, stream>>>(xlb, xrb, we4, attv, bias4, ea, offs, perm, sperm,
                                     (float*)d_out);
}

// Round 4
// 744.750 us; speedup vs baseline: 1.2589x; 1.1058x over previous
//
#include <hip/hip_runtime.h>
#include <math.h>

// ---------------------------------------------------------------------------
// N=32768 nodes, E=524288 edges, node feat 64, edge feat 32, H=4 x C=64 = 256.
// ---------------------------------------------------------------------------

typedef __attribute__((ext_vector_type(2))) _Float16 half2v;
typedef __attribute__((ext_vector_type(4))) _Float16 half4v;

// ---------------- edge_index dtype detection + convert ---------------------
__global__ void k_detect(const unsigned int* __restrict__ w, int* __restrict__ flag)
{
    __shared__ int any;
    if (threadIdx.x == 0) any = 0;
    __syncthreads();
    int found = 0;
    for (int i = threadIdx.x; i < 2048; i += 256)
        if (w[2 * i + 1] != 0u) found = 1;
    if (found) atomicOr(&any, 1);
    __syncthreads();
    if (threadIdx.x == 0) flag[0] = any ? 0 : 1;   // 1 => int64
}

__global__ void k_cvt(const void* __restrict__ eidx, const int* __restrict__ flag,
                      int* __restrict__ out, int n)
{
    int i = blockIdx.x * blockDim.x + threadIdx.x;
    if (i >= n) return;
    if (flag[0])
        out[i] = (int)((const long long*)eidx)[i];
    else
        out[i] = ((const int*)eidx)[i];
}

// ---------------- CSR build (group edges by dst) ---------------------------
__global__ void k_hist(const int* __restrict__ dst, int* __restrict__ counts, int E)
{
    int i = blockIdx.x * blockDim.x + threadIdx.x;
    if (i < E) atomicAdd(&counts[dst[i]], 1);
}

__global__ void k_scan(const int* __restrict__ counts, int* __restrict__ offs,
                       int* __restrict__ cursor, int N)
{
    __shared__ int part[1024];
    int t = threadIdx.x;
    int base = t * 32;
    int loc[32];
    int s = 0;
#pragma unroll
    for (int i = 0; i < 32; i++) { loc[i] = counts[base + i]; s += loc[i]; }
    part[t] = s;
    __syncthreads();
    for (int off = 1; off < 1024; off <<= 1) {
        int v = (t >= off) ? part[t - off] : 0;
        __syncthreads();
        part[t] += v;
        __syncthreads();
    }
    int run = part[t] - s;   // exclusive prefix
#pragma unroll
    for (int i = 0; i < 32; i++) {
        offs[base + i] = run;
        cursor[base + i] = run;
        run += loc[i];
    }
    if (t == 1023) offs[N] = run;
}

__global__ void k_scatter(const int* __restrict__ dst, const int* __restrict__ srcA,
                          int* __restrict__ cursor, int* __restrict__ perm,
                          int* __restrict__ sperm, int E)
{
    int i = blockIdx.x * blockDim.x + threadIdx.x;
    if (i < E) {
        int d = dst[i];
        int p = atomicAdd(&cursor[d], 1);
        perm[p] = i;
        sperm[p] = srcA[i];
    }
}

// ---------------- edge-linear materialize: ep = fp16(ea[perm]@we + be) -----
// wave = 8 edges; lane = output channel (64). Optional dual output.
__global__ __launch_bounds__(256) void k_egv(
    const float* __restrict__ ea, const int* __restrict__ perm,
    const float* __restrict__ weA, const float* __restrict__ beA,
    _Float16* __restrict__ epA,
    const float* __restrict__ weB, const float* __restrict__ beB,
    _Float16* __restrict__ epB, int dual)
{
    int t = threadIdx.x;
    int wid = t >> 6, lane = t & 63;
    float wA[32];
#pragma unroll
    for (int k = 0; k < 32; k++) wA[k] = weA[k * 64 + lane];
    float bAc = beA ? beA[lane] : 0.f;
    float wB[32];
    float bBc = 0.f;
    if (dual) {
#pragma unroll
        for (int k = 0; k < 32; k++) wB[k] = weB[k * 64 + lane];
        bBc = beB ? beB[lane] : 0.f;
    }
    int jbase = (blockIdx.x * 4 + wid) * 8;
    for (int u = 0; u < 8; u++) {
        int j = jbase + u;
        int e = __builtin_amdgcn_readfirstlane(perm[j]);
        const float4* ea4 = (const float4*)(ea + (size_t)e * 32);
        float eav[32];
#pragma unroll
        for (int w = 0; w < 8; w++) {
            float4 t4 = ea4[w];
            eav[4 * w] = t4.x; eav[4 * w + 1] = t4.y;
            eav[4 * w + 2] = t4.z; eav[4 * w + 3] = t4.w;
        }
        float vA = bAc;
#pragma unroll
        for (int k = 0; k < 32; k++) vA = fmaf(eav[k], wA[k], vA);
        epA[(size_t)j * 64 + lane] = (_Float16)vA;
        if (dual) {
            float vB = bBc;
#pragma unroll
            for (int k = 0; k < 32; k++) vB = fmaf(eav[k], wB[k], vB);
            epB[(size_t)j * 64 + lane] = (_Float16)vB;
        }
    }
}

// ---------------- generic small GEMM: Y = [relu](X @ W + b) ----------------
__global__ __launch_bounds__(256) void k_gemm(
    const float* __restrict__ X, int Kdim,
    const float* __restrict__ W, const float* __restrict__ bias,
    float* __restrict__ Y, int Kout, int dorelu)
{
    __shared__ float Xs[64][68];
    __shared__ float Ws[64][68];
    int n0 = blockIdx.x * 64;
    int j0 = blockIdx.y * 64;
    int t  = threadIdx.x;
    float acc[4][4] = {};
    for (int kk = 0; kk < Kdim; kk += 64) {
        for (int f = t; f < 4096; f += 256) {
            int r = f >> 6, c = f & 63;
            Xs[r][c] = (kk + c < Kdim) ? X[(size_t)(n0 + r) * Kdim + kk + c] : 0.f;
        }
        for (int f = t; f < 4096; f += 256) {
            int k = f >> 6, j = f & 63;
            Ws[k][j] = (kk + k < Kdim && j0 + j < Kout)
                           ? W[(size_t)(kk + k) * Kout + j0 + j] : 0.f;
        }
        __syncthreads();
        int rr = (t >> 4) << 2, jj = (t & 15) << 2;
#pragma unroll 8
        for (int k = 0; k < 64; k++) {
            float4 wv = *(const float4*)&Ws[k][jj];
            float x0 = Xs[rr + 0][k], x1 = Xs[rr + 1][k];
            float x2 = Xs[rr + 2][k], x3 = Xs[rr + 3][k];
            acc[0][0] = fmaf(x0, wv.x, acc[0][0]); acc[0][1] = fmaf(x0, wv.y, acc[0][1]);
            acc[0][2] = fmaf(x0, wv.z, acc[0][2]); acc[0][3] = fmaf(x0, wv.w, acc[0][3]);
            acc[1][0] = fmaf(x1, wv.x, acc[1][0]); acc[1][1] = fmaf(x1, wv.y, acc[1][1]);
            acc[1][2] = fmaf(x1, wv.z, acc[1][2]); acc[1][3] = fmaf(x1, wv.w, acc[1][3]);
            acc[2][0] = fmaf(x2, wv.x, acc[2][0]); acc[2][1] = fmaf(x2, wv.y, acc[2][1]);
            acc[2][2] = fmaf(x2, wv.z, acc[2][2]); acc[2][3] = fmaf(x2, wv.w, acc[2][3]);
            acc[3][0] = fmaf(x3, wv.x, acc[3][0]); acc[3][1] = fmaf(x3, wv.y, acc[3][1]);
            acc[3][2] = fmaf(x3, wv.z, acc[3][2]); acc[3][3] = fmaf(x3, wv.w, acc[3][3]);
        }
        __syncthreads();
    }
    int rr = (t >> 4) << 2, jj = (t & 15) << 2;
    if (j0 + jj < Kout) {
        float4 bv = *(const float4*)&bias[j0 + jj];
#pragma unroll
        for (int i = 0; i < 4; i++) {
            float4 o;
            o.x = acc[i][0] + bv.x; o.y = acc[i][1] + bv.y;
            o.z = acc[i][2] + bv.z; o.w = acc[i][3] + bv.w;
            if (dorelu) {
                o.x = fmaxf(o.x, 0.f); o.y = fmaxf(o.y, 0.f);
                o.z = fmaxf(o.z, 0.f); o.w = fmaxf(o.w, 0.f);
            }
            *(float4*)&Y[(size_t)(n0 + rr + i) * Kout + j0 + jj] = o;
        }
    }
}

// ---------------- fused Q/K/V/skip GEMM; K,V outputs in fp16 ---------------
__global__ __launch_bounds__(256) void k_gemm4(
    const float* __restrict__ X,
    const float* __restrict__ W0, const float* __restrict__ B0, float* __restrict__ Y0,
    const float* __restrict__ W1, const float* __restrict__ B1, _Float16* __restrict__ Y1,
    const float* __restrict__ W2, const float* __restrict__ B2, _Float16* __restrict__ Y2,
    const float* __restrict__ W3, const float* __restrict__ B3, float* __restrict__ Y3)
{
    __shared__ float Xs[64][68];
    __shared__ float Ws[64][68];
    int which = blockIdx.y >> 2;
    const float* W = (which == 0) ? W0 : (which == 1) ? W1 : (which == 2) ? W2 : W3;
    const float* B = (which == 0) ? B0 : (which == 1) ? B1 : (which == 2) ? B2 : B3;
    int n0 = blockIdx.x * 64;
    int j0 = (blockIdx.y & 3) * 64;
    int t  = threadIdx.x;
    float acc[4][4] = {};
    for (int f = t; f < 4096; f += 256) {
        int r = f >> 6, c = f & 63;
        Xs[r][c] = X[(size_t)(n0 + r) * 64 + c];
    }
    for (int f = t; f < 4096; f += 256) {
        int k = f >> 6, j = f & 63;
        Ws[k][j] = W[(size_t)k * 256 + j0 + j];
    }
    __syncthreads();
    int rr = (t >> 4) << 2, jj = (t & 15) << 2;
#pragma unroll 8
    for (int k = 0; k < 64; k++) {
        float4 wv = *(const float4*)&Ws[k][jj];
        float x0 = Xs[rr + 0][k], x1 = Xs[rr + 1][k];
        float x2 = Xs[rr + 2][k], x3 = Xs[rr + 3][k];
        acc[0][0] = fmaf(x0, wv.x, acc[0][0]); acc[0][1] = fmaf(x0, wv.y, acc[0][1]);
        acc[0][2] = fmaf(x0, wv.z, acc[0][2]); acc[0][3] = fmaf(x0, wv.w, acc[0][3]);
        acc[1][0] = fmaf(x1, wv.x, acc[1][0]); acc[1][1] = fmaf(x1, wv.y, acc[1][1]);
        acc[1][2] = fmaf(x1, wv.z, acc[1][2]); acc[1][3] = fmaf(x1, wv.w, acc[1][3]);
        acc[2][0] = fmaf(x2, wv.x, acc[2][0]); acc[2][1] = fmaf(x2, wv.y, acc[2][1]);
        acc[2][2] = fmaf(x2, wv.z, acc[2][2]); acc[2][3] = fmaf(x2, wv.w, acc[2][3]);
        acc[3][0] = fmaf(x3, wv.x, acc[3][0]); acc[3][1] = fmaf(x3, wv.y, acc[3][1]);
        acc[3][2] = fmaf(x3, wv.z, acc[3][2]); acc[3][3] = fmaf(x3, wv.w, acc[3][3]);
    }
    float4 bv = *(const float4*)&B[j0 + jj];
    if (which == 1 || which == 2) {
        _Float16* Yh = (which == 1) ? Y1 : Y2;
#pragma unroll
        for (int i = 0; i < 4; i++) {
            half4v o;
            o[0] = (_Float16)(acc[i][0] + bv.x);
            o[1] = (_Float16)(acc[i][1] + bv.y);
            o[2] = (_Float16)(acc[i][2] + bv.z);
            o[3] = (_Float16)(acc[i][3] + bv.w);
            *(half4v*)&Yh[(size_t)(n0 + rr + i) * 256 + j0 + jj] = o;
        }
    } else {
        float* Y = (which == 0) ? Y0 : Y3;
#pragma unroll
        for (int i = 0; i < 4; i++) {
            float4 o;
            o.x = acc[i][0] + bv.x; o.y = acc[i][1] + bv.y;
            o.z = acc[i][2] + bv.z; o.w = acc[i][3] + bv.w;
            *(float4*)&Y[(size_t)(n0 + rr + i) * 256 + j0 + jj] = o;
        }
    }
}

// ---------------- qt precompute: qt[n,h*32+k] = 0.125*sum_c q[n,h,c]we3[k,h64+c]
__global__ __launch_bounds__(256) void k_qt(
    const float* __restrict__ qb, const float* __restrict__ we3,
    _Float16* __restrict__ qtp, int N)
{
    __shared__ float we3s[32][257];
    __shared__ float qrow[256];
    int t = threadIdx.x;
    for (int f = t; f < 8192; f += 256)
        we3s[f >> 8][f & 255] = we3[f];
    int n0 = blockIdx.x * 32;
    int h = t >> 5, k = t & 31;          // valid for t<128
    for (int i = 0; i < 32; i++) {
        int n = n0 + i;
        __syncthreads();
        qrow[t] = qb[(size_t)n * 256 + t];
        __syncthreads();
        if (t < 128) {
            float s = 0.f;
#pragma unroll
            for (int c = 0; c < 64; c++)
                s = fmaf(qrow[h * 64 + c], we3s[k][h * 64 + c], s);
            qtp[(size_t)n * 128 + t] = (_Float16)(s * 0.125f);
        }
    }
}

// ---------------- GINE aggregation, quad layout ----------------------------
// wave = node; 16 lanes/edge slot; lane handles 4 channels.
__global__ __launch_bounds__(256) void k_gine2(
    const float* __restrict__ xin, const _Float16* __restrict__ ep,
    const float* __restrict__ epsp,
    const int* __restrict__ offs, const int* __restrict__ sperm,
    float* __restrict__ hout)
{
    int t = threadIdx.x;
    int wid  = __builtin_amdgcn_readfirstlane(t >> 6);
    int n    = blockIdx.x * 4 + wid;
    int lane = t & 63;
    int g = lane >> 4, li = lane & 15, c0 = li * 4;
    int j0 = __builtin_amdgcn_readfirstlane(offs[n]);
    int j1 = __builtin_amdgcn_readfirstlane(offs[n + 1]);
    float4 acc = {0.f, 0.f, 0.f, 0.f};
    for (int jq = j0; jq < j1; jq += 4) {
        int j = jq + g;
        int jc = (j < j1) ? j : (j1 - 1);
        int s = sperm[jc];
        half4v ev = *(const half4v*)&ep[(size_t)jc * 64 + c0];
        float4 xv = *(const float4*)&xin[(size_t)s * 64 + c0];
        if (j < j1) {
            acc.x += fmaxf(xv.x + (float)ev[0], 0.f);
            acc.y += fmaxf(xv.y + (float)ev[1], 0.f);
            acc.z += fmaxf(xv.z + (float)ev[2], 0.f);
            acc.w += fmaxf(xv.w + (float)ev[3], 0.f);
        }
    }
    acc.x += __shfl_xor(acc.x, 16); acc.x += __shfl_xor(acc.x, 32);
    acc.y += __shfl_xor(acc.y, 16); acc.y += __shfl_xor(acc.y, 32);
    acc.z += __shfl_xor(acc.z, 16); acc.z += __shfl_xor(acc.z, 32);
    acc.w += __shfl_xor(acc.w, 16); acc.w += __shfl_xor(acc.w, 32);
    if (g == 0) {
        float eps1 = 1.f + epsp[0];
        float4 xn = *(const float4*)&xin[(size_t)n * 64 + c0];
        float4 o;
        o.x = eps1 * xn.x + acc.x;
        o.y = eps1 * xn.y + acc.y;
        o.z = eps1 * xn.z + acc.z;
        o.w = eps1 * xn.w + acc.w;
        *(float4*)&hout[(size_t)n * 64 + c0] = o;
    }
}

// ---------------- TransformerConv, quad layout + e3 decomposition ----------
// block = node; wave = head; 16 lanes/edge slot; lane = 4 channels.
__global__ __launch_bounds__(256) void k_tconv3(
    const float* __restrict__ qb, const _Float16* __restrict__ kb,
    const _Float16* __restrict__ vb, const _Float16* __restrict__ qtp,
    const float* __restrict__ we3, const float* __restrict__ ea,
    const int* __restrict__ offs, const int* __restrict__ perm,
    const int* __restrict__ sperm,
    float* __restrict__ skip_io)
{
    __shared__ float wa_s[4][32];
    int n = blockIdx.x;
    int t = threadIdx.x;
    int h = t >> 6;
    int lane = t & 63;
    int g = lane >> 4, li = lane & 15, c0 = li * 4;
    float4 qv = *(const float4*)&qb[(size_t)n * 256 + h * 64 + c0];
    qv.x *= 0.125f; qv.y *= 0.125f; qv.z *= 0.125f; qv.w *= 0.125f;
    half2v q2 = *(const half2v*)&qtp[(size_t)n * 128 + h * 32 + li * 2];
    float qt0 = (float)q2[0], qt1 = (float)q2[1];
    int j0 = __builtin_amdgcn_readfirstlane(offs[n]);
    int j1 = __builtin_amdgcn_readfirstlane(offs[n + 1]);
    float l = 0.f, wa0 = 0.f, wa1 = 0.f;
    float4 acc = {0.f, 0.f, 0.f, 0.f};
    for (int jq = j0; jq < j1; jq += 4) {
        int j = jq + g;
        int jc = (j < j1) ? j : (j1 - 1);
        int e = perm[jc];
        int s = sperm[jc];
        float2 eav = *(const float2*)&ea[(size_t)e * 32 + li * 2];
        half4v kvh = *(const half4v*)&kb[(size_t)s * 256 + h * 64 + c0];
        float p = qv.x * (float)kvh[0] + qv.y * (float)kvh[1]
                + qv.z * (float)kvh[2] + qv.w * (float)kvh[3]
                + qt0 * eav.x + qt1 * eav.y;
        p += __shfl_xor(p, 1); p += __shfl_xor(p, 2);
        p += __shfl_xor(p, 4); p += __shfl_xor(p, 8);
        float w = (j < j1) ? __expf(p) : 0.f;   // logits O(0.5): no-max exact
        half4v vvh = *(const half4v*)&vb[(size_t)s * 256 + h * 64 + c0];
        l += w;
        acc.x = fmaf(w, (float)vvh[0], acc.x);
        acc.y = fmaf(w, (float)vvh[1], acc.y);
        acc.z = fmaf(w, (float)vvh[2], acc.z);
        acc.w = fmaf(w, (float)vvh[3], acc.w);
        wa0 = fmaf(w, eav.x, wa0);
        wa1 = fmaf(w, eav.y, wa1);
    }
    // cross-group reductions
    l   += __shfl_xor(l, 16);   l   += __shfl_xor(l, 32);
    wa0 += __shfl_xor(wa0, 16); wa0 += __shfl_xor(wa0, 32);
    wa1 += __shfl_xor(wa1, 16); wa1 += __shfl_xor(wa1, 32);
    acc.x += __shfl_xor(acc.x, 16); acc.x += __shfl_xor(acc.x, 32);
    acc.y += __shfl_xor(acc.y, 16); acc.y += __shfl_xor(acc.y, 32);
    acc.z += __shfl_xor(acc.z, 16); acc.z += __shfl_xor(acc.z, 32);
    acc.w += __shfl_xor(acc.w, 16); acc.w += __shfl_xor(acc.w, 32);
    if (g == 0) { wa_s[h][li * 2] = wa0; wa_s[h][li * 2 + 1] = wa1; }
    __syncthreads();
    // corr = wa @ we3 for this lane's 4 channels; split k across groups
    float4 corr = {0.f, 0.f, 0.f, 0.f};
#pragma unroll
    for (int kk = 0; kk < 8; kk++) {
        int k = g * 8 + kk;
        float wv = wa_s[h][k];
        float4 w3 = *(const float4*)&we3[(size_t)k * 256 + h * 64 + c0];
        corr.x = fmaf(wv, w3.x, corr.x);
        corr.y = fmaf(wv, w3.y, corr.y);
        corr.z = fmaf(wv, w3.z, corr.z);
        corr.w = fmaf(wv, w3.w, corr.w);
    }
    corr.x += __shfl_xor(corr.x, 16); corr.x += __shfl_xor(corr.x, 32);
    corr.y += __shfl_xor(corr.y, 16); corr.y += __shfl_xor(corr.y, 32);
    corr.z += __shfl_xor(corr.z, 16); corr.z += __shfl_xor(corr.z, 32);
    corr.w += __shfl_xor(corr.w, 16); corr.w += __shfl_xor(corr.w, 32);
    if (g == 0) {
        float rl = 1.f / (l + 1e-16f);
        size_t o = (size_t)n * 256 + h * 64 + c0;
        float4 sk = *(const float4*)&skip_io[o];
        float4 outv;
        outv.x = (acc.x + corr.x) * rl + sk.x;
        outv.y = (acc.y + corr.y) * rl + sk.y;
        outv.z = (acc.z + corr.z) * rl + sk.z;
        outv.w = (acc.w + corr.w) * rl + sk.w;
        *(float4*)&skip_io[o] = outv;
    }
}

// ---------------- GATv2 aggregation, quad layout ---------------------------
__global__ __launch_bounds__(256) void k_gat2(
    const float* __restrict__ xl, const float* __restrict__ xr,
    const _Float16* __restrict__ e4p,
    const float* __restrict__ attv, const float* __restrict__ bias4,
    const int* __restrict__ offs, const int* __restrict__ sperm,
    float* __restrict__ out)
{
    int t = threadIdx.x;
    int wid  = __builtin_amdgcn_readfirstlane(t >> 6);
    int n    = blockIdx.x * 4 + wid;
    int lane = t & 63;
    int g = lane >> 4, li = lane & 15, c0 = li * 4;
    float4 xrv = *(const float4*)&xr[(size_t)n * 64 + c0];
    float4 av  = *(const float4*)&attv[c0];
    int j0 = __builtin_amdgcn_readfirstlane(offs[n]);
    int j1 = __builtin_amdgcn_readfirstlane(offs[n + 1]);
    float l = 0.f;
    float4 acc = {0.f, 0.f, 0.f, 0.f};
    for (int jq = j0; jq < j1; jq += 4) {
        int j = jq + g;
        int jc = (j < j1) ? j : (j1 - 1);
        int s = sperm[jc];
        half4v ev = *(const half4v*)&e4p[(size_t)jc * 64 + c0];
        float4 xlv = *(const float4*)&xl[(size_t)s * 64 + c0];
        float h0 = xlv.x + xrv.x + (float)ev[0];
        float h1 = xlv.y + xrv.y + (float)ev[1];
        float h2 = xlv.z + xrv.z + (float)ev[2];
        float h3 = xlv.w + xrv.w + (float)ev[3];
        h0 = (h0 > 0.f) ? h0 : 0.2f * h0;
        h1 = (h1 > 0.f) ? h1 : 0.2f * h1;
        h2 = (h2 > 0.f) ? h2 : 0.2f * h2;
        h3 = (h3 > 0.f) ? h3 : 0.2f * h3;
        float p = h0 * av.x + h1 * av.y + h2 * av.z + h3 * av.w;
        p += __shfl_xor(p, 1); p += __shfl_xor(p, 2);
        p += __shfl_xor(p, 4); p += __shfl_xor(p, 8);
        float w = (j < j1) ? __expf(p) : 0.f;   // logits O(0.5): no-max exact
        l += w;
        acc.x = fmaf(w, xlv.x, acc.x);
        acc.y = fmaf(w, xlv.y, acc.y);
        acc.z = fmaf(w, xlv.z, acc.z);
        acc.w = fmaf(w, xlv.w, acc.w);
    }
    l += __shfl_xor(l, 16); l += __shfl_xor(l, 32);
    acc.x += __shfl_xor(acc.x, 16); acc.x += __shfl_xor(acc.x, 32);
    acc.y += __shfl_xor(acc.y, 16); acc.y += __shfl_xor(acc.y, 32);
    acc.z += __shfl_xor(acc.z, 16); acc.z += __shfl_xor(acc.z, 32);
    acc.w += __shfl_xor(acc.w, 16); acc.w += __shfl_xor(acc.w, 32);
    if (g == 0) {
        float rl = 1.f / (l + 1e-16f);
        float4 bv = *(const float4*)&bias4[c0];
        float4 o;
        o.x = acc.x * rl + bv.x;
        o.y = acc.y * rl + bv.y;
        o.z = acc.z * rl + bv.z;
        o.w = acc.w * rl + bv.w;
        *(float4*)&out[(size_t)n * 64 + c0] = o;
    }
}

// ---------------------------------------------------------------------------
extern "C" void kernel_launch(void* const* d_in, const int* in_sizes, int n_in,
                              void* d_out, int out_size, void* d_ws, size_t ws_size,
                              hipStream_t stream)
{
    const float* x     = (const float*)d_in[0];
    const float* ea    = (const float*)d_in[1];
    const float* eps1  = (const float*)d_in[2];
    const float* w1a   = (const float*)d_in[3];
    const float* b1a   = (const float*)d_in[4];
    const float* w1b   = (const float*)d_in[5];
    const float* b1b   = (const float*)d_in[6];
    const float* we1   = (const float*)d_in[7];
    const float* be1   = (const float*)d_in[8];
    const float* eps2  = (const float*)d_in[9];
    const float* w2a   = (const float*)d_in[10];
    const float* b2a   = (const float*)d_in[11];
    const float* w2b   = (const float*)d_in[12];
    const float* b2b   = (const float*)d_in[13];
    const float* we2   = (const float*)d_in[14];
    const float* be2   = (const float*)d_in[15];
    const float* wq    = (const float*)d_in[16];
    const float* bq    = (const float*)d_in[17];
    const float* wk    = (const float*)d_in[18];
    const float* bk    = (const float*)d_in[19];
    const float* wv    = (const float*)d_in[20];
    const float* bv    = (const float*)d_in[21];
    const float* we3   = (const float*)d_in[22];
    const float* wskip = (const float*)d_in[23];
    const float* bskip = (const float*)d_in[24];
    const float* wl    = (const float*)d_in[25];
    const float* bl    = (const float*)d_in[26];
    const float* wr    = (const float*)d_in[27];
    const float* br    = (const float*)d_in[28];
    const float* we4   = (const float*)d_in[29];
    const float* attv  = (const float*)d_in[30];
    const float* bias4 = (const float*)d_in[31];
    const void*  eidx  = d_in[32];

    const int N = in_sizes[0] / 64;     // 32768
    const int E = in_sizes[1] / 32;     // 524288

    char* ws = (char*)d_ws;
    size_t off = 0;
    auto alloc = [&](size_t bytes) {
        void* p = ws + off;
        off += (bytes + 255) & ~(size_t)255;
        return p;
    };
    int* flag    = (int*)alloc(4);
    int* econv   = (int*)alloc((size_t)2 * E * 4);
    int* counts  = (int*)alloc((size_t)N * 4);
    int* cursor  = (int*)alloc((size_t)N * 4);
    int* offs    = (int*)alloc((size_t)(N + 1) * 4);
    int* perm    = (int*)alloc((size_t)E * 4);
    int* sperm   = (int*)alloc((size_t)E * 4);
    float* h     = (float*)alloc((size_t)N * 64 * 4);
    float* t1    = (float*)alloc((size_t)N * 64 * 4);
    float* x1    = (float*)alloc((size_t)N * 64 * 4);
    float* x2    = (float*)alloc((size_t)N * 64 * 4);
    float* qb        = (float*)alloc((size_t)N * 256 * 4);      // also e1p lo half
    _Float16* kbh    = (_Float16*)alloc((size_t)N * 256 * 4);   // e1p hi / e4p lo
    _Float16* vbh    = (_Float16*)alloc((size_t)N * 256 * 4);   // e2p lo / e4p hi
    float* skipb     = (float*)alloc((size_t)N * 256 * 4);      // e2p hi half
    float* xlb   = h;                              // dead by then, reuse
    float* xrb   = t1;                             // dead by then, reuse
    _Float16* qtp = (_Float16*)x1;                 // x1 dead after x2 (N*128*2)
    // edge-linear buffers overlaid on dead qkv regions:
    _Float16* e1p = (_Float16*)qb;    // spans qb+kbh  (E*64*2 = 2*N*256*4 bytes? no:
                                      //  E*64*2 = 67.1MB = exactly qb+kbh regions)
    _Float16* e2p = (_Float16*)vbh;   // spans vbh+skipb
    _Float16* e4p = (_Float16*)kbh;   // spans kbh+vbh (dead after tconv)

    if (off > ws_size) return;   // workspace too small -> visible failure

    // edge_index dtype detect + convert to int32
    k_detect<<<1, 256, 0, stream>>>((const unsigned int*)eidx, flag);
    k_cvt<<<(2 * E + 255) / 256, 256, 0, stream>>>(eidx, flag, econv, 2 * E);
    const int* srcI = econv;
    const int* dstI = econv + E;

    // CSR by dst (+ sperm = src in perm order)
    hipMemsetAsync(counts, 0, (size_t)N * 4, stream);
    k_hist<<<(E + 255) / 256, 256, 0, stream>>>(dstI, counts, E);
    k_scan<<<1, 1024, 0, stream>>>(counts, offs, cursor, N);
    k_scatter<<<(E + 255) / 256, 256, 0, stream>>>(dstI, srcI, cursor, perm, sperm, E);

    // materialize e1, e2 (perm order, fp16) into dead q/k/v/skip regions
    k_egv<<<E / 32, 256, 0, stream>>>(ea, perm, we1, be1, e1p, we2, be2, e2p, 1);

    // GINE 1
    k_gine2<<<N / 4, 256, 0, stream>>>(x, e1p, eps1, offs, sperm, h);
    k_gemm<<<dim3(N / 64, 1), 256, 0, stream>>>(h, 64, w1a, b1a, t1, 64, 1);
    k_gemm<<<dim3(N / 64, 1), 256, 0, stream>>>(t1, 64, w1b, b1b, x1, 64, 0);

    // GINE 2
    k_gine2<<<N / 4, 256, 0, stream>>>(x1, e2p, eps2, offs, sperm, h);
    k_gemm<<<dim3(N / 64, 1), 256, 0, stream>>>(h, 64, w2a, b2a, t1, 32, 1);
    k_gemm<<<dim3(N / 64, 1), 256, 0, stream>>>(t1, 32, w2b, b2b, x2, 64, 0);

    // TransformerConv (x1 dead -> qtp; e1p/e2p dead -> q/k/v/skip)
    k_gemm4<<<dim3(N / 64, 16), 256, 0, stream>>>(x2,
                                                  wq, bq, qb, wk, bk, kbh,
                                                  wv, bv, vbh, wskip, bskip, skipb);
    k_qt<<<N / 32, 256, 0, stream>>>(qb, we3, qtp, N);
    k_tconv3<<<N, 256, 0, stream>>>(qb, kbh, vbh, qtp, we3, ea, offs, perm, sperm,
                                    skipb);

    // GATv2 (kbh/vbh dead -> e4p)
    k_gemm<<<dim3(N / 64, 1), 256, 0, stream>>>(skipb, 256, wl, bl, xlb, 64, 0);
    k_gemm<<<dim3(N / 64, 1), 256, 0, stream>>>(skipb, 256, wr, br, xrb, 64, 0);
    k_egv<<<E / 32, 256, 0, stream>>>(ea, perm, we4, (const float*)nullptr, e4p,
                                      (const float*)nullptr, (const float*)nullptr,
                                      (_Float16*)nullptr, 0);
    k_gat2<<<N / 4, 256, 0, stream>>>(xlb, xrb, e4p, attv, bias4, offs, sperm,
                                      (float*)d_out);
}

// Round 5
// 497.743 us; speedup vs baseline: 1.8836x; 1.4963x over previous
//
#include <hip/hip_runtime.h>
#include <math.h>

// ---------------------------------------------------------------------------
// N=32768 nodes, E=524288 edges, node feat 64, edge feat 32, H=4 x C=64 = 256.
// MFMA fragment maps (mfma_f32_16x16x32_f16):
//   A(16x32): lane l, reg j -> row=l&15,  k=(l>>4)*8+j   (contiguous 8 k)
//   B(32x16): lane l, reg j -> col=l&15,  k=(l>>4)*8+j   (store W^T[col][k])
//   C/D:      lane l, reg r -> col=l&15,  row=(l>>4)*4+r (verified layout)
// ---------------------------------------------------------------------------

typedef __attribute__((ext_vector_type(2))) _Float16 half2v;
typedef __attribute__((ext_vector_type(4))) _Float16 half4v;
typedef __attribute__((ext_vector_type(8))) _Float16 half8v;
typedef __attribute__((ext_vector_type(4))) float float4v;

// ---------------- edge_index dtype detection + convert ---------------------
__global__ void k_detect(const unsigned int* __restrict__ w, int* __restrict__ flag)
{
    __shared__ int any;
    if (threadIdx.x == 0) any = 0;
    __syncthreads();
    int found = 0;
    for (int i = threadIdx.x; i < 2048; i += 256)
        if (w[2 * i + 1] != 0u) found = 1;
    if (found) atomicOr(&any, 1);
    __syncthreads();
    if (threadIdx.x == 0) flag[0] = any ? 0 : 1;   // 1 => int64
}

__global__ void k_cvt(const void* __restrict__ eidx, const int* __restrict__ flag,
                      int* __restrict__ out, int n)
{
    int i = blockIdx.x * blockDim.x + threadIdx.x;
    if (i >= n) return;
    if (flag[0])
        out[i] = (int)((const long long*)eidx)[i];
    else
        out[i] = ((const int*)eidx)[i];
}

// ---------------- CSR build (group edges by dst) ---------------------------
__global__ void k_hist(const int* __restrict__ dst, int* __restrict__ counts, int E)
{
    int i = blockIdx.x * blockDim.x + threadIdx.x;
    if (i < E) atomicAdd(&counts[dst[i]], 1);
}

__global__ void k_scan(const int* __restrict__ counts, int* __restrict__ offs,
                       int* __restrict__ cursor, int N)
{
    __shared__ int part[1024];
    int t = threadIdx.x;
    int base = t * 32;
    int loc[32];
    int s = 0;
#pragma unroll
    for (int i = 0; i < 32; i++) { loc[i] = counts[base + i]; s += loc[i]; }
    part[t] = s;
    __syncthreads();
    for (int off = 1; off < 1024; off <<= 1) {
        int v = (t >= off) ? part[t - off] : 0;
        __syncthreads();
        part[t] += v;
        __syncthreads();
    }
    int run = part[t] - s;   // exclusive prefix
#pragma unroll
    for (int i = 0; i < 32; i++) {
        offs[base + i] = run;
        cursor[base + i] = run;
        run += loc[i];
    }
    if (t == 1023) offs[N] = run;
}

__global__ void k_scatter(const int* __restrict__ dst, const int* __restrict__ srcA,
                          int* __restrict__ cursor, int* __restrict__ perm,
                          int* __restrict__ sperm, int E)
{
    int i = blockIdx.x * blockDim.x + threadIdx.x;
    if (i < E) {
        int d = dst[i];
        int p = atomicAdd(&cursor[d], 1);
        perm[p] = i;
        sperm[p] = srcA[i];
    }
}

// ---------------- weight prep: fp16 transposes + qt-folded matrix ----------
// Wt*[col][k] layouts for MFMA B-operand; Mt = 0.125*wq.we3^T per head; xh=fp16(x)
__global__ __launch_bounds__(256) void k_prep(
    const float* __restrict__ x, int NX,
    const float* __restrict__ wq, const float* __restrict__ wk,
    const float* __restrict__ wv, const float* __restrict__ wskip,
    const float* __restrict__ wl, const float* __restrict__ wr,
    const float* __restrict__ w1a, const float* __restrict__ w1b,
    const float* __restrict__ w2a, const float* __restrict__ w2b,
    const float* __restrict__ we3, const float* __restrict__ bq,
    _Float16* __restrict__ xh,
    _Float16* __restrict__ Wtq, _Float16* __restrict__ Wtk,
    _Float16* __restrict__ Wtv, _Float16* __restrict__ Wts,
    _Float16* __restrict__ Wtl, _Float16* __restrict__ Wtr,
    _Float16* __restrict__ Wt1a, _Float16* __restrict__ Wt1b,
    _Float16* __restrict__ Wt2a, _Float16* __restrict__ Wt2b,
    _Float16* __restrict__ Mt, float* __restrict__ cst)
{
    int g = blockIdx.x * 256 + threadIdx.x;
    if (g < 16384) {                       // q/k/v/skip: Wt[c][k], c<256,k<64
        int c = g >> 6, k = g & 63;
        Wtq[g] = (_Float16)wq[(size_t)k * 256 + c];
        Wtk[g] = (_Float16)wk[(size_t)k * 256 + c];
        Wtv[g] = (_Float16)wv[(size_t)k * 256 + c];
        Wts[g] = (_Float16)wskip[(size_t)k * 256 + c];
    } else if (g < 32768) {                // wl/wr: Wt[c][k], c<64,k<256
        int q = g - 16384, c = q >> 8, k = q & 255;
        Wtl[q] = (_Float16)wl[(size_t)k * 64 + c];
        Wtr[q] = (_Float16)wr[(size_t)k * 64 + c];
    } else if (g < 36864) {                // w1a/w1b 64x64
        int q = g - 32768, m = q >> 6, k = q & 63;
        Wt1a[q] = (_Float16)w1a[(size_t)k * 64 + m];
        Wt1b[q] = (_Float16)w1b[(size_t)k * 64 + m];
    } else if (g < 38912) {                // w2a 64x32 -> Wt2a[m<32][k<64]
        int q = g - 36864, m = q >> 6, k = q & 63;
        Wt2a[q] = (_Float16)w2a[(size_t)k * 32 + m];
    } else if (g < 40960) {                // w2b 32x64 -> Wt2b[c<64][k<32]
        int q = g - 38912, c = q >> 5, k = q & 31;
        Wt2b[q] = (_Float16)w2b[(size_t)k * 64 + c];
    } else if (g < 49152) {                // Mt[m<128][d<64]
        int q = g - 40960, m = q >> 6, d = q & 63;
        int h = m >> 5, kk = m & 31;
        float s = 0.f;
        for (int c = 0; c < 64; c++)
            s = fmaf(wq[(size_t)d * 256 + h * 64 + c],
                     we3[(size_t)kk * 256 + h * 64 + c], s);
        Mt[q] = (_Float16)(0.125f * s);
    } else if (g < 49280) {                // cst[128]
        int m = g - 49152, h = m >> 5, kk = m & 31;
        float s = 0.f;
        for (int c = 0; c < 64; c++)
            s = fmaf(bq[h * 64 + c], we3[(size_t)kk * 256 + h * 64 + c], s);
        cst[m] = 0.125f * s;
    }
    for (int i = g; i < NX; i += 256 * 256)
        xh[i] = (_Float16)x[i];
}

// ---------------- edge-linear materialize: ep = fp16(ea[perm]@we + be) -----
__global__ __launch_bounds__(256) void k_egv(
    const float* __restrict__ ea, const int* __restrict__ perm,
    const float* __restrict__ weA, const float* __restrict__ beA,
    _Float16* __restrict__ epA,
    const float* __restrict__ weB, const float* __restrict__ beB,
    _Float16* __restrict__ epB, int dual)
{
    int t = threadIdx.x;
    int wid = t >> 6, lane = t & 63;
    float wA[32];
#pragma unroll
    for (int k = 0; k < 32; k++) wA[k] = weA[k * 64 + lane];
    float bAc = beA ? beA[lane] : 0.f;
    float wB[32];
    float bBc = 0.f;
    if (dual) {
#pragma unroll
        for (int k = 0; k < 32; k++) wB[k] = weB[k * 64 + lane];
        bBc = beB ? beB[lane] : 0.f;
    }
    int jbase = (blockIdx.x * 4 + wid) * 8;
    for (int u = 0; u < 8; u++) {
        int j = jbase + u;
        int e = __builtin_amdgcn_readfirstlane(perm[j]);
        const float4* ea4 = (const float4*)(ea + (size_t)e * 32);
        float eav[32];
#pragma unroll
        for (int w = 0; w < 8; w++) {
            float4 t4 = ea4[w];
            eav[4 * w] = t4.x; eav[4 * w + 1] = t4.y;
            eav[4 * w + 2] = t4.z; eav[4 * w + 3] = t4.w;
        }
        float vA = bAc;
#pragma unroll
        for (int k = 0; k < 32; k++) vA = fmaf(eav[k], wA[k], vA);
        epA[(size_t)j * 64 + lane] = (_Float16)vA;
        if (dual) {
            float vB = bBc;
#pragma unroll
            for (int k = 0; k < 32; k++) vB = fmaf(eav[k], wB[k], vB);
            epB[(size_t)j * 64 + lane] = (_Float16)vB;
        }
    }
}

// ---------------- fused 2-layer MLP via MFMA: out = (relu(A@W1+b1))@W2+b2 --
template<int MID>
__global__ __launch_bounds__(256) void k_mlp(
    const _Float16* __restrict__ A,      // [N][64] fp16
    const _Float16* __restrict__ Wt1,    // [MID][64]
    const float* __restrict__ b1,
    const _Float16* __restrict__ Wt2,    // [64][MID]
    const float* __restrict__ b2,
    _Float16* __restrict__ out)          // [N][64] fp16
{
    __shared__ _Float16 As[64][72];
    __shared__ _Float16 Ws1[MID][72];
    __shared__ _Float16 Ws2[64][MID + 8];
    __shared__ _Float16 mids[64][MID + 8];
    int t = threadIdx.x;
    int n0 = blockIdx.x * 64;
    for (int f = t; f < 512; f += 256) {
        int r = f >> 3, seg = f & 7;
        *(uint4*)&As[r][seg * 8] = *(const uint4*)&A[(size_t)(n0 + r) * 64 + seg * 8];
    }
    for (int f = t; f < MID * 8; f += 256) {
        int r = f >> 3, seg = f & 7;
        *(uint4*)&Ws1[r][seg * 8] = *(const uint4*)&Wt1[(size_t)r * 64 + seg * 8];
    }
    constexpr int CH = MID / 8;
    for (int f = t; f < 64 * CH; f += 256) {
        int r = f / CH, seg = f % CH;
        *(uint4*)&Ws2[r][seg * 8] = *(const uint4*)&Wt2[(size_t)r * MID + seg * 8];
    }
    __syncthreads();
    int w = t >> 6, l = t & 63;
    int arow = w * 16 + (l & 15);
    int kg = (l >> 4) * 8;
    int colg = l & 15;
    int orow = w * 16 + (l >> 4) * 4;
    half8v a0 = *(const half8v*)&As[arow][kg];
    half8v a1 = *(const half8v*)&As[arow][32 + kg];
    constexpr int NCT1 = MID / 16;
#pragma unroll
    for (int ct = 0; ct < NCT1; ct++) {
        half8v b0 = *(const half8v*)&Ws1[ct * 16 + colg][kg];
        half8v b1v = *(const half8v*)&Ws1[ct * 16 + colg][32 + kg];
        float4v acc = {0.f, 0.f, 0.f, 0.f};
        acc = __builtin_amdgcn_mfma_f32_16x16x32_f16(a0, b0, acc, 0, 0, 0);
        acc = __builtin_amdgcn_mfma_f32_16x16x32_f16(a1, b1v, acc, 0, 0, 0);
        int col = ct * 16 + colg;
        float bb = b1[col];
#pragma unroll
        for (int r = 0; r < 4; r++)
            mids[orow + r][col] = (_Float16)fmaxf(acc[r] + bb, 0.f);
    }
    __syncthreads();
    half8v m0 = *(const half8v*)&mids[arow][kg];
#pragma unroll
    for (int ct = 0; ct < 4; ct++) {
        half8v b0 = *(const half8v*)&Ws2[ct * 16 + colg][kg];
        float4v acc = {0.f, 0.f, 0.f, 0.f};
        acc = __builtin_amdgcn_mfma_f32_16x16x32_f16(m0, b0, acc, 0, 0, 0);
        if (MID == 64) {
            half8v m1 = *(const half8v*)&mids[arow][32 + kg];
            half8v b1v = *(const half8v*)&Ws2[ct * 16 + colg][32 + kg];
            acc = __builtin_amdgcn_mfma_f32_16x16x32_f16(m1, b1v, acc, 0, 0, 0);
        }
        int col = ct * 16 + colg;
        float bb = b2[col];
#pragma unroll
        for (int r = 0; r < 4; r++)
            out[(size_t)(n0 + orow + r) * 64 + col] = (_Float16)(acc[r] + bb);
    }
}

// ---------------- fused q/k/v/skip/qt projections via MFMA -----------------
// grid (N/64, 17): y<16 -> proj y>>2, col-tile (y&3)*64; y==16 -> qt (128 col)
__global__ __launch_bounds__(256) void k_gemm4m(
    const _Float16* __restrict__ A,
    const _Float16* __restrict__ Wtq, const float* __restrict__ bq,
    const _Float16* __restrict__ Wtk, const float* __restrict__ bk,
    const _Float16* __restrict__ Wtv, const float* __restrict__ bv,
    const _Float16* __restrict__ Wts, const float* __restrict__ bs,
    const _Float16* __restrict__ Mt,  const float* __restrict__ cst,
    _Float16* __restrict__ qbh, _Float16* __restrict__ kbh,
    _Float16* __restrict__ vbh, float* __restrict__ skipb,
    _Float16* __restrict__ qtp)
{
    __shared__ _Float16 As[64][72];
    __shared__ _Float16 Ws[128][72];
    int t = threadIdx.x;
    int n0 = blockIdx.x * 64;
    int y = blockIdx.y;
    for (int f = t; f < 512; f += 256) {
        int r = f >> 3, seg = f & 7;
        *(uint4*)&As[r][seg * 8] = *(const uint4*)&A[(size_t)(n0 + r) * 64 + seg * 8];
    }
    if (y < 16) {
        int p = y >> 2, j0 = (y & 3) * 64;
        const _Float16* Wt = (p == 0) ? Wtq : (p == 1) ? Wtk : (p == 2) ? Wtv : Wts;
        for (int f = t; f < 512; f += 256) {
            int c = f >> 3, seg = f & 7;
            *(uint4*)&Ws[c][seg * 8] = *(const uint4*)&Wt[(size_t)(j0 + c) * 64 + seg * 8];
        }
    } else {
        for (int f = t; f < 1024; f += 256) {
            int c = f >> 3, seg = f & 7;
            *(uint4*)&Ws[c][seg * 8] = *(const uint4*)&Mt[(size_t)c * 64 + seg * 8];
        }
    }
    __syncthreads();
    int w = t >> 6, l = t & 63;
    int arow = w * 16 + (l & 15);
    int kg = (l >> 4) * 8;
    int colg = l & 15;
    int orow = w * 16 + (l >> 4) * 4;
    half8v a0 = *(const half8v*)&As[arow][kg];
    half8v a1 = *(const half8v*)&As[arow][32 + kg];
    if (y < 16) {
        int p = y >> 2, j0 = (y & 3) * 64;
        const float* B = (p == 0) ? bq : (p == 1) ? bk : (p == 2) ? bv : bs;
        float4v acc[4];
#pragma unroll
        for (int ct = 0; ct < 4; ct++) {
            half8v b0 = *(const half8v*)&Ws[ct * 16 + colg][kg];
            half8v b1 = *(const half8v*)&Ws[ct * 16 + colg][32 + kg];
            float4v a = {0.f, 0.f, 0.f, 0.f};
            a = __builtin_amdgcn_mfma_f32_16x16x32_f16(a0, b0, a, 0, 0, 0);
            a = __builtin_amdgcn_mfma_f32_16x16x32_f16(a1, b1, a, 0, 0, 0);
            acc[ct] = a;
        }
#pragma unroll
        for (int ct = 0; ct < 4; ct++) {
            int col = j0 + ct * 16 + colg;
            float bb = B[col];
            if (p == 3) {
#pragma unroll
                for (int r = 0; r < 4; r++)
                    skipb[(size_t)(n0 + orow + r) * 256 + col] = acc[ct][r] + bb;
            } else {
                _Float16* O = (p == 0) ? qbh : (p == 1) ? kbh : vbh;
#pragma unroll
                for (int r = 0; r < 4; r++)
                    O[(size_t)(n0 + orow + r) * 256 + col] = (_Float16)(acc[ct][r] + bb);
            }
        }
    } else {
        float4v acc[8];
#pragma unroll
        for (int ct = 0; ct < 8; ct++) {
            half8v b0 = *(const half8v*)&Ws[ct * 16 + colg][kg];
            half8v b1 = *(const half8v*)&Ws[ct * 16 + colg][32 + kg];
            float4v a = {0.f, 0.f, 0.f, 0.f};
            a = __builtin_amdgcn_mfma_f32_16x16x32_f16(a0, b0, a, 0, 0, 0);
            a = __builtin_amdgcn_mfma_f32_16x16x32_f16(a1, b1, a, 0, 0, 0);
            acc[ct] = a;
        }
#pragma unroll
        for (int ct = 0; ct < 8; ct++) {
            int col = ct * 16 + colg;
            float bb = cst[col];
#pragma unroll
            for (int r = 0; r < 4; r++)
                qtp[(size_t)(n0 + orow + r) * 128 + col] = (_Float16)(acc[ct][r] + bb);
        }
    }
}

// ---------------- GAT xl/xr projections via MFMA (K=256, 2 stage rounds) ---
__global__ __launch_bounds__(256) void k_gatgemm(
    const float* __restrict__ A,         // skipb [N][256] fp32
    const _Float16* __restrict__ WtL, const float* __restrict__ bL,
    const _Float16* __restrict__ WtR, const float* __restrict__ bR,
    _Float16* __restrict__ xlh, _Float16* __restrict__ xrh)
{
    __shared__ _Float16 As[64][136];
    __shared__ _Float16 Ws[64][136];
    int t = threadIdx.x;
    int n0 = blockIdx.x * 64;
    int y = blockIdx.y;
    const _Float16* Wt = y ? WtR : WtL;
    const float* bb = y ? bR : bL;
    _Float16* out = y ? xrh : xlh;
    int w = t >> 6, l = t & 63;
    int arow = w * 16 + (l & 15);
    int kg = (l >> 4) * 8;
    int colg = l & 15;
    int orow = w * 16 + (l >> 4) * 4;
    float4v acc[4] = {{0.f,0.f,0.f,0.f},{0.f,0.f,0.f,0.f},
                      {0.f,0.f,0.f,0.f},{0.f,0.f,0.f,0.f}};
    for (int kh = 0; kh < 2; kh++) {
        __syncthreads();
        for (int f = t; f < 2048; f += 256) {     // A: 64 rows x 128 k, cvt fp32->fp16
            int r = f >> 5, seg = f & 31;
            float4 v = *(const float4*)&A[(size_t)(n0 + r) * 256 + kh * 128 + seg * 4];
            half4v hv;
            hv[0] = (_Float16)v.x; hv[1] = (_Float16)v.y;
            hv[2] = (_Float16)v.z; hv[3] = (_Float16)v.w;
            *(half4v*)&As[r][seg * 4] = hv;
        }
        for (int f = t; f < 1024; f += 256) {     // W: 64 cols x 128 k
            int c = f >> 4, seg = f & 15;
            *(uint4*)&Ws[c][seg * 8] = *(const uint4*)&Wt[(size_t)c * 256 + kh * 128 + seg * 8];
        }
        __syncthreads();
#pragma unroll
        for (int ks = 0; ks < 4; ks++) {
            half8v a = *(const half8v*)&As[arow][ks * 32 + kg];
#pragma unroll
            for (int ct = 0; ct < 4; ct++) {
                half8v b = *(const half8v*)&Ws[ct * 16 + colg][ks * 32 + kg];
                acc[ct] = __builtin_amdgcn_mfma_f32_16x16x32_f16(a, b, acc[ct], 0, 0, 0);
            }
        }
    }
#pragma unroll
    for (int ct = 0; ct < 4; ct++) {
        int col = ct * 16 + colg;
        float bv = bb[col];
#pragma unroll
        for (int r = 0; r < 4; r++)
            out[(size_t)(n0 + orow + r) * 64 + col] = (_Float16)(acc[ct][r] + bv);
    }
}

// ---------------- GINE aggregation, quad layout, fp16 in/out ---------------
__global__ __launch_bounds__(256) void k_gine2(
    const _Float16* __restrict__ xin, const _Float16* __restrict__ ep,
    const float* __restrict__ epsp,
    const int* __restrict__ offs, const int* __restrict__ sperm,
    _Float16* __restrict__ hout)
{
    int t = threadIdx.x;
    int wid  = __builtin_amdgcn_readfirstlane(t >> 6);
    int n    = blockIdx.x * 4 + wid;
    int lane = t & 63;
    int g = lane >> 4, li = lane & 15, c0 = li * 4;
    int j0 = __builtin_amdgcn_readfirstlane(offs[n]);
    int j1 = __builtin_amdgcn_readfirstlane(offs[n + 1]);
    float4 acc = {0.f, 0.f, 0.f, 0.f};
    for (int jq = j0; jq < j1; jq += 4) {
        int j = jq + g;
        int jc = (j < j1) ? j : (j1 - 1);
        int s = sperm[jc];
        half4v ev = *(const half4v*)&ep[(size_t)jc * 64 + c0];
        half4v xv = *(const half4v*)&xin[(size_t)s * 64 + c0];
        if (j < j1) {
            acc.x += fmaxf((float)xv[0] + (float)ev[0], 0.f);
            acc.y += fmaxf((float)xv[1] + (float)ev[1], 0.f);
            acc.z += fmaxf((float)xv[2] + (float)ev[2], 0.f);
            acc.w += fmaxf((float)xv[3] + (float)ev[3], 0.f);
        }
    }
    acc.x += __shfl_xor(acc.x, 16); acc.x += __shfl_xor(acc.x, 32);
    acc.y += __shfl_xor(acc.y, 16); acc.y += __shfl_xor(acc.y, 32);
    acc.z += __shfl_xor(acc.z, 16); acc.z += __shfl_xor(acc.z, 32);
    acc.w += __shfl_xor(acc.w, 16); acc.w += __shfl_xor(acc.w, 32);
    if (g == 0) {
        float eps1 = 1.f + epsp[0];
        half4v xn = *(const half4v*)&xin[(size_t)n * 64 + c0];
        half4v o;
        o[0] = (_Float16)(eps1 * (float)xn[0] + acc.x);
        o[1] = (_Float16)(eps1 * (float)xn[1] + acc.y);
        o[2] = (_Float16)(eps1 * (float)xn[2] + acc.z);
        o[3] = (_Float16)(eps1 * (float)xn[3] + acc.w);
        *(half4v*)&hout[(size_t)n * 64 + c0] = o;
    }
}

// ---------------- TransformerConv, quad layout + e3 decomposition ----------
__global__ __launch_bounds__(256) void k_tconv3(
    const _Float16* __restrict__ qb, const _Float16* __restrict__ kb,
    const _Float16* __restrict__ vb, const _Float16* __restrict__ qtp,
    const float* __restrict__ we3, const float* __restrict__ ea,
    const int* __restrict__ offs, const int* __restrict__ perm,
    const int* __restrict__ sperm,
    float* __restrict__ skip_io)
{
    __shared__ float wa_s[4][32];
    int n = blockIdx.x;
    int t = threadIdx.x;
    int h = t >> 6;
    int lane = t & 63;
    int g = lane >> 4, li = lane & 15, c0 = li * 4;
    half4v qh = *(const half4v*)&qb[(size_t)n * 256 + h * 64 + c0];
    float qx = (float)qh[0] * 0.125f, qy = (float)qh[1] * 0.125f;
    float qz = (float)qh[2] * 0.125f, qw = (float)qh[3] * 0.125f;
    half2v q2 = *(const half2v*)&qtp[(size_t)n * 128 + h * 32 + li * 2];
    float qt0 = (float)q2[0], qt1 = (float)q2[1];
    int j0 = __builtin_amdgcn_readfirstlane(offs[n]);
    int j1 = __builtin_amdgcn_readfirstlane(offs[n + 1]);
    float l = 0.f, wa0 = 0.f, wa1 = 0.f;
    float4 acc = {0.f, 0.f, 0.f, 0.f};
    for (int jq = j0; jq < j1; jq += 4) {
        int j = jq + g;
        int jc = (j < j1) ? j : (j1 - 1);
        int e = perm[jc];
        int s = sperm[jc];
        float2 eav = *(const float2*)&ea[(size_t)e * 32 + li * 2];
        half4v kvh = *(const half4v*)&kb[(size_t)s * 256 + h * 64 + c0];
        float p = qx * (float)kvh[0] + qy * (float)kvh[1]
                + qz * (float)kvh[2] + qw * (float)kvh[3]
                + qt0 * eav.x + qt1 * eav.y;
        p += __shfl_xor(p, 1); p += __shfl_xor(p, 2);
        p += __shfl_xor(p, 4); p += __shfl_xor(p, 8);
        float w = (j < j1) ? __expf(p) : 0.f;   // logits O(0.5): no-max exact
        half4v vvh = *(const half4v*)&vb[(size_t)s * 256 + h * 64 + c0];
        l += w;
        acc.x = fmaf(w, (float)vvh[0], acc.x);
        acc.y = fmaf(w, (float)vvh[1], acc.y);
        acc.z = fmaf(w, (float)vvh[2], acc.z);
        acc.w = fmaf(w, (float)vvh[3], acc.w);
        wa0 = fmaf(w, eav.x, wa0);
        wa1 = fmaf(w, eav.y, wa1);
    }
    l   += __shfl_xor(l, 16);   l   += __shfl_xor(l, 32);
    wa0 += __shfl_xor(wa0, 16); wa0 += __shfl_xor(wa0, 32);
    wa1 += __shfl_xor(wa1, 16); wa1 += __shfl_xor(wa1, 32);
    acc.x += __shfl_xor(acc.x, 16); acc.x += __shfl_xor(acc.x, 32);
    acc.y += __shfl_xor(acc.y, 16); acc.y += __shfl_xor(acc.y, 32);
    acc.z += __shfl_xor(acc.z, 16); acc.z += __shfl_xor(acc.z, 32);
    acc.w += __shfl_xor(acc.w, 16); acc.w += __shfl_xor(acc.w, 32);
    if (g == 0) { wa_s[h][li * 2] = wa0; wa_s[h][li * 2 + 1] = wa1; }
    __syncthreads();
    float4 corr = {0.f, 0.f, 0.f, 0.f};
#pragma unroll
    for (int kk = 0; kk < 8; kk++) {
        int k = g * 8 + kk;
        float wv = wa_s[h][k];
        float4 w3 = *(const float4*)&we3[(size_t)k * 256 + h * 64 + c0];
        corr.x = fmaf(wv, w3.x, corr.x);
        corr.y = fmaf(wv, w3.y, corr.y);
        corr.z = fmaf(wv, w3.z, corr.z);
        corr.w = fmaf(wv, w3.w, corr.w);
    }
    corr.x += __shfl_xor(corr.x, 16); corr.x += __shfl_xor(corr.x, 32);
    corr.y += __shfl_xor(corr.y, 16); corr.y += __shfl_xor(corr.y, 32);
    corr.z += __shfl_xor(corr.z, 16); corr.z += __shfl_xor(corr.z, 32);
    corr.w += __shfl_xor(corr.w, 16); corr.w += __shfl_xor(corr.w, 32);
    if (g == 0) {
        float rl = 1.f / (l + 1e-16f);
        size_t o = (size_t)n * 256 + h * 64 + c0;
        float4 sk = *(const float4*)&skip_io[o];
        float4 outv;
        outv.x = (acc.x + corr.x) * rl + sk.x;
        outv.y = (acc.y + corr.y) * rl + sk.y;
        outv.z = (acc.z + corr.z) * rl + sk.z;
        outv.w = (acc.w + corr.w) * rl + sk.w;
        *(float4*)&skip_io[o] = outv;
    }
}

// ---------------- GATv2 aggregation, quad layout, fp16 operands ------------
__global__ __launch_bounds__(256) void k_gat2(
    const _Float16* __restrict__ xl, const _Float16* __restrict__ xr,
    const _Float16* __restrict__ e4p,
    const float* __restrict__ attv, const float* __restrict__ bias4,
    const int* __restrict__ offs, const int* __restrict__ sperm,
    float* __restrict__ out)
{
    int t = threadIdx.x;
    int wid  = __builtin_amdgcn_readfirstlane(t >> 6);
    int n    = blockIdx.x * 4 + wid;
    int lane = t & 63;
    int g = lane >> 4, li = lane & 15, c0 = li * 4;
    half4v xrh = *(const half4v*)&xr[(size_t)n * 64 + c0];
    float xr0 = (float)xrh[0], xr1 = (float)xrh[1];
    float xr2 = (float)xrh[2], xr3 = (float)xrh[3];
    float4 av  = *(const float4*)&attv[c0];
    int j0 = __builtin_amdgcn_readfirstlane(offs[n]);
    int j1 = __builtin_amdgcn_readfirstlane(offs[n + 1]);
    float l = 0.f;
    float4 acc = {0.f, 0.f, 0.f, 0.f};
    for (int jq = j0; jq < j1; jq += 4) {
        int j = jq + g;
        int jc = (j < j1) ? j : (j1 - 1);
        int s = sperm[jc];
        half4v ev = *(const half4v*)&e4p[(size_t)jc * 64 + c0];
        half4v xlv = *(const half4v*)&xl[(size_t)s * 64 + c0];
        float x0 = (float)xlv[0], x1 = (float)xlv[1];
        float x2 = (float)xlv[2], x3 = (float)xlv[3];
        float h0 = x0 + xr0 + (float)ev[0];
        float h1 = x1 + xr1 + (float)ev[1];
        float h2 = x2 + xr2 + (float)ev[2];
        float h3 = x3 + xr3 + (float)ev[3];
        h0 = (h0 > 0.f) ? h0 : 0.2f * h0;
        h1 = (h1 > 0.f) ? h1 : 0.2f * h1;
        h2 = (h2 > 0.f) ? h2 : 0.2f * h2;
        h3 = (h3 > 0.f) ? h3 : 0.2f * h3;
        float p = h0 * av.x + h1 * av.y + h2 * av.z + h3 * av.w;
        p += __shfl_xor(p, 1); p += __shfl_xor(p, 2);
        p += __shfl_xor(p, 4); p += __shfl_xor(p, 8);
        float w = (j < j1) ? __expf(p) : 0.f;   // logits O(0.5): no-max exact
        l += w;
        acc.x = fmaf(w, x0, acc.x);
        acc.y = fmaf(w, x1, acc.y);
        acc.z = fmaf(w, x2, acc.z);
        acc.w = fmaf(w, x3, acc.w);
    }
    l += __shfl_xor(l, 16); l += __shfl_xor(l, 32);
    acc.x += __shfl_xor(acc.x, 16); acc.x += __shfl_xor(acc.x, 32);
    acc.y += __shfl_xor(acc.y, 16); acc.y += __shfl_xor(acc.y, 32);
    acc.z += __shfl_xor(acc.z, 16); acc.z += __shfl_xor(acc.z, 32);
    acc.w += __shfl_xor(acc.w, 16); acc.w += __shfl_xor(acc.w, 32);
    if (g == 0) {
        float rl = 1.f / (l + 1e-16f);
        float4 bv = *(const float4*)&bias4[c0];
        float4 o;
        o.x = acc.x * rl + bv.x;
        o.y = acc.y * rl + bv.y;
        o.z = acc.z * rl + bv.z;
        o.w = acc.w * rl + bv.w;
        *(float4*)&out[(size_t)n * 64 + c0] = o;
    }
}

// ---------------------------------------------------------------------------
extern "C" void kernel_launch(void* const* d_in, const int* in_sizes, int n_in,
                              void* d_out, int out_size, void* d_ws, size_t ws_size,
                              hipStream_t stream)
{
    const float* x     = (const float*)d_in[0];
    const float* ea    = (const float*)d_in[1];
    const float* eps1  = (const float*)d_in[2];
    const float* w1a   = (const float*)d_in[3];
    const float* b1a   = (const float*)d_in[4];
    const float* w1b   = (const float*)d_in[5];
    const float* b1b   = (const float*)d_in[6];
    const float* we1   = (const float*)d_in[7];
    const float* be1   = (const float*)d_in[8];
    const float* eps2  = (const float*)d_in[9];
    const float* w2a   = (const float*)d_in[10];
    const float* b2a   = (const float*)d_in[11];
    const float* w2b   = (const float*)d_in[12];
    const float* b2b   = (const float*)d_in[13];
    const float* we2   = (const float*)d_in[14];
    const float* be2   = (const float*)d_in[15];
    const float* wq    = (const float*)d_in[16];
    const float* bq    = (const float*)d_in[17];
    const float* wk    = (const float*)d_in[18];
    const float* bk    = (const float*)d_in[19];
    const float* wv    = (const float*)d_in[20];
    const float* bv    = (const float*)d_in[21];
    const float* we3   = (const float*)d_in[22];
    const float* wskip = (const float*)d_in[23];
    const float* bskip = (const float*)d_in[24];
    const float* wl    = (const float*)d_in[25];
    const float* bl    = (const float*)d_in[26];
    const float* wr    = (const float*)d_in[27];
    const float* br    = (const float*)d_in[28];
    const float* we4   = (const float*)d_in[29];
    const float* attv  = (const float*)d_in[30];
    const float* bias4 = (const float*)d_in[31];
    const void*  eidx  = d_in[32];

    const int N = in_sizes[0] / 64;     // 32768
    const int E = in_sizes[1] / 32;     // 524288

    char* ws = (char*)d_ws;
    size_t off = 0;
    auto alloc = [&](size_t bytes) {
        void* p = ws + off;
        off += (bytes + 255) & ~(size_t)255;
        return p;
    };
    int* flag    = (int*)alloc(4);
    int* econv   = (int*)alloc((size_t)2 * E * 4);
    int* counts  = (int*)alloc((size_t)N * 4);
    int* cursor  = (int*)alloc((size_t)N * 4);
    int* offs    = (int*)alloc((size_t)(N + 1) * 4);
    int* perm    = (int*)alloc((size_t)E * 4);
    int* sperm   = (int*)alloc((size_t)E * 4);
    _Float16* xh  = (_Float16*)alloc((size_t)N * 64 * 2);
    _Float16* h16 = (_Float16*)alloc((size_t)N * 64 * 2);
    _Float16* x1h = (_Float16*)alloc((size_t)N * 64 * 2);
    _Float16* x2h = (_Float16*)alloc((size_t)N * 64 * 2);
    _Float16* Wtq = (_Float16*)alloc(16384 * 2);
    _Float16* Wtk = (_Float16*)alloc(16384 * 2);
    _Float16* Wtv = (_Float16*)alloc(16384 * 2);
    _Float16* Wts = (_Float16*)alloc(16384 * 2);
    _Float16* Wtl = (_Float16*)alloc(16384 * 2);
    _Float16* Wtr = (_Float16*)alloc(16384 * 2);
    _Float16* Wt1a = (_Float16*)alloc(4096 * 2);
    _Float16* Wt1b = (_Float16*)alloc(4096 * 2);
    _Float16* Wt2a = (_Float16*)alloc(2048 * 2);
    _Float16* Wt2b = (_Float16*)alloc(2048 * 2);
    _Float16* Mt   = (_Float16*)alloc(8192 * 2);
    float*    cst  = (float*)alloc(128 * 4);
    // big overlaid region R: e1p/e2p first, then q/k/v/skip/qt, then e4p
    char* R = (char*)alloc((size_t)2 * E * 64 * 2);
    _Float16* e1p   = (_Float16*)R;
    _Float16* e2p   = e1p + (size_t)E * 64;
    _Float16* qbh   = (_Float16*)R;
    _Float16* kbh   = qbh + (size_t)N * 256;
    _Float16* vbh   = kbh + (size_t)N * 256;
    float*    skipb = (float*)(R + (size_t)3 * N * 256 * 2);
    _Float16* qtp   = (_Float16*)(R + (size_t)3 * N * 256 * 2 + (size_t)N * 256 * 4);
    _Float16* e4p   = (_Float16*)R;
    _Float16* xlh   = h16;   // dead by GAT stage
    _Float16* xrh   = x1h;   // dead by GAT stage

    if (off > ws_size) return;   // workspace too small -> visible failure

    // weight prep + x fp16
    k_prep<<<256, 256, 0, stream>>>(x, N * 64, wq, wk, wv, wskip, wl, wr,
                                    w1a, w1b, w2a, w2b, we3, bq,
                                    xh, Wtq, Wtk, Wtv, Wts, Wtl, Wtr,
                                    Wt1a, Wt1b, Wt2a, Wt2b, Mt, cst);

    // edge_index dtype detect + convert to int32
    k_detect<<<1, 256, 0, stream>>>((const unsigned int*)eidx, flag);
    k_cvt<<<(2 * E + 255) / 256, 256, 0, stream>>>(eidx, flag, econv, 2 * E);
    const int* srcI = econv;
    const int* dstI = econv + E;

    // CSR by dst (+ sperm = src in perm order)
    hipMemsetAsync(counts, 0, (size_t)N * 4, stream);
    k_hist<<<(E + 255) / 256, 256, 0, stream>>>(dstI, counts, E);
    k_scan<<<1, 1024, 0, stream>>>(counts, offs, cursor, N);
    k_scatter<<<(E + 255) / 256, 256, 0, stream>>>(dstI, srcI, cursor, perm, sperm, E);

    // materialize e1, e2 (perm order, fp16)
    k_egv<<<E / 32, 256, 0, stream>>>(ea, perm, we1, be1, e1p, we2, be2, e2p, 1);

    // GINE 1 + MLP1
    k_gine2<<<N / 4, 256, 0, stream>>>(xh, e1p, eps1, offs, sperm, h16);
    k_mlp<64><<<N / 64, 256, 0, stream>>>(h16, Wt1a, b1a, Wt1b, b1b, x1h);

    // GINE 2 + MLP2
    k_gine2<<<N / 4, 256, 0, stream>>>(x1h, e2p, eps2, offs, sperm, h16);
    k_mlp<32><<<N / 64, 256, 0, stream>>>(h16, Wt2a, b2a, Wt2b, b2b, x2h);

    // TransformerConv (e1p/e2p dead -> q/k/v/skip/qt overlay)
    k_gemm4m<<<dim3(N / 64, 17), 256, 0, stream>>>(x2h,
                                                   Wtq, bq, Wtk, bk, Wtv, bv,
                                                   Wts, bskip, Mt, cst,
                                                   qbh, kbh, vbh, skipb, qtp);
    k_tconv3<<<N, 256, 0, stream>>>(qbh, kbh, vbh, qtp, we3, ea, offs, perm, sperm,
                                    skipb);

    // GATv2: projections first (skipb read), then e4p overlay, then agg
    k_gatgemm<<<dim3(N / 64, 2), 256, 0, stream>>>(skipb, Wtl, bl, Wtr, br, xlh, xrh);
    k_egv<<<E / 32, 256, 0, stream>>>(ea, perm, we4, (const float*)nullptr, e4p,
                                      (const float*)nullptr, (const float*)nullptr,
                                      (_Float16*)nullptr, 0);
    k_gat2<<<N / 4, 256, 0, stream>>>(xlh, xrh, e4p, attv, bias4, offs, sperm,
                                      (float*)d_out);
}

// Round 6
// 401.426 us; speedup vs baseline: 2.3356x; 1.2399x over previous
//
#include <hip/hip_runtime.h>
#include <math.h>

// ---------------------------------------------------------------------------
// N=32768 nodes, E=524288 edges, node feat 64, edge feat 32, H=4 x C=64 = 256.
// MFMA fragment maps (mfma_f32_16x16x32_f16):
//   A(16x32): lane l, reg j -> row=l&15,  k=(l>>4)*8+j
//   B(32x16): lane l, reg j -> col=l&15,  k=(l>>4)*8+j   (store W^T[col][k])
//   C/D:      lane l, reg r -> col=l&15,  row=(l>>4)*4+r
// ---------------------------------------------------------------------------

typedef __attribute__((ext_vector_type(2))) _Float16 half2v;
typedef __attribute__((ext_vector_type(4))) _Float16 half4v;
typedef __attribute__((ext_vector_type(8))) _Float16 half8v;
typedef __attribute__((ext_vector_type(4))) float float4v;

// ---------------- edge_index dtype detection + convert(+hist) --------------
__global__ void k_detect(const unsigned int* __restrict__ w, int* __restrict__ flag)
{
    __shared__ int any;
    if (threadIdx.x == 0) any = 0;
    __syncthreads();
    int found = 0;
    for (int i = threadIdx.x; i < 2048; i += 256)
        if (w[2 * i + 1] != 0u) found = 1;
    if (found) atomicOr(&any, 1);
    __syncthreads();
    if (threadIdx.x == 0) flag[0] = any ? 0 : 1;   // 1 => int64
}

__global__ void k_cvt(const void* __restrict__ eidx, const int* __restrict__ flag,
                      int* __restrict__ out, int* __restrict__ counts, int E)
{
    int i = blockIdx.x * blockDim.x + threadIdx.x;
    if (i >= 2 * E) return;
    int v = flag[0] ? (int)((const long long*)eidx)[i] : ((const int*)eidx)[i];
    out[i] = v;
    if (i >= E) atomicAdd(&counts[v], 1);    // dst histogram fused
}

// ---------------- CSR build (group edges by dst) ---------------------------
__global__ void k_scan(const int* __restrict__ counts, int* __restrict__ offs,
                       int* __restrict__ cursor, int N)
{
    __shared__ int part[1024];
    int t = threadIdx.x;
    int base = t * 32;
    int loc[32];
    int s = 0;
#pragma unroll
    for (int i = 0; i < 32; i++) { loc[i] = counts[base + i]; s += loc[i]; }
    part[t] = s;
    __syncthreads();
    for (int off = 1; off < 1024; off <<= 1) {
        int v = (t >= off) ? part[t - off] : 0;
        __syncthreads();
        part[t] += v;
        __syncthreads();
    }
    int run = part[t] - s;   // exclusive prefix
#pragma unroll
    for (int i = 0; i < 32; i++) {
        offs[base + i] = run;
        cursor[base + i] = run;
        run += loc[i];
    }
    if (t == 1023) offs[N] = run;
}

__global__ void k_scatter(const int* __restrict__ dst, const int* __restrict__ srcA,
                          int* __restrict__ cursor, int* __restrict__ perm,
                          int* __restrict__ sperm, int* __restrict__ pos, int E)
{
    int i = blockIdx.x * blockDim.x + threadIdx.x;
    if (i < E) {
        int d = dst[i];
        int p = atomicAdd(&cursor[d], 1);
        perm[p] = i;
        sperm[p] = srcA[i];
        pos[i] = p;
    }
}

// ---------------- eap: edge_attr -> fp16, perm order -----------------------
// seq read of ea, random full-64B-line writes via pos[].
__global__ __launch_bounds__(256) void k_eap(const float* __restrict__ ea,
                                             const int* __restrict__ pos,
                                             _Float16* __restrict__ eap)
{
    int t = threadIdx.x;
    int i = blockIdx.x * 64 + (t >> 2);
    int ks = (t & 3) * 8;
    float4 a0 = *(const float4*)&ea[(size_t)i * 32 + ks];
    float4 a1 = *(const float4*)&ea[(size_t)i * 32 + ks + 4];
    half8v h8;
    h8[0] = (_Float16)a0.x; h8[1] = (_Float16)a0.y;
    h8[2] = (_Float16)a0.z; h8[3] = (_Float16)a0.w;
    h8[4] = (_Float16)a1.x; h8[5] = (_Float16)a1.y;
    h8[6] = (_Float16)a1.z; h8[7] = (_Float16)a1.w;
    int p = pos[i];
    *(half8v*)&eap[(size_t)p * 32 + ks] = h8;
}

// ---------------- edge-linear via MFMA: ep = fp16(eap@We + be) -------------
// wave = 16 edges (seq A rows from eap). Wt layouts: [col<64][k<32] fp16.
__global__ __launch_bounds__(256) void k_emm(
    const _Float16* __restrict__ eap,
    const _Float16* __restrict__ WtA, const float* __restrict__ beA,
    _Float16* __restrict__ epA,
    const _Float16* __restrict__ WtB, const float* __restrict__ beB,
    _Float16* __restrict__ epB, int dual)
{
    int t = threadIdx.x;
    int wid = t >> 6, l = t & 63;
    int jb = (blockIdx.x * 4 + wid) * 16;
    int cr = l & 15, kg = l >> 4;
    half8v a = *(const half8v*)&eap[(size_t)(jb + cr) * 32 + kg * 8];
    int orow = kg * 4;
#pragma unroll
    for (int c = 0; c < 4; c++) {
        half8v b = *(const half8v*)&WtA[(size_t)(c * 16 + cr) * 32 + kg * 8];
        float4v d = __builtin_amdgcn_mfma_f32_16x16x32_f16(a, b, (float4v){0.f,0.f,0.f,0.f}, 0, 0, 0);
        int col = c * 16 + cr;
        float bv = beA ? beA[col] : 0.f;
#pragma unroll
        for (int r = 0; r < 4; r++)
            epA[(size_t)(jb + orow + r) * 64 + col] = (_Float16)(d[r] + bv);
    }
    if (dual) {
#pragma unroll
        for (int c = 0; c < 4; c++) {
            half8v b = *(const half8v*)&WtB[(size_t)(c * 16 + cr) * 32 + kg * 8];
            float4v d = __builtin_amdgcn_mfma_f32_16x16x32_f16(a, b, (float4v){0.f,0.f,0.f,0.f}, 0, 0, 0);
            int col = c * 16 + cr;
            float bv = beB ? beB[col] : 0.f;
#pragma unroll
            for (int r = 0; r < 4; r++)
                epB[(size_t)(jb + orow + r) * 64 + col] = (_Float16)(d[r] + bv);
        }
    }
}

// ---------------- edge-linear fallback (no eap): reads ea via perm ---------
__global__ __launch_bounds__(256) void k_egv(
    const float* __restrict__ ea, const int* __restrict__ perm,
    const float* __restrict__ weA, const float* __restrict__ beA,
    _Float16* __restrict__ epA,
    const float* __restrict__ weB, const float* __restrict__ beB,
    _Float16* __restrict__ epB, int dual)
{
    int t = threadIdx.x;
    int wid = t >> 6, lane = t & 63;
    float wA[32];
#pragma unroll
    for (int k = 0; k < 32; k++) wA[k] = weA[k * 64 + lane];
    float bAc = beA ? beA[lane] : 0.f;
    float wB[32];
    float bBc = 0.f;
    if (dual) {
#pragma unroll
        for (int k = 0; k < 32; k++) wB[k] = weB[k * 64 + lane];
        bBc = beB ? beB[lane] : 0.f;
    }
    int jbase = (blockIdx.x * 4 + wid) * 8;
    for (int u = 0; u < 8; u++) {
        int j = jbase + u;
        int e = __builtin_amdgcn_readfirstlane(perm[j]);
        const float4* ea4 = (const float4*)(ea + (size_t)e * 32);
        float eav[32];
#pragma unroll
        for (int w = 0; w < 8; w++) {
            float4 t4 = ea4[w];
            eav[4 * w] = t4.x; eav[4 * w + 1] = t4.y;
            eav[4 * w + 2] = t4.z; eav[4 * w + 3] = t4.w;
        }
        float vA = bAc;
#pragma unroll
        for (int k = 0; k < 32; k++) vA = fmaf(eav[k], wA[k], vA);
        epA[(size_t)j * 64 + lane] = (_Float16)vA;
        if (dual) {
            float vB = bBc;
#pragma unroll
            for (int k = 0; k < 32; k++) vB = fmaf(eav[k], wB[k], vB);
            epB[(size_t)j * 64 + lane] = (_Float16)vB;
        }
    }
}

// ---------------- weight prep ----------------------------------------------
__global__ __launch_bounds__(256) void k_prep(
    const float* __restrict__ x, int NX,
    const float* __restrict__ wq, const float* __restrict__ wk,
    const float* __restrict__ wv, const float* __restrict__ wskip,
    const float* __restrict__ wl, const float* __restrict__ wr,
    const float* __restrict__ w1a, const float* __restrict__ w1b,
    const float* __restrict__ w2a, const float* __restrict__ w2b,
    const float* __restrict__ we3, const float* __restrict__ bq,
    const float* __restrict__ we1, const float* __restrict__ we2,
    const float* __restrict__ we4,
    _Float16* __restrict__ xh,
    _Float16* __restrict__ Wtq, _Float16* __restrict__ Wtk,
    _Float16* __restrict__ Wtv, _Float16* __restrict__ Wts,
    _Float16* __restrict__ Wtl, _Float16* __restrict__ Wtr,
    _Float16* __restrict__ Wt1a, _Float16* __restrict__ Wt1b,
    _Float16* __restrict__ Wt2a, _Float16* __restrict__ Wt2b,
    _Float16* __restrict__ Mt, float* __restrict__ cst,
    _Float16* __restrict__ we3r,
    _Float16* __restrict__ Wt1e, _Float16* __restrict__ Wt2e,
    _Float16* __restrict__ Wt4e)
{
    int g = blockIdx.x * 256 + threadIdx.x;
    if (g < 16384) {                       // q/k/v/skip: Wt[c][k], c<256,k<64
        int c = g >> 6, k = g & 63;
        Wtq[g] = (_Float16)wq[(size_t)k * 256 + c];
        Wtk[g] = (_Float16)wk[(size_t)k * 256 + c];
        Wtv[g] = (_Float16)wv[(size_t)k * 256 + c];
        Wts[g] = (_Float16)wskip[(size_t)k * 256 + c];
    } else if (g < 32768) {                // wl/wr: Wt[c][k], c<64,k<256
        int q = g - 16384, c = q >> 8, k = q & 255;
        Wtl[q] = (_Float16)wl[(size_t)k * 64 + c];
        Wtr[q] = (_Float16)wr[(size_t)k * 64 + c];
    } else if (g < 36864) {                // w1a/w1b 64x64
        int q = g - 32768, m = q >> 6, k = q & 63;
        Wt1a[q] = (_Float16)w1a[(size_t)k * 64 + m];
        Wt1b[q] = (_Float16)w1b[(size_t)k * 64 + m];
    } else if (g < 38912) {                // w2a 64x32 -> Wt2a[m<32][k<64]
        int q = g - 36864, m = q >> 6, k = q & 63;
        Wt2a[q] = (_Float16)w2a[(size_t)k * 32 + m];
    } else if (g < 40960) {                // w2b 32x64 -> Wt2b[c<64][k<32]
        int q = g - 38912, c = q >> 5, k = q & 31;
        Wt2b[q] = (_Float16)w2b[(size_t)k * 64 + c];
    } else if (g < 49152) {                // Mt[m<128][d<64]
        int q = g - 40960, m = q >> 6, d = q & 63;
        int h = m >> 5, kk = m & 31;
        float s = 0.f;
        for (int c = 0; c < 64; c++)
            s = fmaf(wq[(size_t)d * 256 + h * 64 + c],
                     we3[(size_t)kk * 256 + h * 64 + c], s);
        Mt[q] = (_Float16)(0.125f * s);
    } else if (g < 49280) {                // cst[128]
        int m = g - 49152, h = m >> 5, kk = m & 31;
        float s = 0.f;
        for (int c = 0; c < 64; c++)
            s = fmaf(bq[h * 64 + c], we3[(size_t)kk * 256 + h * 64 + c], s);
        cst[m] = 0.125f * s;
    } else if (g < 57472) {                // we3r[kk<8][ph<2][lane<64][i<8]
        int q = g - 49280;
        int kk = q >> 10, ph = (q >> 9) & 1, lane = (q >> 3) & 63, i = q & 7;
        int slot = lane >> 4, hh = (lane >> 2) & 3, ss = lane & 3;
        we3r[q] = (_Float16)we3[(size_t)(slot * 8 + kk) * 256
                                + hh * 64 + ss * 16 + ph * 8 + i];
    } else if (g < 59520) {                // Wt1e[c<64][k<32]
        int q = g - 57472, c = q >> 5, k = q & 31;
        Wt1e[q] = (_Float16)we1[(size_t)k * 64 + c];
    } else if (g < 61568) {
        int q = g - 59520, c = q >> 5, k = q & 31;
        Wt2e[q] = (_Float16)we2[(size_t)k * 64 + c];
    } else if (g < 63616) {
        int q = g - 61568, c = q >> 5, k = q & 31;
        Wt4e[q] = (_Float16)we4[(size_t)k * 64 + c];
    }
    for (int i = g; i < NX; i += 256 * 256)
        xh[i] = (_Float16)x[i];
}

// ---------------- fused 2-layer MLP via MFMA -------------------------------
template<int MID>
__global__ __launch_bounds__(256) void k_mlp(
    const _Float16* __restrict__ A,
    const _Float16* __restrict__ Wt1, const float* __restrict__ b1,
    const _Float16* __restrict__ Wt2, const float* __restrict__ b2,
    _Float16* __restrict__ out)
{
    __shared__ _Float16 As[64][72];
    __shared__ _Float16 Ws1[MID][72];
    __shared__ _Float16 Ws2[64][MID + 8];
    __shared__ _Float16 mids[64][MID + 8];
    int t = threadIdx.x;
    int n0 = blockIdx.x * 64;
    for (int f = t; f < 512; f += 256) {
        int r = f >> 3, seg = f & 7;
        *(uint4*)&As[r][seg * 8] = *(const uint4*)&A[(size_t)(n0 + r) * 64 + seg * 8];
    }
    for (int f = t; f < MID * 8; f += 256) {
        int r = f >> 3, seg = f & 7;
        *(uint4*)&Ws1[r][seg * 8] = *(const uint4*)&Wt1[(size_t)r * 64 + seg * 8];
    }
    constexpr int CH = MID / 8;
    for (int f = t; f < 64 * CH; f += 256) {
        int r = f / CH, seg = f % CH;
        *(uint4*)&Ws2[r][seg * 8] = *(const uint4*)&Wt2[(size_t)r * MID + seg * 8];
    }
    __syncthreads();
    int w = t >> 6, l = t & 63;
    int arow = w * 16 + (l & 15);
    int kg = (l >> 4) * 8;
    int colg = l & 15;
    int orow = w * 16 + (l >> 4) * 4;
    half8v a0 = *(const half8v*)&As[arow][kg];
    half8v a1 = *(const half8v*)&As[arow][32 + kg];
    constexpr int NCT1 = MID / 16;
#pragma unroll
    for (int ct = 0; ct < NCT1; ct++) {
        half8v b0 = *(const half8v*)&Ws1[ct * 16 + colg][kg];
        half8v b1v = *(const half8v*)&Ws1[ct * 16 + colg][32 + kg];
        float4v acc = {0.f, 0.f, 0.f, 0.f};
        acc = __builtin_amdgcn_mfma_f32_16x16x32_f16(a0, b0, acc, 0, 0, 0);
        acc = __builtin_amdgcn_mfma_f32_16x16x32_f16(a1, b1v, acc, 0, 0, 0);
        int col = ct * 16 + colg;
        float bb = b1[col];
#pragma unroll
        for (int r = 0; r < 4; r++)
            mids[orow + r][col] = (_Float16)fmaxf(acc[r] + bb, 0.f);
    }
    __syncthreads();
    half8v m0 = *(const half8v*)&mids[arow][kg];
#pragma unroll
    for (int ct = 0; ct < 4; ct++) {
        half8v b0 = *(const half8v*)&Ws2[ct * 16 + colg][kg];
        float4v acc = {0.f, 0.f, 0.f, 0.f};
        acc = __builtin_amdgcn_mfma_f32_16x16x32_f16(m0, b0, acc, 0, 0, 0);
        if (MID == 64) {
            half8v m1 = *(const half8v*)&mids[arow][32 + kg];
            half8v b1v = *(const half8v*)&Ws2[ct * 16 + colg][32 + kg];
            acc = __builtin_amdgcn_mfma_f32_16x16x32_f16(m1, b1v, acc, 0, 0, 0);
        }
        int col = ct * 16 + colg;
        float bb = b2[col];
#pragma unroll
        for (int r = 0; r < 4; r++)
            out[(size_t)(n0 + orow + r) * 64 + col] = (_Float16)(acc[r] + bb);
    }
}

// ---------------- fused q/k/v/skip/qt projections via MFMA -----------------
__global__ __launch_bounds__(256) void k_gemm4m(
    const _Float16* __restrict__ A,
    const _Float16* __restrict__ Wtq, const float* __restrict__ bq,
    const _Float16* __restrict__ Wtk, const float* __restrict__ bk,
    const _Float16* __restrict__ Wtv, const float* __restrict__ bv,
    const _Float16* __restrict__ Wts, const float* __restrict__ bs,
    const _Float16* __restrict__ Mt,  const float* __restrict__ cst,
    _Float16* __restrict__ qbh, _Float16* __restrict__ kbh,
    _Float16* __restrict__ vbh, float* __restrict__ skipb,
    _Float16* __restrict__ qtp)
{
    __shared__ _Float16 As[64][72];
    __shared__ _Float16 Ws[128][72];
    int t = threadIdx.x;
    int n0 = blockIdx.x * 64;
    int y = blockIdx.y;
    for (int f = t; f < 512; f += 256) {
        int r = f >> 3, seg = f & 7;
        *(uint4*)&As[r][seg * 8] = *(const uint4*)&A[(size_t)(n0 + r) * 64 + seg * 8];
    }
    if (y < 16) {
        int p = y >> 2, j0 = (y & 3) * 64;
        const _Float16* Wt = (p == 0) ? Wtq : (p == 1) ? Wtk : (p == 2) ? Wtv : Wts;
        for (int f = t; f < 512; f += 256) {
            int c = f >> 3, seg = f & 7;
            *(uint4*)&Ws[c][seg * 8] = *(const uint4*)&Wt[(size_t)(j0 + c) * 64 + seg * 8];
        }
    } else {
        for (int f = t; f < 1024; f += 256) {
            int c = f >> 3, seg = f & 7;
            *(uint4*)&Ws[c][seg * 8] = *(const uint4*)&Mt[(size_t)c * 64 + seg * 8];
        }
    }
    __syncthreads();
    int w = t >> 6, l = t & 63;
    int arow = w * 16 + (l & 15);
    int kg = (l >> 4) * 8;
    int colg = l & 15;
    int orow = w * 16 + (l >> 4) * 4;
    half8v a0 = *(const half8v*)&As[arow][kg];
    half8v a1 = *(const half8v*)&As[arow][32 + kg];
    if (y < 16) {
        int p = y >> 2, j0 = (y & 3) * 64;
        const float* B = (p == 0) ? bq : (p == 1) ? bk : (p == 2) ? bv : bs;
        float4v acc[4];
#pragma unroll
        for (int ct = 0; ct < 4; ct++) {
            half8v b0 = *(const half8v*)&Ws[ct * 16 + colg][kg];
            half8v b1 = *(const half8v*)&Ws[ct * 16 + colg][32 + kg];
            float4v a = {0.f, 0.f, 0.f, 0.f};
            a = __builtin_amdgcn_mfma_f32_16x16x32_f16(a0, b0, a, 0, 0, 0);
            a = __builtin_amdgcn_mfma_f32_16x16x32_f16(a1, b1, a, 0, 0, 0);
            acc[ct] = a;
        }
#pragma unroll
        for (int ct = 0; ct < 4; ct++) {
            int col = j0 + ct * 16 + colg;
            float bb = B[col];
            if (p == 3) {
#pragma unroll
                for (int r = 0; r < 4; r++)
                    skipb[(size_t)(n0 + orow + r) * 256 + col] = acc[ct][r] + bb;
            } else {
                _Float16* O = (p == 0) ? qbh : (p == 1) ? kbh : vbh;
#pragma unroll
                for (int r = 0; r < 4; r++)
                    O[(size_t)(n0 + orow + r) * 256 + col] = (_Float16)(acc[ct][r] + bb);
            }
        }
    } else {
        float4v acc[8];
#pragma unroll
        for (int ct = 0; ct < 8; ct++) {
            half8v b0 = *(const half8v*)&Ws[ct * 16 + colg][kg];
            half8v b1 = *(const half8v*)&Ws[ct * 16 + colg][32 + kg];
            float4v a = {0.f, 0.f, 0.f, 0.f};
            a = __builtin_amdgcn_mfma_f32_16x16x32_f16(a0, b0, a, 0, 0, 0);
            a = __builtin_amdgcn_mfma_f32_16x16x32_f16(a1, b1, a, 0, 0, 0);
            acc[ct] = a;
        }
#pragma unroll
        for (int ct = 0; ct < 8; ct++) {
            int col = ct * 16 + colg;
            float bb = cst[col];
#pragma unroll
            for (int r = 0; r < 4; r++)
                qtp[(size_t)(n0 + orow + r) * 128 + col] = (_Float16)(acc[ct][r] + bb);
        }
    }
}

// ---------------- GAT xl/xr projections via MFMA ---------------------------
__global__ __launch_bounds__(256) void k_gatgemm(
    const float* __restrict__ A,
    const _Float16* __restrict__ WtL, const float* __restrict__ bL,
    const _Float16* __restrict__ WtR, const float* __restrict__ bR,
    _Float16* __restrict__ xlh, _Float16* __restrict__ xrh)
{
    __shared__ _Float16 As[64][136];
    __shared__ _Float16 Ws[64][136];
    int t = threadIdx.x;
    int n0 = blockIdx.x * 64;
    int y = blockIdx.y;
    const _Float16* Wt = y ? WtR : WtL;
    const float* bb = y ? bR : bL;
    _Float16* out = y ? xrh : xlh;
    int w = t >> 6, l = t & 63;
    int arow = w * 16 + (l & 15);
    int kg = (l >> 4) * 8;
    int colg = l & 15;
    int orow = w * 16 + (l >> 4) * 4;
    float4v acc[4] = {{0.f,0.f,0.f,0.f},{0.f,0.f,0.f,0.f},
                      {0.f,0.f,0.f,0.f},{0.f,0.f,0.f,0.f}};
    for (int kh = 0; kh < 2; kh++) {
        __syncthreads();
        for (int f = t; f < 2048; f += 256) {
            int r = f >> 5, seg = f & 31;
            float4 v = *(const float4*)&A[(size_t)(n0 + r) * 256 + kh * 128 + seg * 4];
            half4v hv;
            hv[0] = (_Float16)v.x; hv[1] = (_Float16)v.y;
            hv[2] = (_Float16)v.z; hv[3] = (_Float16)v.w;
            *(half4v*)&As[r][seg * 4] = hv;
        }
        for (int f = t; f < 1024; f += 256) {
            int c = f >> 4, seg = f & 15;
            *(uint4*)&Ws[c][seg * 8] = *(const uint4*)&Wt[(size_t)c * 256 + kh * 128 + seg * 8];
        }
        __syncthreads();
#pragma unroll
        for (int ks = 0; ks < 4; ks++) {
            half8v a = *(const half8v*)&As[arow][ks * 32 + kg];
#pragma unroll
            for (int ct = 0; ct < 4; ct++) {
                half8v b = *(const half8v*)&Ws[ct * 16 + colg][ks * 32 + kg];
                acc[ct] = __builtin_amdgcn_mfma_f32_16x16x32_f16(a, b, acc[ct], 0, 0, 0);
            }
        }
    }
#pragma unroll
    for (int ct = 0; ct < 4; ct++) {
        int col = ct * 16 + colg;
        float bv = bb[col];
#pragma unroll
        for (int r = 0; r < 4; r++)
            out[(size_t)(n0 + orow + r) * 64 + col] = (_Float16)(acc[ct][r] + bv);
    }
}

// ---------------- GINE aggregation, quad layout ----------------------------
__global__ __launch_bounds__(256) void k_gine2(
    const _Float16* __restrict__ xin, const _Float16* __restrict__ ep,
    const float* __restrict__ epsp,
    const int* __restrict__ offs, const int* __restrict__ sperm,
    _Float16* __restrict__ hout)
{
    int t = threadIdx.x;
    int wid  = __builtin_amdgcn_readfirstlane(t >> 6);
    int n    = blockIdx.x * 4 + wid;
    int lane = t & 63;
    int g = lane >> 4, li = lane & 15, c0 = li * 4;
    int j0 = __builtin_amdgcn_readfirstlane(offs[n]);
    int j1 = __builtin_amdgcn_readfirstlane(offs[n + 1]);
    float4 acc = {0.f, 0.f, 0.f, 0.f};
    for (int jq = j0; jq < j1; jq += 4) {
        int j = jq + g;
        int jc = (j < j1) ? j : (j1 - 1);
        int s = sperm[jc];
        half4v ev = *(const half4v*)&ep[(size_t)jc * 64 + c0];
        half4v xv = *(const half4v*)&xin[(size_t)s * 64 + c0];
        if (j < j1) {
            acc.x += fmaxf((float)xv[0] + (float)ev[0], 0.f);
            acc.y += fmaxf((float)xv[1] + (float)ev[1], 0.f);
            acc.z += fmaxf((float)xv[2] + (float)ev[2], 0.f);
            acc.w += fmaxf((float)xv[3] + (float)ev[3], 0.f);
        }
    }
    acc.x += __shfl_xor(acc.x, 16); acc.x += __shfl_xor(acc.x, 32);
    acc.y += __shfl_xor(acc.y, 16); acc.y += __shfl_xor(acc.y, 32);
    acc.z += __shfl_xor(acc.z, 16); acc.z += __shfl_xor(acc.z, 32);
    acc.w += __shfl_xor(acc.w, 16); acc.w += __shfl_xor(acc.w, 32);
    if (g == 0) {
        float eps1 = 1.f + epsp[0];
        half4v xn = *(const half4v*)&xin[(size_t)n * 64 + c0];
        half4v o;
        o[0] = (_Float16)(eps1 * (float)xn[0] + acc.x);
        o[1] = (_Float16)(eps1 * (float)xn[1] + acc.y);
        o[2] = (_Float16)(eps1 * (float)xn[2] + acc.z);
        o[3] = (_Float16)(eps1 * (float)xn[3] + acc.w);
        *(half4v*)&hout[(size_t)n * 64 + c0] = o;
    }
}

// ---------------- TransformerConv: wave = node, all 4 heads in-wave --------
// lane = slot(g)*16 + h*4 + sub; lane covers 16 contiguous ch (h*64+sub*16).
template<int USE_EAP>
__global__ __launch_bounds__(256) void k_tconv4(
    const _Float16* __restrict__ qb, const _Float16* __restrict__ kb,
    const _Float16* __restrict__ vb, const _Float16* __restrict__ qtp,
    const _Float16* __restrict__ we3r, const _Float16* __restrict__ eap,
    const float* __restrict__ ea, const int* __restrict__ perm,
    const int* __restrict__ offs, const int* __restrict__ sperm,
    float* __restrict__ skip_io)
{
    __shared__ _Float16 we3s[8192];       // [kk][ph][lane][8] conflict-free
    __shared__ float wa_s[4][4][32];
    int t = threadIdx.x;
    ((uint4*)we3s)[t]       = ((const uint4*)we3r)[t];
    ((uint4*)we3s)[t + 256] = ((const uint4*)we3r)[t + 256];
    ((uint4*)we3s)[t + 512] = ((const uint4*)we3r)[t + 512];
    ((uint4*)we3s)[t + 768] = ((const uint4*)we3r)[t + 768];
    int wid = __builtin_amdgcn_readfirstlane(t >> 6);
    int n = blockIdx.x * 4 + wid;
    int lane = t & 63;
    int g = lane >> 4, li = lane & 15;
    int h = li >> 2, sub = li & 3;
    int ch0 = h * 64 + sub * 16;
    float qs[16];
    {
        half8v q0 = *(const half8v*)&qb[(size_t)n * 256 + ch0];
        half8v q1 = *(const half8v*)&qb[(size_t)n * 256 + ch0 + 8];
#pragma unroll
        for (int i = 0; i < 8; i++) {
            qs[i] = (float)q0[i] * 0.125f;
            qs[8 + i] = (float)q1[i] * 0.125f;
        }
    }
    float qtf[8];
    {
        half8v qt8 = *(const half8v*)&qtp[(size_t)n * 128 + h * 32 + sub * 8];
#pragma unroll
        for (int i = 0; i < 8; i++) qtf[i] = (float)qt8[i];
    }
    int j0 = __builtin_amdgcn_readfirstlane(offs[n]);
    int j1 = __builtin_amdgcn_readfirstlane(offs[n + 1]);
    float l = 0.f;
    float acc[16] = {};
    float wa[8] = {};
    for (int jq = j0; jq < j1; jq += 4) {
        int j = jq + g;
        int jc = (j < j1) ? j : (j1 - 1);
        int s = sperm[jc];
        const _Float16* kr = &kb[(size_t)s * 256 + ch0];
        half8v k0 = *(const half8v*)kr;
        half8v k1 = *(const half8v*)(kr + 8);
        float ef[8];
        if (USE_EAP) {
            half8v e8 = *(const half8v*)&eap[(size_t)jc * 32 + sub * 8];
#pragma unroll
            for (int i = 0; i < 8; i++) ef[i] = (float)e8[i];
        } else {
            int e = perm[jc];
            float4 a0 = *(const float4*)&ea[(size_t)e * 32 + sub * 8];
            float4 a1 = *(const float4*)&ea[(size_t)e * 32 + sub * 8 + 4];
            ef[0] = a0.x; ef[1] = a0.y; ef[2] = a0.z; ef[3] = a0.w;
            ef[4] = a1.x; ef[5] = a1.y; ef[6] = a1.z; ef[7] = a1.w;
        }
        float p = 0.f;
#pragma unroll
        for (int i = 0; i < 8; i++)
            p += qs[i] * (float)k0[i] + qs[8 + i] * (float)k1[i];
#pragma unroll
        for (int i = 0; i < 8; i++) p += qtf[i] * ef[i];
        p += __shfl_xor(p, 1);
        p += __shfl_xor(p, 2);
        float w = (j < j1) ? __expf(p) : 0.f;    // logits O(0.5): no-max exact
        const _Float16* vr = &vb[(size_t)s * 256 + ch0];
        half8v v0 = *(const half8v*)vr;
        half8v v1 = *(const half8v*)(vr + 8);
        l += w;
#pragma unroll
        for (int i = 0; i < 8; i++) {
            acc[i] = fmaf(w, (float)v0[i], acc[i]);
            acc[8 + i] = fmaf(w, (float)v1[i], acc[8 + i]);
        }
#pragma unroll
        for (int i = 0; i < 8; i++) wa[i] = fmaf(w, ef[i], wa[i]);
    }
    // reduce over the 4 edge-slots
    l += __shfl_xor(l, 16); l += __shfl_xor(l, 32);
#pragma unroll
    for (int i = 0; i < 16; i++) {
        acc[i] += __shfl_xor(acc[i], 16);
        acc[i] += __shfl_xor(acc[i], 32);
    }
#pragma unroll
    for (int i = 0; i < 8; i++) {
        wa[i] += __shfl_xor(wa[i], 16);
        wa[i] += __shfl_xor(wa[i], 32);
    }
    if (g == 0) {
#pragma unroll
        for (int i = 0; i < 8; i++) wa_s[wid][h][sub * 8 + i] = wa[i];
    }
    __syncthreads();
    // corr = wa_h @ we3 for this lane's 16 channels; k split across slots
    float corr[16] = {};
#pragma unroll
    for (int kk = 0; kk < 8; kk++) {
        float wv = wa_s[wid][h][g * 8 + kk];
        half8v w3a = *(const half8v*)&we3s[kk * 1024 + lane * 8];
        half8v w3b = *(const half8v*)&we3s[kk * 1024 + 512 + lane * 8];
#pragma unroll
        for (int i = 0; i < 8; i++) {
            corr[i] = fmaf(wv, (float)w3a[i], corr[i]);
            corr[8 + i] = fmaf(wv, (float)w3b[i], corr[8 + i]);
        }
    }
#pragma unroll
    for (int i = 0; i < 16; i++) {
        corr[i] += __shfl_xor(corr[i], 16);
        corr[i] += __shfl_xor(corr[i], 32);
    }
    if (g == 0) {
        float rl = 1.f / (l + 1e-16f);
        size_t o = (size_t)n * 256 + ch0;
#pragma unroll
        for (int i = 0; i < 16; i += 4) {
            float4 sk = *(const float4*)&skip_io[o + i];
            float4 ov;
            ov.x = (acc[i]     + corr[i])     * rl + sk.x;
            ov.y = (acc[i + 1] + corr[i + 1]) * rl + sk.y;
            ov.z = (acc[i + 2] + corr[i + 2]) * rl + sk.z;
            ov.w = (acc[i + 3] + corr[i + 3]) * rl + sk.w;
            *(float4*)&skip_io[o + i] = ov;
        }
    }
}

// ---------------- GATv2 aggregation, quad layout ---------------------------
__global__ __launch_bounds__(256) void k_gat2(
    const _Float16* __restrict__ xl, const _Float16* __restrict__ xr,
    const _Float16* __restrict__ e4p,
    const float* __restrict__ attv, const float* __restrict__ bias4,
    const int* __restrict__ offs, const int* __restrict__ sperm,
    float* __restrict__ out)
{
    int t = threadIdx.x;
    int wid  = __builtin_amdgcn_readfirstlane(t >> 6);
    int n    = blockIdx.x * 4 + wid;
    int lane = t & 63;
    int g = lane >> 4, li = lane & 15, c0 = li * 4;
    half4v xrh = *(const half4v*)&xr[(size_t)n * 64 + c0];
    float xr0 = (float)xrh[0], xr1 = (float)xrh[1];
    float xr2 = (float)xrh[2], xr3 = (float)xrh[3];
    float4 av  = *(const float4*)&attv[c0];
    int j0 = __builtin_amdgcn_readfirstlane(offs[n]);
    int j1 = __builtin_amdgcn_readfirstlane(offs[n + 1]);
    float l = 0.f;
    float4 acc = {0.f, 0.f, 0.f, 0.f};
    for (int jq = j0; jq < j1; jq += 4) {
        int j = jq + g;
        int jc = (j < j1) ? j : (j1 - 1);
        int s = sperm[jc];
        half4v ev = *(const half4v*)&e4p[(size_t)jc * 64 + c0];
        half4v xlv = *(const half4v*)&xl[(size_t)s * 64 + c0];
        float x0 = (float)xlv[0], x1 = (float)xlv[1];
        float x2 = (float)xlv[2], x3 = (float)xlv[3];
        float h0 = x0 + xr0 + (float)ev[0];
        float h1 = x1 + xr1 + (float)ev[1];
        float h2 = x2 + xr2 + (float)ev[2];
        float h3 = x3 + xr3 + (float)ev[3];
        h0 = (h0 > 0.f) ? h0 : 0.2f * h0;
        h1 = (h1 > 0.f) ? h1 : 0.2f * h1;
        h2 = (h2 > 0.f) ? h2 : 0.2f * h2;
        h3 = (h3 > 0.f) ? h3 : 0.2f * h3;
        float p = h0 * av.x + h1 * av.y + h2 * av.z + h3 * av.w;
        p += __shfl_xor(p, 1); p += __shfl_xor(p, 2);
        p += __shfl_xor(p, 4); p += __shfl_xor(p, 8);
        float w = (j < j1) ? __expf(p) : 0.f;
        l += w;
        acc.x = fmaf(w, x0, acc.x);
        acc.y = fmaf(w, x1, acc.y);
        acc.z = fmaf(w, x2, acc.z);
        acc.w = fmaf(w, x3, acc.w);
    }
    l += __shfl_xor(l, 16); l += __shfl_xor(l, 32);
    acc.x += __shfl_xor(acc.x, 16); acc.x += __shfl_xor(acc.x, 32);
    acc.y += __shfl_xor(acc.y, 16); acc.y += __shfl_xor(acc.y, 32);
    acc.z += __shfl_xor(acc.z, 16); acc.z += __shfl_xor(acc.z, 32);
    acc.w += __shfl_xor(acc.w, 16); acc.w += __shfl_xor(acc.w, 32);
    if (g == 0) {
        float rl = 1.f / (l + 1e-16f);
        float4 bv = *(const float4*)&bias4[c0];
        float4 o;
        o.x = acc.x * rl + bv.x;
        o.y = acc.y * rl + bv.y;
        o.z = acc.z * rl + bv.z;
        o.w = acc.w * rl + bv.w;
        *(float4*)&out[(size_t)n * 64 + c0] = o;
    }
}

// ---------------------------------------------------------------------------
extern "C" void kernel_launch(void* const* d_in, const int* in_sizes, int n_in,
                              void* d_out, int out_size, void* d_ws, size_t ws_size,
                              hipStream_t stream)
{
    const float* x     = (const float*)d_in[0];
    const float* ea    = (const float*)d_in[1];
    const float* eps1  = (const float*)d_in[2];
    const float* w1a   = (const float*)d_in[3];
    const float* b1a   = (const float*)d_in[4];
    const float* w1b   = (const float*)d_in[5];
    const float* b1b   = (const float*)d_in[6];
    const float* we1   = (const float*)d_in[7];
    const float* be1   = (const float*)d_in[8];
    const float* eps2  = (const float*)d_in[9];
    const float* w2a   = (const float*)d_in[10];
    const float* b2a   = (const float*)d_in[11];
    const float* w2b   = (const float*)d_in[12];
    const float* b2b   = (const float*)d_in[13];
    const float* we2   = (const float*)d_in[14];
    const float* be2   = (const float*)d_in[15];
    const float* wq    = (const float*)d_in[16];
    const float* bq    = (const float*)d_in[17];
    const float* wk    = (const float*)d_in[18];
    const float* bk    = (const float*)d_in[19];
    const float* wv    = (const float*)d_in[20];
    const float* bv    = (const float*)d_in[21];
    const float* we3   = (const float*)d_in[22];
    const float* wskip = (const float*)d_in[23];
    const float* bskip = (const float*)d_in[24];
    const float* wl    = (const float*)d_in[25];
    const float* bl    = (const float*)d_in[26];
    const float* wr    = (const float*)d_in[27];
    const float* br    = (const float*)d_in[28];
    const float* we4   = (const float*)d_in[29];
    const float* attv  = (const float*)d_in[30];
    const float* bias4 = (const float*)d_in[31];
    const void*  eidx  = d_in[32];

    const int N = in_sizes[0] / 64;     // 32768
    const int E = in_sizes[1] / 32;     // 524288

    char* ws = (char*)d_ws;
    size_t off = 0;
    auto alloc = [&](size_t bytes) {
        void* p = ws + off;
        off += (bytes + 255) & ~(size_t)255;
        return p;
    };
    int* flag    = (int*)alloc(4);
    int* econv   = (int*)alloc((size_t)2 * E * 4);
    int* counts  = (int*)alloc((size_t)N * 4);
    int* cursor  = (int*)alloc((size_t)N * 4);
    int* offs    = (int*)alloc((size_t)(N + 1) * 4);
    int* perm    = (int*)alloc((size_t)E * 4);
    int* sperm   = (int*)alloc((size_t)E * 4);
    int* pos     = (int*)alloc((size_t)E * 4);
    _Float16* xh  = (_Float16*)alloc((size_t)N * 64 * 2);
    _Float16* h16 = (_Float16*)alloc((size_t)N * 64 * 2);
    _Float16* x1h = (_Float16*)alloc((size_t)N * 64 * 2);
    _Float16* x2h = (_Float16*)alloc((size_t)N * 64 * 2);
    _Float16* Wtq = (_Float16*)alloc(16384 * 2);
    _Float16* Wtk = (_Float16*)alloc(16384 * 2);
    _Float16* Wtv = (_Float16*)alloc(16384 * 2);
    _Float16* Wts = (_Float16*)alloc(16384 * 2);
    _Float16* Wtl = (_Float16*)alloc(16384 * 2);
    _Float16* Wtr = (_Float16*)alloc(16384 * 2);
    _Float16* Wt1a = (_Float16*)alloc(4096 * 2);
    _Float16* Wt1b = (_Float16*)alloc(4096 * 2);
    _Float16* Wt2a = (_Float16*)alloc(2048 * 2);
    _Float16* Wt2b = (_Float16*)alloc(2048 * 2);
    _Float16* Mt   = (_Float16*)alloc(8192 * 2);
    float*    cst  = (float*)alloc(128 * 4);
    _Float16* we3r = (_Float16*)alloc(8192 * 2);
    _Float16* Wt1e = (_Float16*)alloc(2048 * 2);
    _Float16* Wt2e = (_Float16*)alloc(2048 * 2);
    _Float16* Wt4e = (_Float16*)alloc(2048 * 2);
    // big overlaid region R
    char* R = (char*)alloc((size_t)2 * E * 64 * 2);      // 134.2 MB
    _Float16* e1p   = (_Float16*)R;
    _Float16* e2p   = e1p + (size_t)E * 64;
    _Float16* qbh   = (_Float16*)R;
    _Float16* kbh   = qbh + (size_t)N * 256;
    _Float16* vbh   = kbh + (size_t)N * 256;
    float*    skipb = (float*)(R + (size_t)3 * N * 256 * 2);
    _Float16* qtp   = (_Float16*)(R + (size_t)3 * N * 256 * 2 + (size_t)N * 256 * 4);
    _Float16* e4p   = (_Float16*)R;          // after gatgemm, over dead q/k/v+skip
    _Float16* xlh   = h16;
    _Float16* xrh   = x1h;
    size_t base_off = off;
    _Float16* eap = (_Float16*)alloc((size_t)E * 32 * 2);   // 33.5 MB, optional
    int use_eap = (off <= ws_size) ? 1 : 0;

    if (base_off > ws_size) return;   // catastrophic: visible failure

    // weight prep + x fp16
    k_prep<<<256, 256, 0, stream>>>(x, N * 64, wq, wk, wv, wskip, wl, wr,
                                    w1a, w1b, w2a, w2b, we3, bq, we1, we2, we4,
                                    xh, Wtq, Wtk, Wtv, Wts, Wtl, Wtr,
                                    Wt1a, Wt1b, Wt2a, Wt2b, Mt, cst,
                                    we3r, Wt1e, Wt2e, Wt4e);

    // edge_index: detect dtype, convert, histogram dst
    k_detect<<<1, 256, 0, stream>>>((const unsigned int*)eidx, flag);
    hipMemsetAsync(counts, 0, (size_t)N * 4, stream);
    k_cvt<<<(2 * E + 255) / 256, 256, 0, stream>>>(eidx, flag, econv, counts, E);
    const int* srcI = econv;
    const int* dstI = econv + E;

    // CSR by dst
    k_scan<<<1, 1024, 0, stream>>>(counts, offs, cursor, N);
    k_scatter<<<(E + 255) / 256, 256, 0, stream>>>(dstI, srcI, cursor, perm, sperm,
                                                   pos, E);

    // edge-linear materialization
    if (use_eap) {
        k_eap<<<E / 64, 256, 0, stream>>>(ea, pos, eap);
        k_emm<<<E / 64, 256, 0, stream>>>(eap, Wt1e, be1, e1p, Wt2e, be2, e2p, 1);
    } else {
        k_egv<<<E / 32, 256, 0, stream>>>(ea, perm, we1, be1, e1p, we2, be2, e2p, 1);
    }

    // GINE 1 + MLP1
    k_gine2<<<N / 4, 256, 0, stream>>>(xh, e1p, eps1, offs, sperm, h16);
    k_mlp<64><<<N / 64, 256, 0, stream>>>(h16, Wt1a, b1a, Wt1b, b1b, x1h);

    // GINE 2 + MLP2
    k_gine2<<<N / 4, 256, 0, stream>>>(x1h, e2p, eps2, offs, sperm, h16);
    k_mlp<32><<<N / 64, 256, 0, stream>>>(h16, Wt2a, b2a, Wt2b, b2b, x2h);

    // TransformerConv
    k_gemm4m<<<dim3(N / 64, 17), 256, 0, stream>>>(x2h,
                                                   Wtq, bq, Wtk, bk, Wtv, bv,
                                                   Wts, bskip, Mt, cst,
                                                   qbh, kbh, vbh, skipb, qtp);
    if (use_eap)
        k_tconv4<1><<<N / 4, 256, 0, stream>>>(qbh, kbh, vbh, qtp, we3r, eap,
                                               ea, perm, offs, sperm, skipb);
    else
        k_tconv4<0><<<N / 4, 256, 0, stream>>>(qbh, kbh, vbh, qtp, we3r, eap,
                                               ea, perm, offs, sperm, skipb);

    // GATv2: projections (skipb read) BEFORE e4p overlay, then aggregation
    k_gatgemm<<<dim3(N / 64, 2), 256, 0, stream>>>(skipb, Wtl, bl, Wtr, br, xlh, xrh);
    if (use_eap)
        k_emm<<<E / 64, 256, 0, stream>>>(eap, Wt4e, (const float*)nullptr, e4p,
                                          (const _Float16*)nullptr,
                                          (const float*)nullptr,
                                          (_Float16*)nullptr, 0);
    else
        k_egv<<<E / 32, 256, 0, stream>>>(ea, perm, we4, (const float*)nullptr, e4p,
                                          (const float*)nullptr,
                                          (const float*)nullptr,
                                          (_Float16*)nullptr, 0);
    k_gat2<<<N / 4, 256, 0, stream>>>(xlh, xrh, e4p, attv, bias4, offs, sperm,
                                      (float*)d_out);
}

// Round 7
// 343.896 us; speedup vs baseline: 2.7263x; 1.1673x over previous
//
#include <hip/hip_runtime.h>
#include <math.h>

// ---------------------------------------------------------------------------
// N=32768 nodes, E=524288 edges, node feat 64, edge feat 32, H=4 x C=64 = 256.
// MFMA fragment maps (mfma_f32_16x16x32_f16):
//   A(16x32): lane l, reg j -> row=l&15,  k=(l>>4)*8+j
//   B(32x16): lane l, reg j -> col=l&15,  k=(l>>4)*8+j   (store W^T[col][k])
//   C/D:      lane l, reg r -> col=l&15,  row=(l>>4)*4+r
// TransformerConv decomposition (softmax cancels per-(n,h) constants):
//   logit = Y[n]·x2[s] + (0.125 Wk_h bq_h)·x2[s] + qtp[n]·ea   (Y = 0.125 x2·WqWk^T)
//   msg   = (Σw x2[s])@Wv_h + l·bv + (Σw ea)@We3_h             (k_tpost, K=96 MFMA)
// ---------------------------------------------------------------------------

typedef __attribute__((ext_vector_type(2))) _Float16 half2v;
typedef __attribute__((ext_vector_type(4))) _Float16 half4v;
typedef __attribute__((ext_vector_type(8))) _Float16 half8v;
typedef __attribute__((ext_vector_type(4))) float float4v;

// ---------------- edge_index dtype detection + convert(+hist) --------------
__global__ void k_detect(const unsigned int* __restrict__ w, int* __restrict__ flag)
{
    __shared__ int any;
    if (threadIdx.x == 0) any = 0;
    __syncthreads();
    int found = 0;
    for (int i = threadIdx.x; i < 2048; i += 256)
        if (w[2 * i + 1] != 0u) found = 1;
    if (found) atomicOr(&any, 1);
    __syncthreads();
    if (threadIdx.x == 0) flag[0] = any ? 0 : 1;   // 1 => int64
}

__global__ void k_cvt(const void* __restrict__ eidx, const int* __restrict__ flag,
                      int* __restrict__ out, int* __restrict__ counts, int E)
{
    int i = blockIdx.x * blockDim.x + threadIdx.x;
    if (i >= 2 * E) return;
    int v = flag[0] ? (int)((const long long*)eidx)[i] : ((const int*)eidx)[i];
    out[i] = v;
    if (i >= E) atomicAdd(&counts[v], 1);    // dst histogram fused
}

// ---------------- CSR build ------------------------------------------------
__global__ void k_scan(const int* __restrict__ counts, int* __restrict__ offs,
                       int* __restrict__ cursor, int N)
{
    __shared__ int part[1024];
    int t = threadIdx.x;
    int base = t * 32;
    int loc[32];
    int s = 0;
#pragma unroll
    for (int i = 0; i < 32; i++) { loc[i] = counts[base + i]; s += loc[i]; }
    part[t] = s;
    __syncthreads();
    for (int off = 1; off < 1024; off <<= 1) {
        int v = (t >= off) ? part[t - off] : 0;
        __syncthreads();
        part[t] += v;
        __syncthreads();
    }
    int run = part[t] - s;
#pragma unroll
    for (int i = 0; i < 32; i++) {
        offs[base + i] = run;
        cursor[base + i] = run;
        run += loc[i];
    }
    if (t == 1023) offs[N] = run;
}

// scatter + fused eap (edge_attr fp16 in perm order)
template<int WEAP>
__global__ void k_scatter(const int* __restrict__ dst, const int* __restrict__ srcA,
                          int* __restrict__ cursor, int* __restrict__ perm,
                          int* __restrict__ sperm, const float* __restrict__ ea,
                          _Float16* __restrict__ eap, int E)
{
    int i = blockIdx.x * blockDim.x + threadIdx.x;
    if (i >= E) return;
    int d = dst[i];
    int p = atomicAdd(&cursor[d], 1);
    perm[p] = i;
    sperm[p] = srcA[i];
    if (WEAP) {
        const float4* r = (const float4*)(ea + (size_t)i * 32);
        half8v* o = (half8v*)(eap + (size_t)p * 32);
#pragma unroll
        for (int w = 0; w < 4; w++) {
            float4 a = r[2 * w], b = r[2 * w + 1];
            half8v h8;
            h8[0] = (_Float16)a.x; h8[1] = (_Float16)a.y;
            h8[2] = (_Float16)a.z; h8[3] = (_Float16)a.w;
            h8[4] = (_Float16)b.x; h8[5] = (_Float16)b.y;
            h8[6] = (_Float16)b.z; h8[7] = (_Float16)b.w;
            o[w] = h8;
        }
    }
}

// ---------------- edge-linear via MFMA: ep = fp16(eap@We + be) -------------
__global__ __launch_bounds__(256) void k_emm(
    const _Float16* __restrict__ eap,
    const _Float16* __restrict__ WtA, const float* __restrict__ beA,
    _Float16* __restrict__ epA,
    const _Float16* __restrict__ WtB, const float* __restrict__ beB,
    _Float16* __restrict__ epB, int dual)
{
    int t = threadIdx.x;
    int wid = t >> 6, l = t & 63;
    int jb = (blockIdx.x * 4 + wid) * 16;
    int cr = l & 15, kg = l >> 4;
    half8v a = *(const half8v*)&eap[(size_t)(jb + cr) * 32 + kg * 8];
    int orow = kg * 4;
#pragma unroll
    for (int c = 0; c < 4; c++) {
        half8v b = *(const half8v*)&WtA[(size_t)(c * 16 + cr) * 32 + kg * 8];
        float4v d = __builtin_amdgcn_mfma_f32_16x16x32_f16(a, b, (float4v){0.f,0.f,0.f,0.f}, 0, 0, 0);
        int col = c * 16 + cr;
        float bv = beA ? beA[col] : 0.f;
#pragma unroll
        for (int r = 0; r < 4; r++)
            epA[(size_t)(jb + orow + r) * 64 + col] = (_Float16)(d[r] + bv);
    }
    if (dual) {
#pragma unroll
        for (int c = 0; c < 4; c++) {
            half8v b = *(const half8v*)&WtB[(size_t)(c * 16 + cr) * 32 + kg * 8];
            float4v d = __builtin_amdgcn_mfma_f32_16x16x32_f16(a, b, (float4v){0.f,0.f,0.f,0.f}, 0, 0, 0);
            int col = c * 16 + cr;
            float bv = beB ? beB[col] : 0.f;
#pragma unroll
            for (int r = 0; r < 4; r++)
                epB[(size_t)(jb + orow + r) * 64 + col] = (_Float16)(d[r] + bv);
        }
    }
}

// ---------------- edge-linear fallback (no eap) ----------------------------
__global__ __launch_bounds__(256) void k_egv(
    const float* __restrict__ ea, const int* __restrict__ perm,
    const float* __restrict__ weA, const float* __restrict__ beA,
    _Float16* __restrict__ epA,
    const float* __restrict__ weB, const float* __restrict__ beB,
    _Float16* __restrict__ epB, int dual)
{
    int t = threadIdx.x;
    int wid = t >> 6, lane = t & 63;
    float wA[32];
#pragma unroll
    for (int k = 0; k < 32; k++) wA[k] = weA[k * 64 + lane];
    float bAc = beA ? beA[lane] : 0.f;
    float wB[32];
    float bBc = 0.f;
    if (dual) {
#pragma unroll
        for (int k = 0; k < 32; k++) wB[k] = weB[k * 64 + lane];
        bBc = beB ? beB[lane] : 0.f;
    }
    int jbase = (blockIdx.x * 4 + wid) * 8;
    for (int u = 0; u < 8; u++) {
        int j = jbase + u;
        int e = __builtin_amdgcn_readfirstlane(perm[j]);
        const float4* ea4 = (const float4*)(ea + (size_t)e * 32);
        float eav[32];
#pragma unroll
        for (int w = 0; w < 8; w++) {
            float4 t4 = ea4[w];
            eav[4 * w] = t4.x; eav[4 * w + 1] = t4.y;
            eav[4 * w + 2] = t4.z; eav[4 * w + 3] = t4.w;
        }
        float vA = bAc;
#pragma unroll
        for (int k = 0; k < 32; k++) vA = fmaf(eav[k], wA[k], vA);
        epA[(size_t)j * 64 + lane] = (_Float16)vA;
        if (dual) {
            float vB = bBc;
#pragma unroll
            for (int k = 0; k < 32; k++) vB = fmaf(eav[k], wB[k], vB);
            epB[(size_t)j * 64 + lane] = (_Float16)vB;
        }
    }
}

// ---------------- weight prep ----------------------------------------------
__global__ __launch_bounds__(256) void k_prep(
    const float* __restrict__ x, int NX,
    const float* __restrict__ wq, const float* __restrict__ wk,
    const float* __restrict__ wv, const float* __restrict__ wskip,
    const float* __restrict__ wl, const float* __restrict__ wr,
    const float* __restrict__ w1a, const float* __restrict__ w1b,
    const float* __restrict__ w2a, const float* __restrict__ w2b,
    const float* __restrict__ we3, const float* __restrict__ bq,
    const float* __restrict__ we1, const float* __restrict__ we2,
    const float* __restrict__ we4,
    _Float16* __restrict__ xh,
    _Float16* __restrict__ Wts, _Float16* __restrict__ Gt,
    _Float16* __restrict__ Wtl, _Float16* __restrict__ Wtr,
    _Float16* __restrict__ Wt1a, _Float16* __restrict__ Wt1b,
    _Float16* __restrict__ Wt2a, _Float16* __restrict__ Wt2b,
    _Float16* __restrict__ Mt, float* __restrict__ cst,
    _Float16* __restrict__ Wt1e, _Float16* __restrict__ Wt2e,
    _Float16* __restrict__ Wt4e, float* __restrict__ zt,
    _Float16* __restrict__ Bt3)
{
    int g = blockIdx.x * 256 + threadIdx.x;
    if (g < 16384) {                       // Wts[c<256][k<64]
        int c = g >> 6, k = g & 63;
        Wts[g] = (_Float16)wskip[(size_t)k * 256 + c];
    } else if (g < 32768) {                // Gt[col<256][d<64] = 0.125 WqWk^T
        int q = g - 16384, col = q >> 6, d = q & 63;
        int h = col >> 6, c = col & 63;
        float s = 0.f;
        for (int mq = 0; mq < 64; mq++)
            s = fmaf(wq[(size_t)d * 256 + h * 64 + mq],
                     wk[(size_t)c * 256 + h * 64 + mq], s);
        Gt[q] = (_Float16)(0.125f * s);
    } else if (g < 49152) {                // wl/wr: Wt[c<64][k<256]
        int q = g - 32768, c = q >> 8, k = q & 255;
        Wtl[q] = (_Float16)wl[(size_t)k * 64 + c];
        Wtr[q] = (_Float16)wr[(size_t)k * 64 + c];
    } else if (g < 53248) {                // w1a/w1b 64x64
        int q = g - 49152, m = q >> 6, k = q & 63;
        Wt1a[q] = (_Float16)w1a[(size_t)k * 64 + m];
        Wt1b[q] = (_Float16)w1b[(size_t)k * 64 + m];
    } else if (g < 55296) {                // w2a -> Wt2a[m<32][k<64]
        int q = g - 53248, m = q >> 6, k = q & 63;
        Wt2a[q] = (_Float16)w2a[(size_t)k * 32 + m];
    } else if (g < 57344) {                // w2b -> Wt2b[c<64][k<32]
        int q = g - 55296, c = q >> 5, k = q & 31;
        Wt2b[q] = (_Float16)w2b[(size_t)k * 64 + c];
    } else if (g < 65536) {                // Mt[m<128][d<64]
        int q = g - 57344, m = q >> 6, d = q & 63;
        int h = m >> 5, kk = m & 31;
        float s = 0.f;
        for (int c = 0; c < 64; c++)
            s = fmaf(wq[(size_t)d * 256 + h * 64 + c],
                     we3[(size_t)kk * 256 + h * 64 + c], s);
        Mt[q] = (_Float16)(0.125f * s);
    } else if (g < 65664) {                // cst[128]
        int m = g - 65536, h = m >> 5, kk = m & 31;
        float s = 0.f;
        for (int c = 0; c < 64; c++)
            s = fmaf(bq[h * 64 + c], we3[(size_t)kk * 256 + h * 64 + c], s);
        cst[m] = 0.125f * s;
    } else if (g < 67712) {                // Wt1e[c<64][k<32]
        int q = g - 65664, c = q >> 5, k = q & 31;
        Wt1e[q] = (_Float16)we1[(size_t)k * 64 + c];
    } else if (g < 69760) {
        int q = g - 67712, c = q >> 5, k = q & 31;
        Wt2e[q] = (_Float16)we2[(size_t)k * 64 + c];
    } else if (g < 71808) {
        int q = g - 69760, c = q >> 5, k = q & 31;
        Wt4e[q] = (_Float16)we4[(size_t)k * 64 + c];
    } else if (g < 72064) {                // zt[h*64+c] = 0.125 Wk_h^T bq_h
        int q = g - 71808, h = q >> 6, c = q & 63;
        float s = 0.f;
        for (int mq = 0; mq < 64; mq++)
            s = fmaf(wk[(size_t)c * 256 + h * 64 + mq], bq[h * 64 + mq], s);
        zt[q] = 0.125f * s;
    } else if (g < 96640) {                // Bt3[(h*64+col)*96 + k]
        int q = g - 72064;
        int hc = q / 96, k = q - hc * 96;
        int h = hc >> 6, col = hc & 63;
        float v = (k < 64) ? wv[(size_t)k * 256 + h * 64 + col]
                           : we3[(size_t)(k - 64) * 256 + h * 64 + col];
        Bt3[q] = (_Float16)v;
    }
    for (int i = g; i < NX; i += 512 * 256)
        xh[i] = (_Float16)x[i];
}

// ---------------- fused 2-layer MLP via MFMA -------------------------------
template<int MID>
__global__ __launch_bounds__(256) void k_mlp(
    const _Float16* __restrict__ A,
    const _Float16* __restrict__ Wt1, const float* __restrict__ b1,
    const _Float16* __restrict__ Wt2, const float* __restrict__ b2,
    _Float16* __restrict__ out)
{
    __shared__ _Float16 As[64][72];
    __shared__ _Float16 Ws1[MID][72];
    __shared__ _Float16 Ws2[64][MID + 8];
    __shared__ _Float16 mids[64][MID + 8];
    int t = threadIdx.x;
    int n0 = blockIdx.x * 64;
    for (int f = t; f < 512; f += 256) {
        int r = f >> 3, seg = f & 7;
        *(uint4*)&As[r][seg * 8] = *(const uint4*)&A[(size_t)(n0 + r) * 64 + seg * 8];
    }
    for (int f = t; f < MID * 8; f += 256) {
        int r = f >> 3, seg = f & 7;
        *(uint4*)&Ws1[r][seg * 8] = *(const uint4*)&Wt1[(size_t)r * 64 + seg * 8];
    }
    constexpr int CH = MID / 8;
    for (int f = t; f < 64 * CH; f += 256) {
        int r = f / CH, seg = f % CH;
        *(uint4*)&Ws2[r][seg * 8] = *(const uint4*)&Wt2[(size_t)r * MID + seg * 8];
    }
    __syncthreads();
    int w = t >> 6, l = t & 63;
    int arow = w * 16 + (l & 15);
    int kg = (l >> 4) * 8;
    int colg = l & 15;
    int orow = w * 16 + (l >> 4) * 4;
    half8v a0 = *(const half8v*)&As[arow][kg];
    half8v a1 = *(const half8v*)&As[arow][32 + kg];
    constexpr int NCT1 = MID / 16;
#pragma unroll
    for (int ct = 0; ct < NCT1; ct++) {
        half8v b0 = *(const half8v*)&Ws1[ct * 16 + colg][kg];
        half8v b1v = *(const half8v*)&Ws1[ct * 16 + colg][32 + kg];
        float4v acc = {0.f, 0.f, 0.f, 0.f};
        acc = __builtin_amdgcn_mfma_f32_16x16x32_f16(a0, b0, acc, 0, 0, 0);
        acc = __builtin_amdgcn_mfma_f32_16x16x32_f16(a1, b1v, acc, 0, 0, 0);
        int col = ct * 16 + colg;
        float bb = b1[col];
#pragma unroll
        for (int r = 0; r < 4; r++)
            mids[orow + r][col] = (_Float16)fmaxf(acc[r] + bb, 0.f);
    }
    __syncthreads();
    half8v m0 = *(const half8v*)&mids[arow][kg];
#pragma unroll
    for (int ct = 0; ct < 4; ct++) {
        half8v b0 = *(const half8v*)&Ws2[ct * 16 + colg][kg];
        float4v acc = {0.f, 0.f, 0.f, 0.f};
        acc = __builtin_amdgcn_mfma_f32_16x16x32_f16(m0, b0, acc, 0, 0, 0);
        if (MID == 64) {
            half8v m1 = *(const half8v*)&mids[arow][32 + kg];
            half8v b1v = *(const half8v*)&Ws2[ct * 16 + colg][32 + kg];
            acc = __builtin_amdgcn_mfma_f32_16x16x32_f16(m1, b1v, acc, 0, 0, 0);
        }
        int col = ct * 16 + colg;
        float bb = b2[col];
#pragma unroll
        for (int r = 0; r < 4; r++)
            out[(size_t)(n0 + orow + r) * 64 + col] = (_Float16)(acc[r] + bb);
    }
}

// ---------------- fused Y/skip/qt projections via MFMA ---------------------
// grid (N/64, 9): y<4 -> Y tile; y<8 -> skip tile; y==8 -> qt.
__global__ __launch_bounds__(256) void k_gemm4m(
    const _Float16* __restrict__ A,
    const _Float16* __restrict__ Gt,
    const _Float16* __restrict__ Wts, const float* __restrict__ bs,
    const _Float16* __restrict__ Mt,  const float* __restrict__ cst,
    _Float16* __restrict__ Yb, _Float16* __restrict__ skiph,
    _Float16* __restrict__ qtp)
{
    __shared__ _Float16 As[64][72];
    __shared__ _Float16 Ws[128][72];
    int t = threadIdx.x;
    int n0 = blockIdx.x * 64;
    int y = blockIdx.y;
    for (int f = t; f < 512; f += 256) {
        int r = f >> 3, seg = f & 7;
        *(uint4*)&As[r][seg * 8] = *(const uint4*)&A[(size_t)(n0 + r) * 64 + seg * 8];
    }
    if (y < 8) {
        int j0 = (y & 3) * 64;
        const _Float16* Wt = (y < 4) ? Gt : Wts;
        for (int f = t; f < 512; f += 256) {
            int c = f >> 3, seg = f & 7;
            *(uint4*)&Ws[c][seg * 8] = *(const uint4*)&Wt[(size_t)(j0 + c) * 64 + seg * 8];
        }
    } else {
        for (int f = t; f < 1024; f += 256) {
            int c = f >> 3, seg = f & 7;
            *(uint4*)&Ws[c][seg * 8] = *(const uint4*)&Mt[(size_t)c * 64 + seg * 8];
        }
    }
    __syncthreads();
    int w = t >> 6, l = t & 63;
    int arow = w * 16 + (l & 15);
    int kg = (l >> 4) * 8;
    int colg = l & 15;
    int orow = w * 16 + (l >> 4) * 4;
    half8v a0 = *(const half8v*)&As[arow][kg];
    half8v a1 = *(const half8v*)&As[arow][32 + kg];
    if (y < 8) {
        int j0 = (y & 3) * 64;
        _Float16* O = (y < 4) ? Yb : skiph;
#pragma unroll
        for (int ct = 0; ct < 4; ct++) {
            half8v b0 = *(const half8v*)&Ws[ct * 16 + colg][kg];
            half8v b1 = *(const half8v*)&Ws[ct * 16 + colg][32 + kg];
            float4v a = {0.f, 0.f, 0.f, 0.f};
            a = __builtin_amdgcn_mfma_f32_16x16x32_f16(a0, b0, a, 0, 0, 0);
            a = __builtin_amdgcn_mfma_f32_16x16x32_f16(a1, b1, a, 0, 0, 0);
            int col = j0 + ct * 16 + colg;
            float bb = (y < 4) ? 0.f : bs[col];
#pragma unroll
            for (int r = 0; r < 4; r++)
                O[(size_t)(n0 + orow + r) * 256 + col] = (_Float16)(a[r] + bb);
        }
    } else {
#pragma unroll
        for (int ct = 0; ct < 8; ct++) {
            half8v b0 = *(const half8v*)&Ws[ct * 16 + colg][kg];
            half8v b1 = *(const half8v*)&Ws[ct * 16 + colg][32 + kg];
            float4v a = {0.f, 0.f, 0.f, 0.f};
            a = __builtin_amdgcn_mfma_f32_16x16x32_f16(a0, b0, a, 0, 0, 0);
            a = __builtin_amdgcn_mfma_f32_16x16x32_f16(a1, b1, a, 0, 0, 0);
            int col = ct * 16 + colg;
            float bb = cst[col];
#pragma unroll
            for (int r = 0; r < 4; r++)
                qtp[(size_t)(n0 + orow + r) * 128 + col] = (_Float16)(a[r] + bb);
        }
    }
}

// ---------------- GINE aggregation, quad layout ----------------------------
__global__ __launch_bounds__(256) void k_gine2(
    const _Float16* __restrict__ xin, const _Float16* __restrict__ ep,
    const float* __restrict__ epsp,
    const int* __restrict__ offs, const int* __restrict__ sperm,
    _Float16* __restrict__ hout)
{
    int t = threadIdx.x;
    int wid  = __builtin_amdgcn_readfirstlane(t >> 6);
    int n    = blockIdx.x * 4 + wid;
    int lane = t & 63;
    int g = lane >> 4, li = lane & 15, c0 = li * 4;
    int j0 = __builtin_amdgcn_readfirstlane(offs[n]);
    int j1 = __builtin_amdgcn_readfirstlane(offs[n + 1]);
    float4 acc = {0.f, 0.f, 0.f, 0.f};
    for (int jq = j0; jq < j1; jq += 4) {
        int j = jq + g;
        int jc = (j < j1) ? j : (j1 - 1);
        int s = sperm[jc];
        half4v ev = *(const half4v*)&ep[(size_t)jc * 64 + c0];
        half4v xv = *(const half4v*)&xin[(size_t)s * 64 + c0];
        if (j < j1) {
            acc.x += fmaxf((float)xv[0] + (float)ev[0], 0.f);
            acc.y += fmaxf((float)xv[1] + (float)ev[1], 0.f);
            acc.z += fmaxf((float)xv[2] + (float)ev[2], 0.f);
            acc.w += fmaxf((float)xv[3] + (float)ev[3], 0.f);
        }
    }
    acc.x += __shfl_xor(acc.x, 16); acc.x += __shfl_xor(acc.x, 32);
    acc.y += __shfl_xor(acc.y, 16); acc.y += __shfl_xor(acc.y, 32);
    acc.z += __shfl_xor(acc.z, 16); acc.z += __shfl_xor(acc.z, 32);
    acc.w += __shfl_xor(acc.w, 16); acc.w += __shfl_xor(acc.w, 32);
    if (g == 0) {
        float eps1 = 1.f + epsp[0];
        half4v xn = *(const half4v*)&xin[(size_t)n * 64 + c0];
        half4v o;
        o[0] = (_Float16)(eps1 * (float)xn[0] + acc.x);
        o[1] = (_Float16)(eps1 * (float)xn[1] + acc.y);
        o[2] = (_Float16)(eps1 * (float)xn[2] + acc.z);
        o[3] = (_Float16)(eps1 * (float)xn[3] + acc.w);
        *(half4v*)&hout[(size_t)n * 64 + c0] = o;
    }
}

// ---------------- TransformerConv core: x2-gather only ---------------------
// wave = node; lane = h*16 + c; lane covers x2 channels [c*4, c*4+4).
template<int USE_EAP>
__global__ __launch_bounds__(256) void k_tconv5(
    const _Float16* __restrict__ Yb, const _Float16* __restrict__ qtp,
    const float* __restrict__ zt, const _Float16* __restrict__ x2h,
    const _Float16* __restrict__ eap, const float* __restrict__ ea,
    const int* __restrict__ perm, const int* __restrict__ offs,
    const int* __restrict__ sperm,
    _Float16* __restrict__ xaccb, _Float16* __restrict__ wab,
    float* __restrict__ lb)
{
    int t = threadIdx.x;
    int wid = __builtin_amdgcn_readfirstlane(t >> 6);
    int n = blockIdx.x * 4 + wid;
    int lane = t & 63;
    int h = lane >> 4, c = lane & 15;
    float yb0, yb1, yb2, yb3;
    {
        half4v Y4 = *(const half4v*)&Yb[(size_t)n * 256 + h * 64 + c * 4];
        float4 z4 = *(const float4*)&zt[h * 64 + c * 4];
        yb0 = (float)Y4[0] + z4.x; yb1 = (float)Y4[1] + z4.y;
        yb2 = (float)Y4[2] + z4.z; yb3 = (float)Y4[3] + z4.w;
    }
    half2v qt2 = *(const half2v*)&qtp[(size_t)n * 128 + h * 32 + c * 2];
    float qt0 = (float)qt2[0], qt1 = (float)qt2[1];
    int j0 = __builtin_amdgcn_readfirstlane(offs[n]);
    int j1 = __builtin_amdgcn_readfirstlane(offs[n + 1]);
    float l = 0.f;
    float xa0 = 0.f, xa1 = 0.f, xa2 = 0.f, xa3 = 0.f;
    float wa0 = 0.f, wa1 = 0.f;
    int j = j0;
    for (; j + 1 < j1; j += 2) {
        int s0 = __builtin_amdgcn_readfirstlane(sperm[j]);
        int s1 = __builtin_amdgcn_readfirstlane(sperm[j + 1]);
        half4v xA = *(const half4v*)&x2h[(size_t)s0 * 64 + c * 4];
        half4v xB = *(const half4v*)&x2h[(size_t)s1 * 64 + c * 4];
        float eA0, eA1, eB0, eB1;
        if (USE_EAP) {
            half2v vA = *(const half2v*)&eap[(size_t)j * 32 + c * 2];
            half2v vB = *(const half2v*)&eap[(size_t)(j + 1) * 32 + c * 2];
            eA0 = (float)vA[0]; eA1 = (float)vA[1];
            eB0 = (float)vB[0]; eB1 = (float)vB[1];
        } else {
            int e0 = __builtin_amdgcn_readfirstlane(perm[j]);
            int e1 = __builtin_amdgcn_readfirstlane(perm[j + 1]);
            float2 fA = *(const float2*)&ea[(size_t)e0 * 32 + c * 2];
            float2 fB = *(const float2*)&ea[(size_t)e1 * 32 + c * 2];
            eA0 = fA.x; eA1 = fA.y; eB0 = fB.x; eB1 = fB.y;
        }
        float xA0 = (float)xA[0], xA1f = (float)xA[1];
        float xA2 = (float)xA[2], xA3 = (float)xA[3];
        float xB0 = (float)xB[0], xB1f = (float)xB[1];
        float xB2 = (float)xB[2], xB3 = (float)xB[3];
        float p0 = yb0 * xA0 + yb1 * xA1f + yb2 * xA2 + yb3 * xA3
                 + qt0 * eA0 + qt1 * eA1;
        float p1 = yb0 * xB0 + yb1 * xB1f + yb2 * xB2 + yb3 * xB3
                 + qt0 * eB0 + qt1 * eB1;
        p0 += __shfl_xor(p0, 1); p1 += __shfl_xor(p1, 1);
        p0 += __shfl_xor(p0, 2); p1 += __shfl_xor(p1, 2);
        p0 += __shfl_xor(p0, 4); p1 += __shfl_xor(p1, 4);
        p0 += __shfl_xor(p0, 8); p1 += __shfl_xor(p1, 8);
        float w0 = __expf(p0), w1 = __expf(p1);   // logits O(0.5): no-max exact
        l += w0 + w1;
        xa0 += w0 * xA0 + w1 * xB0;
        xa1 += w0 * xA1f + w1 * xB1f;
        xa2 += w0 * xA2 + w1 * xB2;
        xa3 += w0 * xA3 + w1 * xB3;
        wa0 += w0 * eA0 + w1 * eB0;
        wa1 += w0 * eA1 + w1 * eB1;
    }
    if (j < j1) {
        int s0 = __builtin_amdgcn_readfirstlane(sperm[j]);
        half4v xA = *(const half4v*)&x2h[(size_t)s0 * 64 + c * 4];
        float eA0, eA1;
        if (USE_EAP) {
            half2v vA = *(const half2v*)&eap[(size_t)j * 32 + c * 2];
            eA0 = (float)vA[0]; eA1 = (float)vA[1];
        } else {
            int e0 = __builtin_amdgcn_readfirstlane(perm[j]);
            float2 fA = *(const float2*)&ea[(size_t)e0 * 32 + c * 2];
            eA0 = fA.x; eA1 = fA.y;
        }
        float xA0 = (float)xA[0], xA1f = (float)xA[1];
        float xA2 = (float)xA[2], xA3 = (float)xA[3];
        float p0 = yb0 * xA0 + yb1 * xA1f + yb2 * xA2 + yb3 * xA3
                 + qt0 * eA0 + qt1 * eA1;
        p0 += __shfl_xor(p0, 1); p0 += __shfl_xor(p0, 2);
        p0 += __shfl_xor(p0, 4); p0 += __shfl_xor(p0, 8);
        float w0 = __expf(p0);
        l += w0;
        xa0 += w0 * xA0; xa1 += w0 * xA1f; xa2 += w0 * xA2; xa3 += w0 * xA3;
        wa0 += w0 * eA0; wa1 += w0 * eA1;
    }
    half4v xo;
    xo[0] = (_Float16)xa0; xo[1] = (_Float16)xa1;
    xo[2] = (_Float16)xa2; xo[3] = (_Float16)xa3;
    *(half4v*)&xaccb[(size_t)n * 256 + h * 64 + c * 4] = xo;
    half2v wo;
    wo[0] = (_Float16)wa0; wo[1] = (_Float16)wa1;
    *(half2v*)&wab[(size_t)n * 128 + h * 32 + c * 2] = wo;
    if (c == 0) lb[n * 4 + h] = l;
}

// ---------------- tconv epilogue: out = ([xacc|wa]@[Wv;We3])/l + bv + skip -
// grid N/64; wave = head; direct global fragment loads, no LDS.
__global__ __launch_bounds__(256) void k_tpost(
    const _Float16* __restrict__ xaccb, const _Float16* __restrict__ wab,
    const float* __restrict__ lb, const _Float16* __restrict__ Bt3,
    const float* __restrict__ bv, _Float16* __restrict__ skiph)
{
    int t = threadIdx.x;
    int h = t >> 6;
    int l = t & 63;
    int n0 = blockIdx.x * 64;
    int colg = l & 15, kg = (l >> 4) * 8;
    half8v Bf[4][3];
#pragma unroll
    for (int ct = 0; ct < 4; ct++) {
        size_t cb = (size_t)(h * 64 + ct * 16 + colg) * 96;
        Bf[ct][0] = *(const half8v*)&Bt3[cb + kg];
        Bf[ct][1] = *(const half8v*)&Bt3[cb + 32 + kg];
        Bf[ct][2] = *(const half8v*)&Bt3[cb + 64 + kg];
    }
#pragma unroll
    for (int rt = 0; rt < 4; rt++) {
        int arow = n0 + rt * 16 + (l & 15);
        half8v A0 = *(const half8v*)&xaccb[(size_t)arow * 256 + h * 64 + kg];
        half8v A1 = *(const half8v*)&xaccb[(size_t)arow * 256 + h * 64 + 32 + kg];
        half8v A2 = *(const half8v*)&wab[(size_t)arow * 128 + h * 32 + kg];
#pragma unroll
        for (int ct = 0; ct < 4; ct++) {
            float4v acc = {0.f, 0.f, 0.f, 0.f};
            acc = __builtin_amdgcn_mfma_f32_16x16x32_f16(A0, Bf[ct][0], acc, 0, 0, 0);
            acc = __builtin_amdgcn_mfma_f32_16x16x32_f16(A1, Bf[ct][1], acc, 0, 0, 0);
            acc = __builtin_amdgcn_mfma_f32_16x16x32_f16(A2, Bf[ct][2], acc, 0, 0, 0);
            int col = h * 64 + ct * 16 + colg;
            float bvc = bv[col];
#pragma unroll
            for (int r = 0; r < 4; r++) {
                int row = n0 + rt * 16 + (l >> 4) * 4 + r;
                float lv = lb[row * 4 + h];
                float rl = (lv > 0.f) ? 1.f / lv : 0.f;
                float bterm = (lv > 0.f) ? bvc : 0.f;
                size_t o = (size_t)row * 256 + col;
                float out = acc[r] * rl + bterm + (float)skiph[o];
                skiph[o] = (_Float16)out;
            }
        }
    }
}

// ---------------- GAT xl/xr projections (fused L+R, fp16 A) ----------------
__global__ __launch_bounds__(256) void k_gatgemm(
    const _Float16* __restrict__ A,
    const _Float16* __restrict__ WtL, const float* __restrict__ bL,
    const _Float16* __restrict__ WtR, const float* __restrict__ bR,
    _Float16* __restrict__ xlh, _Float16* __restrict__ xrh)
{
    __shared__ _Float16 As[64][136];
    __shared__ _Float16 WsL[64][136];
    __shared__ _Float16 WsR[64][136];
    int t = threadIdx.x;
    int n0 = blockIdx.x * 64;
    int w = t >> 6, l = t & 63;
    int arow = w * 16 + (l & 15);
    int kg = (l >> 4) * 8;
    int colg = l & 15;
    int orow = w * 16 + (l >> 4) * 4;
    float4v accL[4] = {{0.f,0.f,0.f,0.f},{0.f,0.f,0.f,0.f},
                       {0.f,0.f,0.f,0.f},{0.f,0.f,0.f,0.f}};
    float4v accR[4] = {{0.f,0.f,0.f,0.f},{0.f,0.f,0.f,0.f},
                       {0.f,0.f,0.f,0.f},{0.f,0.f,0.f,0.f}};
    for (int kh = 0; kh < 2; kh++) {
        __syncthreads();
        for (int f = t; f < 1024; f += 256) {
            int r = f >> 4, seg = f & 15;
            *(uint4*)&As[r][seg * 8] =
                *(const uint4*)&A[(size_t)(n0 + r) * 256 + kh * 128 + seg * 8];
            *(uint4*)&WsL[r][seg * 8] =
                *(const uint4*)&WtL[(size_t)r * 256 + kh * 128 + seg * 8];
            *(uint4*)&WsR[r][seg * 8] =
                *(const uint4*)&WtR[(size_t)r * 256 + kh * 128 + seg * 8];
        }
        __syncthreads();
#pragma unroll
        for (int ks = 0; ks < 4; ks++) {
            half8v a = *(const half8v*)&As[arow][ks * 32 + kg];
#pragma unroll
            for (int ct = 0; ct < 4; ct++) {
                half8v bl_ = *(const half8v*)&WsL[ct * 16 + colg][ks * 32 + kg];
                half8v br_ = *(const half8v*)&WsR[ct * 16 + colg][ks * 32 + kg];
                accL[ct] = __builtin_amdgcn_mfma_f32_16x16x32_f16(a, bl_, accL[ct], 0, 0, 0);
                accR[ct] = __builtin_amdgcn_mfma_f32_16x16x32_f16(a, br_, accR[ct], 0, 0, 0);
            }
        }
    }
#pragma unroll
    for (int ct = 0; ct < 4; ct++) {
        int col = ct * 16 + colg;
        float bvL = bL[col], bvR = bR[col];
#pragma unroll
        for (int r = 0; r < 4; r++) {
            xlh[(size_t)(n0 + orow + r) * 64 + col] = (_Float16)(accL[ct][r] + bvL);
            xrh[(size_t)(n0 + orow + r) * 64 + col] = (_Float16)(accR[ct][r] + bvR);
        }
    }
}

// ---------------- GATv2 aggregation, quad layout ---------------------------
__global__ __launch_bounds__(256) void k_gat2(
    const _Float16* __restrict__ xl, const _Float16* __restrict__ xr,
    const _Float16* __restrict__ e4p,
    const float* __restrict__ attv, const float* __restrict__ bias4,
    const int* __restrict__ offs, const int* __restrict__ sperm,
    float* __restrict__ out)
{
    int t = threadIdx.x;
    int wid  = __builtin_amdgcn_readfirstlane(t >> 6);
    int n    = blockIdx.x * 4 + wid;
    int lane = t & 63;
    int g = lane >> 4, li = lane & 15, c0 = li * 4;
    half4v xrh = *(const half4v*)&xr[(size_t)n * 64 + c0];
    float xr0 = (float)xrh[0], xr1 = (float)xrh[1];
    float xr2 = (float)xrh[2], xr3 = (float)xrh[3];
    float4 av  = *(const float4*)&attv[c0];
    int j0 = __builtin_amdgcn_readfirstlane(offs[n]);
    int j1 = __builtin_amdgcn_readfirstlane(offs[n + 1]);
    float l = 0.f;
    float4 acc = {0.f, 0.f, 0.f, 0.f};
    for (int jq = j0; jq < j1; jq += 4) {
        int j = jq + g;
        int jc = (j < j1) ? j : (j1 - 1);
        int s = sperm[jc];
        half4v ev = *(const half4v*)&e4p[(size_t)jc * 64 + c0];
        half4v xlv = *(const half4v*)&xl[(size_t)s * 64 + c0];
        float x0 = (float)xlv[0], x1 = (float)xlv[1];
        float x2 = (float)xlv[2], x3 = (float)xlv[3];
        float h0 = x0 + xr0 + (float)ev[0];
        float h1 = x1 + xr1 + (float)ev[1];
        float h2 = x2 + xr2 + (float)ev[2];
        float h3 = x3 + xr3 + (float)ev[3];
        h0 = (h0 > 0.f) ? h0 : 0.2f * h0;
        h1 = (h1 > 0.f) ? h1 : 0.2f * h1;
        h2 = (h2 > 0.f) ? h2 : 0.2f * h2;
        h3 = (h3 > 0.f) ? h3 : 0.2f * h3;
        float p = h0 * av.x + h1 * av.y + h2 * av.z + h3 * av.w;
        p += __shfl_xor(p, 1); p += __shfl_xor(p, 2);
        p += __shfl_xor(p, 4); p += __shfl_xor(p, 8);
        float w = (j < j1) ? __expf(p) : 0.f;
        l += w;
        acc.x = fmaf(w, x0, acc.x);
        acc.y = fmaf(w, x1, acc.y);
        acc.z = fmaf(w, x2, acc.z);
        acc.w = fmaf(w, x3, acc.w);
    }
    l += __shfl_xor(l, 16); l += __shfl_xor(l, 32);
    acc.x += __shfl_xor(acc.x, 16); acc.x += __shfl_xor(acc.x, 32);
    acc.y += __shfl_xor(acc.y, 16); acc.y += __shfl_xor(acc.y, 32);
    acc.z += __shfl_xor(acc.z, 16); acc.z += __shfl_xor(acc.z, 32);
    acc.w += __shfl_xor(acc.w, 16); acc.w += __shfl_xor(acc.w, 32);
    if (g == 0) {
        float rl = 1.f / (l + 1e-16f);
        float4 bv = *(const float4*)&bias4[c0];
        float4 o;
        o.x = acc.x * rl + bv.x;
        o.y = acc.y * rl + bv.y;
        o.z = acc.z * rl + bv.z;
        o.w = acc.w * rl + bv.w;
        *(float4*)&out[(size_t)n * 64 + c0] = o;
    }
}

// ---------------------------------------------------------------------------
extern "C" void kernel_launch(void* const* d_in, const int* in_sizes, int n_in,
                              void* d_out, int out_size, void* d_ws, size_t ws_size,
                              hipStream_t stream)
{
    const float* x     = (const float*)d_in[0];
    const float* ea    = (const float*)d_in[1];
    const float* eps1  = (const float*)d_in[2];
    const float* w1a   = (const float*)d_in[3];
    const float* b1a   = (const float*)d_in[4];
    const float* w1b   = (const float*)d_in[5];
    const float* b1b   = (const float*)d_in[6];
    const float* we1   = (const float*)d_in[7];
    const float* be1   = (const float*)d_in[8];
    const float* eps2  = (const float*)d_in[9];
    const float* w2a   = (const float*)d_in[10];
    const float* b2a   = (const float*)d_in[11];
    const float* w2b   = (const float*)d_in[12];
    const float* b2b   = (const float*)d_in[13];
    const float* we2   = (const float*)d_in[14];
    const float* be2   = (const float*)d_in[15];
    const float* wq    = (const float*)d_in[16];
    const float* bq    = (const float*)d_in[17];
    const float* wk    = (const float*)d_in[18];
    const float* bk    = (const float*)d_in[19];
    const float* wv    = (const float*)d_in[20];
    const float* bvv   = (const float*)d_in[21];
    const float* we3   = (const float*)d_in[22];
    const float* wskip = (const float*)d_in[23];
    const float* bskip = (const float*)d_in[24];
    const float* wl    = (const float*)d_in[25];
    const float* bl    = (const float*)d_in[26];
    const float* wr    = (const float*)d_in[27];
    const float* br    = (const float*)d_in[28];
    const float* we4   = (const float*)d_in[29];
    const float* attv  = (const float*)d_in[30];
    const float* bias4 = (const float*)d_in[31];
    const void*  eidx  = d_in[32];
    (void)bk;

    const int N = in_sizes[0] / 64;     // 32768
    const int E = in_sizes[1] / 32;     // 524288

    char* ws = (char*)d_ws;
    size_t off = 0;
    auto alloc = [&](size_t bytes) {
        void* p = ws + off;
        off += (bytes + 255) & ~(size_t)255;
        return p;
    };
    int* flag    = (int*)alloc(4);
    int* econv   = (int*)alloc((size_t)2 * E * 4);
    int* counts  = (int*)alloc((size_t)N * 4);
    int* cursor  = (int*)alloc((size_t)N * 4);
    int* offs    = (int*)alloc((size_t)(N + 1) * 4);
    int* perm    = (int*)alloc((size_t)E * 4);
    int* sperm   = (int*)alloc((size_t)E * 4);
    _Float16* xh  = (_Float16*)alloc((size_t)N * 64 * 2);
    _Float16* h16 = (_Float16*)alloc((size_t)N * 64 * 2);
    _Float16* x1h = (_Float16*)alloc((size_t)N * 64 * 2);
    _Float16* x2h = (_Float16*)alloc((size_t)N * 64 * 2);
    _Float16* Wts  = (_Float16*)alloc(16384 * 2);
    _Float16* Gt   = (_Float16*)alloc(16384 * 2);
    _Float16* Wtl  = (_Float16*)alloc(16384 * 2);
    _Float16* Wtr  = (_Float16*)alloc(16384 * 2);
    _Float16* Wt1a = (_Float16*)alloc(4096 * 2);
    _Float16* Wt1b = (_Float16*)alloc(4096 * 2);
    _Float16* Wt2a = (_Float16*)alloc(2048 * 2);
    _Float16* Wt2b = (_Float16*)alloc(2048 * 2);
    _Float16* Mt   = (_Float16*)alloc(8192 * 2);
    float*    cst  = (float*)alloc(128 * 4);
    _Float16* Wt1e = (_Float16*)alloc(2048 * 2);
    _Float16* Wt2e = (_Float16*)alloc(2048 * 2);
    _Float16* Wt4e = (_Float16*)alloc(2048 * 2);
    float*    zt   = (float*)alloc(256 * 4);
    _Float16* Bt3  = (_Float16*)alloc(24576 * 2);
    // big overlaid region R (134 MB)
    char* R = (char*)alloc((size_t)2 * E * 64 * 2);
    // phase 1: e1p/e2p
    _Float16* e1p = (_Float16*)R;
    _Float16* e2p = e1p + (size_t)E * 64;
    // phase 2 (after gine2-2): Y | skiph | qtp | xacc | wab | lb
    _Float16* Yb    = (_Float16*)R;
    _Float16* skiph = Yb + (size_t)N * 256;
    _Float16* qtp   = skiph + (size_t)N * 256;
    _Float16* xaccb = qtp + (size_t)N * 128;
    _Float16* wab   = xaccb + (size_t)N * 256;
    float*    lb    = (float*)(wab + (size_t)N * 128);
    // phase 3 (after gatgemm): e4p over dead Y..skiph..
    _Float16* e4p = (_Float16*)R;
    _Float16* xlh = h16;
    _Float16* xrh = x1h;
    size_t base_off = off;
    _Float16* eap = (_Float16*)alloc((size_t)E * 32 * 2);   // optional 33.5 MB
    int use_eap = (off <= ws_size) ? 1 : 0;

    if (base_off > ws_size) return;   // catastrophic: visible failure

    // weight prep + x fp16 (512 blocks: ranges up to 96640)
    k_prep<<<512, 256, 0, stream>>>(x, N * 64, wq, wk, wv, wskip, wl, wr,
                                    w1a, w1b, w2a, w2b, we3, bq, we1, we2, we4,
                                    xh, Wts, Gt, Wtl, Wtr,
                                    Wt1a, Wt1b, Wt2a, Wt2b, Mt, cst,
                                    Wt1e, Wt2e, Wt4e, zt, Bt3);

    // edge_index: detect dtype, convert, histogram dst
    k_detect<<<1, 256, 0, stream>>>((const unsigned int*)eidx, flag);
    hipMemsetAsync(counts, 0, (size_t)N * 4, stream);
    k_cvt<<<(2 * E + 255) / 256, 256, 0, stream>>>(eidx, flag, econv, counts, E);
    const int* srcI = econv;
    const int* dstI = econv + E;

    // CSR by dst (+ fused eap write)
    k_scan<<<1, 1024, 0, stream>>>(counts, offs, cursor, N);
    if (use_eap)
        k_scatter<1><<<(E + 255) / 256, 256, 0, stream>>>(dstI, srcI, cursor, perm,
                                                          sperm, ea, eap, E);
    else
        k_scatter<0><<<(E + 255) / 256, 256, 0, stream>>>(dstI, srcI, cursor, perm,
                                                          sperm, ea, eap, E);

    // e1, e2 materialization (perm order, fp16)
    if (use_eap)
        k_emm<<<E / 64, 256, 0, stream>>>(eap, Wt1e, be1, e1p, Wt2e, be2, e2p, 1);
    else
        k_egv<<<E / 32, 256, 0, stream>>>(ea, perm, we1, be1, e1p, we2, be2, e2p, 1);

    // GINE 1 + MLP1
    k_gine2<<<N / 4, 256, 0, stream>>>(xh, e1p, eps1, offs, sperm, h16);
    k_mlp<64><<<N / 64, 256, 0, stream>>>(h16, Wt1a, b1a, Wt1b, b1b, x1h);

    // GINE 2 + MLP2
    k_gine2<<<N / 4, 256, 0, stream>>>(x1h, e2p, eps2, offs, sperm, h16);
    k_mlp<32><<<N / 64, 256, 0, stream>>>(h16, Wt2a, b2a, Wt2b, b2b, x2h);

    // TransformerConv: Y/skip/qt projections, core, epilogue
    k_gemm4m<<<dim3(N / 64, 9), 256, 0, stream>>>(x2h, Gt, Wts, bskip, Mt, cst,
                                                  Yb, skiph, qtp);
    if (use_eap)
        k_tconv5<1><<<N / 4, 256, 0, stream>>>(Yb, qtp, zt, x2h, eap, ea, perm,
                                               offs, sperm, xaccb, wab, lb);
    else
        k_tconv5<0><<<N / 4, 256, 0, stream>>>(Yb, qtp, zt, x2h, eap, ea, perm,
                                               offs, sperm, xaccb, wab, lb);
    k_tpost<<<N / 64, 256, 0, stream>>>(xaccb, wab, lb, Bt3, bvv, skiph);

    // GATv2: projections (reads skiph), then e4p overlay, then aggregation
    k_gatgemm<<<N / 64, 256, 0, stream>>>(skiph, Wtl, bl, Wtr, br, xlh, xrh);
    if (use_eap)
        k_emm<<<E / 64, 256, 0, stream>>>(eap, Wt4e, (const float*)nullptr, e4p,
                                          (const _Float16*)nullptr,
                                          (const float*)nullptr,
                                          (_Float16*)nullptr, 0);
    else
        k_egv<<<E / 32, 256, 0, stream>>>(ea, perm, we4, (const float*)nullptr, e4p,
                                          (const float*)nullptr,
                                          (const float*)nullptr,
                                          (_Float16*)nullptr, 0);
    k_gat2<<<N / 4, 256, 0, stream>>>(xlh, xrh, e4p, attv, bias4, offs, sperm,
                                      (float*)d_out);
}